// Round 9
// baseline (507.657 us; speedup 1.0000x reference)
//
#include <hip/hip_runtime.h>
#include <hip/hip_bf16.h>
#include <stdint.h>
#include <stddef.h>

typedef __hip_bfloat16 bf16;
typedef __attribute__((ext_vector_type(8))) short short8;
typedef __attribute__((ext_vector_type(4))) float f32x4;
typedef unsigned short us;

__device__ __forceinline__ float dsigm(float z){ return 1.f/(1.f+expf(-z)); }

__device__ __forceinline__ us bf16r(float v) {
  bf16 h = __float2bfloat16(v);
  return __builtin_bit_cast(us, h);
}

// split fp32 -> hi (ROUNDED bf16) + lo (rounded bf16 residual); ~16 mantissa bits
__device__ __forceinline__ void split1(float v, us& h, us& l) {
  bf16 hb = __float2bfloat16(v);
  h = __builtin_bit_cast(us, hb);
  float hf = __bfloat162float(hb);
  bf16 lb = __float2bfloat16(v - hf);
  l = __builtin_bit_cast(us, lb);
}

__device__ __forceinline__ void split8(const float* f, short8& h, short8& l) {
#pragma unroll
  for (int e = 0; e < 8; ++e) {
    us hh, ll;
    split1(f[e], hh, ll);
    h[e] = (short)hh; l[e] = (short)ll;
  }
}

// async global->LDS, 16B per lane (dest = wave-uniform base + lane*16)
__device__ __forceinline__ void gl16(const us* g, us* l) {
  __builtin_amdgcn_global_load_lds((const __attribute__((address_space(1))) void*)g,
                                   (__attribute__((address_space(3))) void*)l, 16, 0, 0);
}

//==================== 1. time-shift lerp -> packed split-bf16 operands ====================
__device__ __forceinline__ void emit_pack(const float* __restrict__ marr, int c4,
    const float4& cur, const float4& dlt, us* __restrict__ out, int row)
{
  float4 m = *(const float4*)(marr + c4);
  float v0 = fmaf(dlt.x, m.x, cur.x);
  float v1 = fmaf(dlt.y, m.y, cur.y);
  float v2 = fmaf(dlt.z, m.z, cur.z);
  float v3 = fmaf(dlt.w, m.w, cur.w);
  us h0,h1,h2,h3,l0,l1,l2,l3;
  split1(v0,h0,l0); split1(v1,h1,l1); split1(v2,h2,l2); split1(v3,h3,l3);
  *(ushort4*)(out + (size_t)row*2048 + c4)        = make_ushort4(h0,h1,h2,h3);
  *(ushort4*)(out + (size_t)row*2048 + 1024 + c4) = make_ushort4(l0,l1,l2,l3);
}

__global__ void k_prep(const float* __restrict__ hs,
    const float* __restrict__ mr, const float* __restrict__ mw, const float* __restrict__ mk,
    const float* __restrict__ mv, const float* __restrict__ ma,
    us* __restrict__ oxr, us* __restrict__ oxw, us* __restrict__ oxk,
    us* __restrict__ oxv, us* __restrict__ oxa)
{
  int id = blockIdx.x * 256 + threadIdx.x;
  int row = id >> 8;
  int c4 = (id & 255) << 2;
  int t = row & 2047;
  const float* hp = hs + (size_t)row*1024 + c4;
  float4 cur = *(const float4*)hp;
  float4 prev = make_float4(0.f,0.f,0.f,0.f);
  if (t > 0) prev = *(const float4*)(hp - 1024);
  float4 dlt = make_float4(prev.x-cur.x, prev.y-cur.y, prev.z-cur.z, prev.w-cur.w);
  emit_pack(mr, c4, cur, dlt, oxr, row);
  emit_pack(mw, c4, cur, dlt, oxw, row);
  emit_pack(mk, c4, cur, dlt, oxk, row);
  emit_pack(mv, c4, cur, dlt, oxv, row);
  emit_pack(ma, c4, cur, dlt, oxa, row);
}

//==================== 2. weight transpose + split-bf16 pack ====================
struct SrcP { const float* p[10]; };
struct DstP { us* p[10]; };

__global__ void k_transpose(SrcP S, DstP Dd)
{
  static constexpr int TR[10]  = {1024,1024,1024,1024,1024,  64,1024,  64,1024, 128};
  static constexpr int TCC[10] = {1024,1024,1024,1024,  64,1024,  64,1024, 128,1024};
  static constexpr int TCP[10] = {1024,1024,1024,1024, 128,1024, 128,1024, 128,1024};
  int z = blockIdx.z;
  int R = TR[z], Cc = TCC[z], Cp = TCP[z];
  int n0 = blockIdx.x * 32, r0 = blockIdx.y * 32;
  if (n0 >= Cp || r0 >= R) return;
  const float* src = S.p[z];
  us* dst = Dd.p[z];
  int tx = threadIdx.x, ty = threadIdx.y;
  __shared__ float tile[32][33];
  if (n0 < Cc) {
#pragma unroll
    for (int i = 0; i < 4; ++i)
      tile[ty + 8*i][tx] = src[(size_t)(r0 + ty + 8*i)*Cc + n0 + tx];
    __syncthreads();
#pragma unroll
    for (int i = 0; i < 4; ++i) {
      float v = tile[tx][ty + 8*i];
      us h, lo;
      split1(v, h, lo);
      size_t nr = (size_t)(n0 + ty + 8*i);
      dst[nr*2*R + r0 + tx]     = h;
      dst[nr*2*R + R + r0 + tx] = lo;
    }
  } else {
#pragma unroll
    for (int i = 0; i < 4; ++i) {
      size_t nr = (size_t)(n0 + ty + 8*i);
      dst[nr*2*R + r0 + tx]     = 0;
      dst[nr*2*R + R + r0 + tx] = 0;
    }
  }
}

//==================== 3. batched split-bf16 GEMM (3-term, fp32-grade) ====================
struct GJob {
  const us* A;
  const us* Bt;
  float* C;
  us* Cpk;
  const float* bias;
  int K; int N; int Npk; int ldc; int act;
  int lda; int ldb; int terms3;
};
struct GJobs { GJob j[5]; };

__global__ __launch_bounds__(256) void k_gemm_bf(GJobs jobs)
{
  GJob jb = jobs.j[blockIdx.z];
  const int colBase = blockIdx.y * 128;
  if (colBase >= jb.N) return;
  const int rowBase = blockIdx.x * 128;
  __shared__ __align__(16) us AsH[128*32];
  __shared__ __align__(16) us AsL[128*32];
  __shared__ __align__(16) us BsH[128*32];
  __shared__ __align__(16) us BsL[128*32];
  const int tid = threadIdx.x;
  const int l = tid & 63, w = tid >> 6;
  const int wm = w >> 1, wn = w & 1;
  const int lrow = l & 15, kid = (l >> 4) * 8;
  const int K = jb.K;
  const int nk = K >> 5;
  const bool t3 = (jb.terms3 != 0);

  const int s0 = w*64 + l, s1 = (4 + w)*64 + l;
  const int ar0 = s0 >> 2, ac0 = (s0 & 3) * 8;
  const int ar1 = s1 >> 2, ac1 = (s1 & 3) * 8;
  const int ld0 = w*512, ld1 = (4 + w)*512;
  const us* Arow0 = jb.A  + (size_t)(rowBase + ar0)*jb.lda + ac0;
  const us* Arow1 = jb.A  + (size_t)(rowBase + ar1)*jb.lda + ac1;
  const us* Brow0 = jb.Bt + (size_t)(colBase + ar0)*jb.ldb + ac0;
  const us* Brow1 = jb.Bt + (size_t)(colBase + ar1)*jb.ldb + ac1;

  f32x4 acc[4][4];
#pragma unroll
  for (int i = 0; i < 4; ++i)
#pragma unroll
    for (int j = 0; j < 4; ++j) { f32x4 z = {0.f,0.f,0.f,0.f}; acc[i][j] = z; }

  for (int kt = 0; kt < nk; ++kt) {
    const int kh = kt*32;
    gl16(Arow0 + kh, &AsH[ld0]);  gl16(Arow1 + kh, &AsH[ld1]);
    gl16(Brow0 + kh, &BsH[ld0]);  gl16(Brow1 + kh, &BsH[ld1]);
    if (t3) {
      const int klo = K + kt*32;
      gl16(Arow0 + klo, &AsL[ld0]);  gl16(Arow1 + klo, &AsL[ld1]);
      gl16(Brow0 + klo, &BsL[ld0]);  gl16(Brow1 + klo, &BsL[ld1]);
    }
    __syncthreads();

    short8 ah[4], bh[4];
#pragma unroll
    for (int mt = 0; mt < 4; ++mt) ah[mt] = *(const short8*)&AsH[(wm*64 + mt*16 + lrow)*32 + kid];
#pragma unroll
    for (int nt = 0; nt < 4; ++nt) bh[nt] = *(const short8*)&BsH[(wn*64 + nt*16 + lrow)*32 + kid];
#pragma unroll
    for (int mt = 0; mt < 4; ++mt)
#pragma unroll
      for (int nt = 0; nt < 4; ++nt)
        acc[mt][nt] = __builtin_amdgcn_mfma_f32_16x16x32_bf16(ah[mt], bh[nt], acc[mt][nt], 0, 0, 0);
    if (t3) {
      short8 al[4], bl[4];
#pragma unroll
      for (int mt = 0; mt < 4; ++mt) al[mt] = *(const short8*)&AsL[(wm*64 + mt*16 + lrow)*32 + kid];
#pragma unroll
      for (int nt = 0; nt < 4; ++nt) bl[nt] = *(const short8*)&BsL[(wn*64 + nt*16 + lrow)*32 + kid];
#pragma unroll
      for (int mt = 0; mt < 4; ++mt)
#pragma unroll
        for (int nt = 0; nt < 4; ++nt) {
          acc[mt][nt] = __builtin_amdgcn_mfma_f32_16x16x32_bf16(al[mt], bh[nt], acc[mt][nt], 0, 0, 0);
          acc[mt][nt] = __builtin_amdgcn_mfma_f32_16x16x32_bf16(ah[mt], bl[nt], acc[mt][nt], 0, 0, 0);
        }
    }
    __syncthreads();
  }
#pragma unroll
  for (int mt = 0; mt < 4; ++mt) {
    int row = rowBase + wm*64 + mt*16 + (l >> 4)*4;
#pragma unroll
    for (int nt = 0; nt < 4; ++nt) {
      int col = colBase + wn*64 + nt*16 + (l & 15);
      float bv = (jb.bias != nullptr) ? jb.bias[col] : 0.f;
#pragma unroll
      for (int rg = 0; rg < 4; ++rg) {
        float v = acc[mt][nt][rg] + bv;
        if (jb.act == 1)      v = dsigm(v);
        else if (jb.act == 2) v = tanhf(v);
        else if (jb.act == 3) v = 0.60653066f * dsigm(v);
        if (jb.C) jb.C[(size_t)(row + rg)*jb.ldc + col] = v;
        if (jb.Cpk && col < jb.Npk) {
          us h, lo;
          split1(v, h, lo);
          us* pk = jb.Cpk + (size_t)(row + rg)*(2*jb.Npk);
          pk[col] = h;
          pk[jb.Npk + col] = lo;
        }
      }
    }
  }
}

//==================== 5. scan prep: kk normalize + k update + b=kk*a ====================
__global__ void k_scanprep(float* __restrict__ kA, float* __restrict__ aA,
                           const float* __restrict__ kkw, const float* __restrict__ kaw,
                           float* __restrict__ kkA)
{
  size_t gt = (size_t)blockIdx.x * 256u + threadIdx.x;
  int d = (int)(gt & 63);
  size_t flat = gt >> 6;
  int c = (int)((flat & 15) * 64 + d);
  float k0 = kA[gt], av = aA[gt];
  float kkv = k0 * kkw[c];
  float ss = kkv * kkv;
  ss += __shfl_xor(ss, 1);  ss += __shfl_xor(ss, 2);  ss += __shfl_xor(ss, 4);
  ss += __shfl_xor(ss, 8);  ss += __shfl_xor(ss, 16); ss += __shfl_xor(ss, 32);
  float inv = 1.f / fmaxf(sqrtf(ss), 1e-12f);
  float kkn = kkv * inv;
  kkA[gt] = kkn;
  aA[gt]  = kkn * av;
  kA[gt]  = k0 * fmaf(av - 1.f, kaw[c], 1.f);
}

//==================== 6a. chunked scan pass 1 (LDS-staged, 4-step groups) ====================
#define SP1_EW 0
#define SP1_KK 256
#define SP1_BB 512
#define SP1_KV 768
#define SP1_RR 1024
#define SP1_VV 1280

__device__ __forceinline__ void step_lds(const float* __restrict__ sb, int s,
    float* u, float* p, float* __restrict__ o0A, float* __restrict__ zA,
    size_t base, int i, int q, int j0)
{
  float4 ew0 = *(const float4*)(sb + SP1_EW + s*64 + j0);
  float4 ew1 = *(const float4*)(sb + SP1_EW + s*64 + j0 + 4);
  float4 kk0 = *(const float4*)(sb + SP1_KK + s*64 + j0);
  float4 kk1 = *(const float4*)(sb + SP1_KK + s*64 + j0 + 4);
  float4 bb0 = *(const float4*)(sb + SP1_BB + s*64 + j0);
  float4 bb1 = *(const float4*)(sb + SP1_BB + s*64 + j0 + 4);
  float4 kv0 = *(const float4*)(sb + SP1_KV + s*64 + j0);
  float4 kv1 = *(const float4*)(sb + SP1_KV + s*64 + j0 + 4);
  float4 rr0 = *(const float4*)(sb + SP1_RR + s*64 + j0);
  float4 rr1 = *(const float4*)(sb + SP1_RR + s*64 + j0 + 4);
  float vi = sb[SP1_VV + s*64 + i];

  float uk = 0.f, pk = 0.f;
#define RED(SI, V, F) { uk += u[SI]*V.F; pk += p[SI]*V.F; }
  RED(0,kk0,x) RED(1,kk0,y) RED(2,kk0,z) RED(3,kk0,w)
  RED(4,kk1,x) RED(5,kk1,y) RED(6,kk1,z) RED(7,kk1,w)
#undef RED
  uk += __shfl_xor(uk, 1); uk += __shfl_xor(uk, 2); uk += __shfl_xor(uk, 4);
  pk += __shfl_xor(pk, 1); pk += __shfl_xor(pk, 2); pk += __shfl_xor(pk, 4);
  const float su = -uk, sp = -pk;
  float oo = 0.f, zz = 0.f;
#define UPD(SI, E, Kv, Bv, Rv, F) { \
    float uu = u[SI]*E.F + su*Bv.F + vi*Kv.F; u[SI] = uu; oo += uu*Rv.F; \
    float pp = p[SI]*E.F + sp*Bv.F;           p[SI] = pp; zz += pp*Rv.F; }
  UPD(0,ew0,kv0,bb0,rr0,x) UPD(1,ew0,kv0,bb0,rr0,y) UPD(2,ew0,kv0,bb0,rr0,z) UPD(3,ew0,kv0,bb0,rr0,w)
  UPD(4,ew1,kv1,bb1,rr1,x) UPD(5,ew1,kv1,bb1,rr1,y) UPD(6,ew1,kv1,bb1,rr1,z) UPD(7,ew1,kv1,bb1,rr1,w)
#undef UPD
  oo += __shfl_xor(oo, 1); oo += __shfl_xor(oo, 2); oo += __shfl_xor(oo, 4);
  zz += __shfl_xor(zz, 1); zz += __shfl_xor(zz, 2); zz += __shfl_xor(zz, 4);
  if (q == 0) { o0A[base + i] = oo; zA[base + i] = zz; }
}

__global__ __launch_bounds__(512) void k_scan_p1(
    const float* __restrict__ rA, const float* __restrict__ ewA,
    const float* __restrict__ kA, const float* __restrict__ vA,
    const float* __restrict__ kkA, const float* __restrict__ bbA,
    float* __restrict__ o0A, float* __restrict__ zA,
    float* __restrict__ UcA, float* __restrict__ PTcA)
{
  const int blk = blockIdx.x;
  const int bh = blk & 31, c = blk >> 5;
  const int b = bh >> 4, h = bh & 15;
  const int tid = threadIdx.x;
  const int i = tid >> 3, q = tid & 7, j0 = q * 8;
  const size_t base0 = (size_t)b*2048*1024 + (size_t)h*64 + (size_t)(c*64)*1024;

  __shared__ __align__(16) float smem[4160];   // staging 2*1536; tail transpose [64][65]

  const int active = (tid < 384);
  const int a0 = tid >> 6, rm0 = tid & 63, s0 = rm0 >> 4, f40 = rm0 & 15;
  const float* pa0 = (a0==0) ? ewA : (a0==1) ? kkA : (a0==2) ? bbA :
                     (a0==3) ? kA  : (a0==4) ? rA  : vA;
  const float* src0 = pa0 + base0 + (size_t)s0*1024 + f40*4;
  const int dst0 = a0*256 + s0*64 + f40*4;

  float u[8], p[8];
#pragma unroll
  for (int jj = 0; jj < 8; ++jj) { u[jj] = 0.f; p[jj] = (j0 + jj == i) ? 1.f : 0.f; }

  if (active) *(float4*)&smem[dst0] = *(const float4*)(src0);
  __syncthreads();

  int curb = 0;
  for (int g = 0; g < 16; ++g) {
    float4 n0;
    if (g < 15 && active) n0 = *(const float4*)(src0 + (size_t)(g+1)*4096);
    const float* sb = smem + curb*1536;
#pragma unroll
    for (int s = 0; s < 4; ++s)
      step_lds(sb, s, u, p, o0A, zA, base0 + (size_t)(g*4 + s)*1024, i, q, j0);
    if (g < 15 && active) *(float4*)&smem[(curb^1)*1536 + dst0] = n0;
    __syncthreads();
    curb ^= 1;
  }

  const size_t cbase = ((size_t)(bh*32 + c)) * 4096;
  *(float4*)(UcA + cbase + (size_t)i*64 + j0)     = make_float4(u[0],u[1],u[2],u[3]);
  *(float4*)(UcA + cbase + (size_t)i*64 + j0 + 4) = make_float4(u[4],u[5],u[6],u[7]);
  float (*lds)[65] = (float(*)[65])smem;
#pragma unroll
  for (int jj = 0; jj < 8; ++jj) lds[i][j0 + jj] = p[jj];
  __syncthreads();
  float4 w0 = make_float4(lds[j0+0][i], lds[j0+1][i], lds[j0+2][i], lds[j0+3][i]);
  float4 w1 = make_float4(lds[j0+4][i], lds[j0+5][i], lds[j0+6][i], lds[j0+7][i]);
  *(float4*)(PTcA + cbase + (size_t)i*64 + j0)     = w0;
  *(float4*)(PTcA + cbase + (size_t)i*64 + j0 + 4) = w1;
}

//==================== 6b. chain: S_{c+1} = U_c + S_c @ P_c, store S0_c ====================
__device__ __forceinline__ void chain_body(int c, int bh, int w, int lr, int lq,
    float (&Slds)[64][65], f32x4 (&acc)[4],
    float (&u_c)[4][4], float4 (&p_c)[2][2],
    float (&u_n)[4][4], float4 (&p_n)[2][2],
    const float* __restrict__ UcA, const float* __restrict__ PTcA,
    float* __restrict__ S0A)
{
  const size_t s0base = ((size_t)bh*32 + c) * 4096;
#pragma unroll
  for (int mt = 0; mt < 4; ++mt)
#pragma unroll
    for (int rg = 0; rg < 4; ++rg) {
      Slds[mt*16 + lq*4 + rg][w*16 + lr] = acc[mt][rg];
      if (c > 0) S0A[s0base + (size_t)(mt*16 + lq*4 + rg)*64 + w*16 + lr] = acc[mt][rg];
    }
  __syncthreads();
  if (c + 1 < 32) {
    const size_t nbase = ((size_t)bh*32 + c + 1) * 4096;
#pragma unroll
    for (int mt = 0; mt < 4; ++mt)
#pragma unroll
      for (int rg = 0; rg < 4; ++rg)
        u_n[mt][rg] = UcA[nbase + (size_t)(mt*16 + lq*4 + rg)*64 + w*16 + lr];
#pragma unroll
    for (int kt = 0; kt < 2; ++kt)
#pragma unroll
      for (int hh = 0; hh < 2; ++hh)
        p_n[kt][hh] = *(const float4*)(PTcA + nbase + (size_t)(w*16 + lr)*64 + kt*32 + lq*8 + hh*4);
  }
  short8 pbh[2], pbl[2];
#pragma unroll
  for (int kt = 0; kt < 2; ++kt) {
    float f[8] = {p_c[kt][0].x, p_c[kt][0].y, p_c[kt][0].z, p_c[kt][0].w,
                  p_c[kt][1].x, p_c[kt][1].y, p_c[kt][1].z, p_c[kt][1].w};
    split8(f, pbh[kt], pbl[kt]);
  }
  f32x4 nacc[4];
#pragma unroll
  for (int mt = 0; mt < 4; ++mt) {
    f32x4 z = {u_c[mt][0], u_c[mt][1], u_c[mt][2], u_c[mt][3]};
    nacc[mt] = z;
  }
#pragma unroll
  for (int kt = 0; kt < 2; ++kt)
#pragma unroll
    for (int mt = 0; mt < 4; ++mt) {
      float f[8];
#pragma unroll
      for (int e = 0; e < 8; ++e) f[e] = Slds[mt*16 + lr][kt*32 + lq*8 + e];
      short8 sah, sal;
      split8(f, sah, sal);
      nacc[mt] = __builtin_amdgcn_mfma_f32_16x16x32_bf16(sah, pbh[kt], nacc[mt], 0, 0, 0);
      nacc[mt] = __builtin_amdgcn_mfma_f32_16x16x32_bf16(sal, pbh[kt], nacc[mt], 0, 0, 0);
      nacc[mt] = __builtin_amdgcn_mfma_f32_16x16x32_bf16(sah, pbl[kt], nacc[mt], 0, 0, 0);
    }
#pragma unroll
  for (int mt = 0; mt < 4; ++mt) acc[mt] = nacc[mt];
  __syncthreads();
}

__global__ __launch_bounds__(256) void k_chain(
    const float* __restrict__ UcA, const float* __restrict__ PTcA,
    float* __restrict__ S0A)
{
  const int bh = blockIdx.x;
  const int l = threadIdx.x & 63, w = threadIdx.x >> 6;
  const int lr = l & 15, lq = l >> 4;
  __shared__ float Slds[64][65];

  f32x4 acc[4];
#pragma unroll
  for (int mt = 0; mt < 4; ++mt) { f32x4 z = {0.f,0.f,0.f,0.f}; acc[mt] = z; }

  float u0[4][4], u1[4][4];
  float4 p0[2][2], p1[2][2];
  {
    const size_t cbase = (size_t)bh * 32 * 4096;
#pragma unroll
    for (int mt = 0; mt < 4; ++mt)
#pragma unroll
      for (int rg = 0; rg < 4; ++rg)
        u0[mt][rg] = UcA[cbase + (size_t)(mt*16 + lq*4 + rg)*64 + w*16 + lr];
#pragma unroll
    for (int kt = 0; kt < 2; ++kt)
#pragma unroll
      for (int hh = 0; hh < 2; ++hh)
        p0[kt][hh] = *(const float4*)(PTcA + cbase + (size_t)(w*16 + lr)*64 + kt*32 + lq*8 + hh*4);
  }
  for (int c = 0; c < 32; c += 2) {
    chain_body(c,     bh, w, lr, lq, Slds, acc, u0, p0, u1, p1, UcA, PTcA, S0A);
    chain_body(c + 1, bh, w, lr, lq, Slds, acc, u1, p1, u0, p0, UcA, PTcA, S0A);
  }
}

//==================== 6c. fused correction + GroupNorm + bonus + gate ====================
// 1024 blocks = chunk*32 + bh; 4 waves; wave w owns rows tl in [w*16, w*16+16).
// o = o0 + Z_c @ S0_c^T (c>0), then per-head GroupNorm, bonus, gate -> packed y.
__global__ __launch_bounds__(256) void k_corrpost(
    const float* __restrict__ S0A, const float* __restrict__ zA,
    const float* __restrict__ o0A, const float* __restrict__ rA,
    const float* __restrict__ kA, const float* __restrict__ vA,
    const float* __restrict__ rk, const float* __restrict__ gnw,
    const float* __restrict__ gnb, const float* __restrict__ gA,
    us* __restrict__ yPk)
{
  const int blk = blockIdx.x;
  const int bh = blk & 31;
  const int c  = blk >> 5;               // 0..31
  const int b = bh >> 4, h = bh & 15;
  const int l = threadIdx.x & 63, w = threadIdx.x >> 6;
  const int lr = l & 15, lq = l >> 4;

  f32x4 a2[4];
#pragma unroll
  for (int nt = 0; nt < 4; ++nt) { f32x4 z = {0.f,0.f,0.f,0.f}; a2[nt] = z; }

  if (c > 0) {
    const size_t s0base = ((size_t)bh*32 + c) * 4096;
    short8 sbh[4][2], sbl[4][2];
#pragma unroll
    for (int nt = 0; nt < 4; ++nt)
#pragma unroll
      for (int kt = 0; kt < 2; ++kt) {
        float f[8];
#pragma unroll
        for (int e = 0; e < 8; ++e)
          f[e] = S0A[s0base + (size_t)(nt*16 + lr)*64 + kt*32 + lq*8 + e];
        split8(f, sbh[nt][kt], sbl[nt][kt]);
      }
    short8 zh[2], zl[2];
#pragma unroll
    for (int kt = 0; kt < 2; ++kt) {
      const float* zp = zA + ((size_t)(b*2048 + c*64 + w*16 + lr)*16 + h)*64 + kt*32 + lq*8;
      float f[8];
#pragma unroll
      for (int e = 0; e < 8; ++e) f[e] = zp[e];
      split8(f, zh[kt], zl[kt]);
    }
#pragma unroll
    for (int kt = 0; kt < 2; ++kt)
#pragma unroll
      for (int nt = 0; nt < 4; ++nt) {
        a2[nt] = __builtin_amdgcn_mfma_f32_16x16x32_bf16(zh[kt], sbh[nt][kt], a2[nt], 0, 0, 0);
        a2[nt] = __builtin_amdgcn_mfma_f32_16x16x32_bf16(zl[kt], sbh[nt][kt], a2[nt], 0, 0, 0);
        a2[nt] = __builtin_amdgcn_mfma_f32_16x16x32_bf16(zh[kt], sbl[nt][kt], a2[nt], 0, 0, 0);
      }
  }

#pragma unroll
  for (int rg = 0; rg < 4; ++rg) {
    const int tl = w*16 + lq*4 + rg;
    const size_t trow = (size_t)(b*2048 + c*64 + tl);
    const size_t rb = trow*1024 + h*64;
    float o4[4], v4[4];
    float sum = 0.f, pr = 0.f;
#pragma unroll
    for (int nt = 0; nt < 4; ++nt) {
      const int ii = nt*16 + lr;
      float o = o0A[rb + ii] + a2[nt][rg];
      o4[nt] = o; sum += o;
      v4[nt] = vA[rb + ii];
      pr += rA[rb + ii] * kA[rb + ii] * rk[h*64 + ii];
    }
    sum += __shfl_xor(sum,1); sum += __shfl_xor(sum,2);
    sum += __shfl_xor(sum,4); sum += __shfl_xor(sum,8);
    pr  += __shfl_xor(pr,1);  pr  += __shfl_xor(pr,2);
    pr  += __shfl_xor(pr,4);  pr  += __shfl_xor(pr,8);
    float mean = sum * (1.f/64.f);
    float vp = 0.f;
#pragma unroll
    for (int nt = 0; nt < 4; ++nt) { float d = o4[nt]-mean; vp += d*d; }
    vp += __shfl_xor(vp,1); vp += __shfl_xor(vp,2);
    vp += __shfl_xor(vp,4); vp += __shfl_xor(vp,8);
    float inv = rsqrtf(vp*(1.f/64.f) + 1e-5f);
#pragma unroll
    for (int nt = 0; nt < 4; ++nt) {
      const int ii = nt*16 + lr;
      const int ch = h*64 + ii;
      float y = (o4[nt]-mean)*inv*gnw[ch] + gnb[ch];
      y = fmaf(pr, v4[nt], y);
      y *= gA[rb + ii];
      us hh, ll;
      split1(y, hh, ll);
      yPk[trow*2048 + ch]        = hh;
      yPk[trow*2048 + 1024 + ch] = ll;
    }
  }
}

//==================== host ====================
extern "C" void kernel_launch(void* const* d_in, const int* in_sizes, int n_in,
                              void* d_out, int out_size, void* d_ws, size_t ws_size,
                              hipStream_t stream)
{
  (void)in_sizes; (void)n_in; (void)out_size; (void)ws_size;
  const float* hs     = (const float*)d_in[0];
  const float* x_r    = (const float*)d_in[1];
  const float* x_w    = (const float*)d_in[2];
  const float* x_k    = (const float*)d_in[3];
  const float* x_v    = (const float*)d_in[4];
  const float* x_a    = (const float*)d_in[5];
  const float* k_k    = (const float*)d_in[7];
  const float* k_a    = (const float*)d_in[8];
  const float* r_k    = (const float*)d_in[9];
  const float* W_r    = (const float*)d_in[10];
  const float* W_k    = (const float*)d_in[11];
  const float* W_v    = (const float*)d_in[12];
  const float* W_o    = (const float*)d_in[13];
  const float* wla    = (const float*)d_in[14];
  const float* wlb    = (const float*)d_in[15];
  const float* wlbias = (const float*)d_in[16];
  const float* ala    = (const float*)d_in[17];
  const float* alb    = (const float*)d_in[18];
  const float* albias = (const float*)d_in[19];
  const float* gla    = (const float*)d_in[20];
  const float* glb    = (const float*)d_in[21];
  const float* glbias = (const float*)d_in[22];
  const float* gnw    = (const float*)d_in[23];
  const float* gnb    = (const float*)d_in[24];

  char* ws = (char*)d_ws;
  size_t cur = 0;
  auto take = [&](size_t bytes) { size_t o = cur; cur += (bytes + 255) & ~(size_t)255; return o; };

  us* xr_aug = (us*)(ws + take((size_t)4096*2048*2));
  us* xw_aug = (us*)(ws + take((size_t)4096*2048*2));
  us* xk_aug = (us*)(ws + take((size_t)4096*2048*2));
  us* xv_aug = (us*)(ws + take((size_t)4096*2048*2));
  us* xa_aug = (us*)(ws + take((size_t)4096*2048*2));
  us* Wr_p  = (us*)(ws + take((size_t)1024*2048*2));
  us* Wk_p  = (us*)(ws + take((size_t)1024*2048*2));
  us* Wv_p  = (us*)(ws + take((size_t)1024*2048*2));
  us* Wo_p  = (us*)(ws + take((size_t)1024*2048*2));
  us* wla_p = (us*)(ws + take((size_t)128*2048*2));
  us* wlb_p = (us*)(ws + take((size_t)1024*128*2));
  us* ala_p = (us*)(ws + take((size_t)128*2048*2));
  us* alb_p = (us*)(ws + take((size_t)1024*128*2));
  us* gla_p = (us*)(ws + take((size_t)128*2048*2));
  us* glb_p = (us*)(ws + take((size_t)1024*256*2));
  us* raug  = (us*)(ws + take((size_t)4096*2048*2));
  us* t2w   = (us*)(ws + take((size_t)4096*128*2));
  us* t2a   = (us*)(ws + take((size_t)4096*128*2));
  us* t2g   = (us*)(ws + take((size_t)4096*256*2));
  float* r_f  = (float*)(ws + take((size_t)4096*1024*4));
  float* k_f  = (float*)(ws + take((size_t)4096*1024*4));
  float* v_f  = (float*)(ws + take((size_t)4096*1024*4));
  float* z_f  = (float*)(ws + take((size_t)4096*1024*4));
  float* Uc_f = (float*)(ws + take((size_t)4096*1024*4));
  float* PT_f = (float*)(ws + take((size_t)4096*1024*4));
  // aliases (lifetime-checked against launch order):
  float* kk_f = (float*)xr_aug;   // xr_aug dead after L2; kk written L5, read L6
  float* ew_f = (float*)xw_aug;   // xw_aug dead after L2 (w-s1); ew written L3, read L6
  float* a_f  = (float*)xa_aug;   // xa_aug dead after L2 (a-s1); a written L3, read L5/L6
  float* g_f  = (float*)raug;     // raug dead after L3 (g-s1); g written L4, read L8
  float* S0_f = (float*)xk_aug;   // xk_aug dead after L2 (k); S0 written L7, read L8
  us*    yaug = xw_aug;           // ew dead after L6; y written L8, read L9
  float* oF   = (float*)d_out;    // o0 lives in d_out until L9 overwrites

  // L1: prep (packs 5 operands)
  k_prep<<<4096, 256, 0, stream>>>(hs, x_r, x_w, x_k, x_v, x_a,
                                   xr_aug, xw_aug, xk_aug, xv_aug, xa_aug);
  // L1b: weight transpose+pack
  SrcP sp; DstP dp;
  sp.p[0]=W_r; sp.p[1]=W_k; sp.p[2]=W_v; sp.p[3]=W_o;
  sp.p[4]=wla; sp.p[5]=wlb; sp.p[6]=ala; sp.p[7]=alb; sp.p[8]=gla; sp.p[9]=glb;
  dp.p[0]=Wr_p; dp.p[1]=Wk_p; dp.p[2]=Wv_p; dp.p[3]=Wo_p;
  dp.p[4]=wla_p; dp.p[5]=wlb_p; dp.p[6]=ala_p; dp.p[7]=alb_p; dp.p[8]=gla_p; dp.p[9]=glb_p;
  k_transpose<<<dim3(32,32,10), dim3(32,8), 0, stream>>>(sp, dp);

  GJobs J{};
  auto job = [](const us* A, const us* Bt, float* C, us* Cpk, const float* bias,
                int K, int N, int Npk, int ldc, int act, int lda, int ldb, int t3) {
    GJob j; j.A=A; j.Bt=Bt; j.C=C; j.Cpk=Cpk; j.bias=bias;
    j.K=K; j.N=N; j.Npk=Npk; j.ldc=ldc; j.act=act; j.lda=lda; j.ldb=ldb; j.terms3=t3;
    return j;
  };

  // L2: r(3,+pack), k(3), v(3), w-s1(3,tanh,pack), a-s1(3,pack)
  J.j[0] = job(xr_aug, Wr_p,  r_f, raug,    nullptr, 1024, 1024, 1024, 1024, 0, 2048, 2048, 1);
  J.j[1] = job(xk_aug, Wk_p,  k_f, nullptr, nullptr, 1024, 1024, 0,    1024, 0, 2048, 2048, 1);
  J.j[2] = job(xv_aug, Wv_p,  v_f, nullptr, nullptr, 1024, 1024, 0,    1024, 0, 2048, 2048, 1);
  J.j[3] = job(xw_aug, wla_p, nullptr, t2w, nullptr, 1024, 128,  64,   0,    2, 2048, 2048, 1);
  J.j[4] = job(xa_aug, ala_p, nullptr, t2a, nullptr, 1024, 128,  64,   0,    0, 2048, 2048, 1);
  k_gemm_bf<<<dim3(32,8,5), 256, 0, stream>>>(J);

  // L3: w-s2 (ew), a-s2 (sigmoid), g-s1 (sigmoid, pack)
  J = GJobs{};
  J.j[0] = job(t2w,  wlb_p, ew_f, nullptr, wlbias, 64,  1024, 0,   1024, 3, 128,  128, 1);
  J.j[1] = job(t2a,  alb_p, a_f,  nullptr, albias, 64,  1024, 0,   1024, 1, 128,  128, 1);
  J.j[2] = job(raug, gla_p, nullptr, t2g,  nullptr, 1024, 128, 128, 0,    1, 2048, 2048, 1);
  k_gemm_bf<<<dim3(32,8,3), 256, 0, stream>>>(J);

  // L4: g-s2 (+bias)
  J = GJobs{};
  J.j[0] = job(t2g, glb_p, g_f, nullptr, glbias, 128, 1024, 0, 1024, 0, 256, 256, 1);
  k_gemm_bf<<<dim3(32,8,1), 256, 0, stream>>>(J);

  // L5: kk normalize + k update + b precompute
  k_scanprep<<<16384, 256, 0, stream>>>(k_f, a_f, k_k, k_a, kk_f);

  // L6-L7: chunked scan
  k_scan_p1<<<1024, 512, 0, stream>>>(r_f, ew_f, k_f, v_f, kk_f, a_f, oF, z_f, Uc_f, PT_f);
  k_chain<<<32, 256, 0, stream>>>(Uc_f, PT_f, S0_f);

  // L8: fused correction + groupnorm + bonus + gate -> packed y
  k_corrpost<<<1024, 256, 0, stream>>>(S0_f, z_f, oF, r_f, k_f, v_f,
                                       r_k, gnw, gnb, g_f, yaug);

  // L9: output projection (3-term, overwrites d_out)
  J = GJobs{};
  J.j[0] = job(yaug, Wo_p, (float*)d_out, nullptr, nullptr, 1024, 1024, 0, 1024, 0, 2048, 2048, 1);
  k_gemm_bf<<<dim3(32,8,1), 256, 0, stream>>>(J);
}

// Round 10
// 391.800 us; speedup vs baseline: 1.2957x; 1.2957x over previous
//
#include <hip/hip_runtime.h>
#include <hip/hip_bf16.h>
#include <hip/hip_fp16.h>
#include <stdint.h>
#include <stddef.h>

typedef __hip_bfloat16 bf16;
typedef _Float16 f16;
typedef __attribute__((ext_vector_type(8))) short short8;
typedef __attribute__((ext_vector_type(8))) _Float16 half8;
typedef __attribute__((ext_vector_type(4))) float f32x4;
typedef unsigned short us;

__device__ __forceinline__ float dsigm(float z){ return 1.f/(1.f+expf(-z)); }

// split fp32 -> hi (rounded bf16) + lo (rounded bf16 residual); used by scan-side MFMA only
__device__ __forceinline__ void split1(float v, us& h, us& l) {
  bf16 hb = __float2bfloat16(v);
  h = __builtin_bit_cast(us, hb);
  float hf = __bfloat162float(hb);
  bf16 lb = __float2bfloat16(v - hf);
  l = __builtin_bit_cast(us, lb);
}

__device__ __forceinline__ void split8(const float* f, short8& h, short8& l) {
#pragma unroll
  for (int e = 0; e < 8; ++e) {
    us hh, ll;
    split1(f[e], hh, ll);
    h[e] = (short)hh; l[e] = (short)ll;
  }
}

// async global->LDS, 16B per lane (dest = wave-uniform base + lane*16)
__device__ __forceinline__ void gl16(const f16* g, f16* l) {
  __builtin_amdgcn_global_load_lds((const __attribute__((address_space(1))) void*)g,
                                   (__attribute__((address_space(3))) void*)l, 16, 0, 0);
}

//==================== 1. time-shift lerp -> fp16 operands ====================
__device__ __forceinline__ void emit16(const float* __restrict__ marr, int c4,
    const float4& cur, const float4& dlt, f16* __restrict__ out, int row)
{
  float4 m = *(const float4*)(marr + c4);
  f16* o = out + (size_t)row*1024 + c4;
  o[0] = (f16)fmaf(dlt.x, m.x, cur.x);
  o[1] = (f16)fmaf(dlt.y, m.y, cur.y);
  o[2] = (f16)fmaf(dlt.z, m.z, cur.z);
  o[3] = (f16)fmaf(dlt.w, m.w, cur.w);
}

__global__ void k_prep(const float* __restrict__ hs,
    const float* __restrict__ mr, const float* __restrict__ mw, const float* __restrict__ mk,
    const float* __restrict__ mv, const float* __restrict__ ma,
    f16* __restrict__ oxr, f16* __restrict__ oxw, f16* __restrict__ oxk,
    f16* __restrict__ oxv, f16* __restrict__ oxa)
{
  int id = blockIdx.x * 256 + threadIdx.x;
  int row = id >> 8;
  int c4 = (id & 255) << 2;
  int t = row & 2047;
  const float* hp = hs + (size_t)row*1024 + c4;
  float4 cur = *(const float4*)hp;
  float4 prev = make_float4(0.f,0.f,0.f,0.f);
  if (t > 0) prev = *(const float4*)(hp - 1024);
  float4 dlt = make_float4(prev.x-cur.x, prev.y-cur.y, prev.z-cur.z, prev.w-cur.w);
  emit16(mr, c4, cur, dlt, oxr, row);
  emit16(mw, c4, cur, dlt, oxw, row);
  emit16(mk, c4, cur, dlt, oxk, row);
  emit16(mv, c4, cur, dlt, oxv, row);
  emit16(ma, c4, cur, dlt, oxa, row);
}

//==================== 2. weight transpose -> fp16 ====================
struct SrcP { const float* p[10]; };
struct DstP { f16* p[10]; };

__global__ void k_transpose(SrcP S, DstP Dd)
{
  static constexpr int TR[10]  = {1024,1024,1024,1024,1024,  64,1024,  64,1024, 128};
  static constexpr int TCC[10] = {1024,1024,1024,1024,  64,1024,  64,1024, 128,1024};
  static constexpr int TCP[10] = {1024,1024,1024,1024, 128,1024, 128,1024, 128,1024};
  int z = blockIdx.z;
  int R = TR[z], Cc = TCC[z], Cp = TCP[z];
  int n0 = blockIdx.x * 32, r0 = blockIdx.y * 32;
  if (n0 >= Cp || r0 >= R) return;
  const float* src = S.p[z];
  f16* dst = Dd.p[z];
  int tx = threadIdx.x, ty = threadIdx.y;
  __shared__ float tile[32][33];
  if (n0 < Cc) {
#pragma unroll
    for (int i = 0; i < 4; ++i)
      tile[ty + 8*i][tx] = src[(size_t)(r0 + ty + 8*i)*Cc + n0 + tx];
    __syncthreads();
#pragma unroll
    for (int i = 0; i < 4; ++i)
      dst[(size_t)(n0 + ty + 8*i)*R + r0 + tx] = (f16)tile[tx][ty + 8*i];
  } else {
#pragma unroll
    for (int i = 0; i < 4; ++i)
      dst[(size_t)(n0 + ty + 8*i)*R + r0 + tx] = (f16)0.f;
  }
}

//==================== 3. batched fp16 MFMA GEMM ====================
// C[M][N] = A[M][K] * Bt[N][K]^T, fp16 inputs, fp32 accumulate.
// tile 128x128, BK=32, 4 waves, global_load_lds staging, 2 barriers / 16 MFMA per K-step.
struct GJob {
  const f16* A;              // [4096][lda]
  const f16* Bt;             // [N][ldb]
  float* C;                  // optional fp32 out [4096][ldc]
  f16* Cpk;                  // optional fp16 out [4096][Npk]
  const float* bias;         // optional per-col (added before act)
  int K; int N; int Npk; int ldc; int act;   // act: 0 none, 1 sigmoid, 2 tanh, 3 e^-.5*sigmoid
  int lda; int ldb;
};
struct GJobs { GJob j[5]; };

__global__ __launch_bounds__(256) void k_gemm_fp16(GJobs jobs)
{
  GJob jb = jobs.j[blockIdx.z];
  const int colBase = blockIdx.y * 128;
  if (colBase >= jb.N) return;
  const int rowBase = blockIdx.x * 128;
  __shared__ __align__(16) f16 As[128*32];
  __shared__ __align__(16) f16 Bs[128*32];
  const int tid = threadIdx.x;
  const int l = tid & 63, w = tid >> 6;
  const int wm = w >> 1, wn = w & 1;
  const int lrow = l & 15, kid = (l >> 4) * 8;
  const int nk = jb.K >> 5;

  // staging geometry: call i (0,1): slot s=(i*4+w)*64+l; row=s>>2, col-oct=(s&3)*8
  const int s0 = w*64 + l, s1 = (4 + w)*64 + l;
  const int ar0 = s0 >> 2, ac0 = (s0 & 3) * 8;
  const int ar1 = s1 >> 2, ac1 = (s1 & 3) * 8;
  const int ld0 = w*512, ld1 = (4 + w)*512;
  const f16* Arow0 = jb.A  + (size_t)(rowBase + ar0)*jb.lda + ac0;
  const f16* Arow1 = jb.A  + (size_t)(rowBase + ar1)*jb.lda + ac1;
  const f16* Brow0 = jb.Bt + (size_t)(colBase + ar0)*jb.ldb + ac0;
  const f16* Brow1 = jb.Bt + (size_t)(colBase + ar1)*jb.ldb + ac1;

  f32x4 acc[4][4];
#pragma unroll
  for (int i = 0; i < 4; ++i)
#pragma unroll
    for (int j = 0; j < 4; ++j) { f32x4 z = {0.f,0.f,0.f,0.f}; acc[i][j] = z; }

  for (int kt = 0; kt < nk; ++kt) {
    const int kh = kt*32;
    gl16(Arow0 + kh, &As[ld0]);  gl16(Arow1 + kh, &As[ld1]);
    gl16(Brow0 + kh, &Bs[ld0]);  gl16(Brow1 + kh, &Bs[ld1]);
    __syncthreads();
    half8 ah[4], bh[4];
#pragma unroll
    for (int mt = 0; mt < 4; ++mt) ah[mt] = *(const half8*)&As[(wm*64 + mt*16 + lrow)*32 + kid];
#pragma unroll
    for (int nt = 0; nt < 4; ++nt) bh[nt] = *(const half8*)&Bs[(wn*64 + nt*16 + lrow)*32 + kid];
#pragma unroll
    for (int mt = 0; mt < 4; ++mt)
#pragma unroll
      for (int nt = 0; nt < 4; ++nt)
        acc[mt][nt] = __builtin_amdgcn_mfma_f32_16x16x32_f16(ah[mt], bh[nt], acc[mt][nt], 0, 0, 0);
    __syncthreads();
  }
#pragma unroll
  for (int mt = 0; mt < 4; ++mt) {
    int row = rowBase + wm*64 + mt*16 + (l >> 4)*4;
#pragma unroll
    for (int nt = 0; nt < 4; ++nt) {
      int col = colBase + wn*64 + nt*16 + (l & 15);
      float bv = (jb.bias != nullptr) ? jb.bias[col] : 0.f;
#pragma unroll
      for (int rg = 0; rg < 4; ++rg) {
        float v = acc[mt][nt][rg] + bv;
        if (jb.act == 1)      v = dsigm(v);
        else if (jb.act == 2) v = tanhf(v);
        else if (jb.act == 3) v = 0.60653066f * dsigm(v);
        if (jb.C) jb.C[(size_t)(row + rg)*jb.ldc + col] = v;
        if (jb.Cpk && col < jb.Npk)
          jb.Cpk[(size_t)(row + rg)*jb.Npk + col] = (f16)v;
      }
    }
  }
}

//==================== 5. scan prep: kk normalize + k update + b=kk*a ====================
__global__ void k_scanprep(float* __restrict__ kA, float* __restrict__ aA,
                           const float* __restrict__ kkw, const float* __restrict__ kaw,
                           float* __restrict__ kkA)
{
  size_t gt = (size_t)blockIdx.x * 256u + threadIdx.x;
  int d = (int)(gt & 63);
  size_t flat = gt >> 6;
  int c = (int)((flat & 15) * 64 + d);
  float k0 = kA[gt], av = aA[gt];
  float kkv = k0 * kkw[c];
  float ss = kkv * kkv;
  ss += __shfl_xor(ss, 1);  ss += __shfl_xor(ss, 2);  ss += __shfl_xor(ss, 4);
  ss += __shfl_xor(ss, 8);  ss += __shfl_xor(ss, 16); ss += __shfl_xor(ss, 32);
  float inv = 1.f / fmaxf(sqrtf(ss), 1e-12f);
  float kkn = kkv * inv;
  kkA[gt] = kkn;
  aA[gt]  = kkn * av;
  kA[gt]  = k0 * fmaf(av - 1.f, kaw[c], 1.f);
}

//==================== 6a. chunked scan pass 1 (LDS-staged, 4-step groups) ====================
#define SP1_EW 0
#define SP1_KK 256
#define SP1_BB 512
#define SP1_KV 768
#define SP1_RR 1024
#define SP1_VV 1280

__device__ __forceinline__ void step_lds(const float* __restrict__ sb, int s,
    float* u, float* p, float* __restrict__ o0A, float* __restrict__ zA,
    size_t base, int i, int q, int j0)
{
  float4 ew0 = *(const float4*)(sb + SP1_EW + s*64 + j0);
  float4 ew1 = *(const float4*)(sb + SP1_EW + s*64 + j0 + 4);
  float4 kk0 = *(const float4*)(sb + SP1_KK + s*64 + j0);
  float4 kk1 = *(const float4*)(sb + SP1_KK + s*64 + j0 + 4);
  float4 bb0 = *(const float4*)(sb + SP1_BB + s*64 + j0);
  float4 bb1 = *(const float4*)(sb + SP1_BB + s*64 + j0 + 4);
  float4 kv0 = *(const float4*)(sb + SP1_KV + s*64 + j0);
  float4 kv1 = *(const float4*)(sb + SP1_KV + s*64 + j0 + 4);
  float4 rr0 = *(const float4*)(sb + SP1_RR + s*64 + j0);
  float4 rr1 = *(const float4*)(sb + SP1_RR + s*64 + j0 + 4);
  float vi = sb[SP1_VV + s*64 + i];

  float uk = 0.f, pk = 0.f;
#define RED(SI, V, F) { uk += u[SI]*V.F; pk += p[SI]*V.F; }
  RED(0,kk0,x) RED(1,kk0,y) RED(2,kk0,z) RED(3,kk0,w)
  RED(4,kk1,x) RED(5,kk1,y) RED(6,kk1,z) RED(7,kk1,w)
#undef RED
  uk += __shfl_xor(uk, 1); uk += __shfl_xor(uk, 2); uk += __shfl_xor(uk, 4);
  pk += __shfl_xor(pk, 1); pk += __shfl_xor(pk, 2); pk += __shfl_xor(pk, 4);
  const float su = -uk, sp = -pk;
  float oo = 0.f, zz = 0.f;
#define UPD(SI, E, Kv, Bv, Rv, F) { \
    float uu = u[SI]*E.F + su*Bv.F + vi*Kv.F; u[SI] = uu; oo += uu*Rv.F; \
    float pp = p[SI]*E.F + sp*Bv.F;           p[SI] = pp; zz += pp*Rv.F; }
  UPD(0,ew0,kv0,bb0,rr0,x) UPD(1,ew0,kv0,bb0,rr0,y) UPD(2,ew0,kv0,bb0,rr0,z) UPD(3,ew0,kv0,bb0,rr0,w)
  UPD(4,ew1,kv1,bb1,rr1,x) UPD(5,ew1,kv1,bb1,rr1,y) UPD(6,ew1,kv1,bb1,rr1,z) UPD(7,ew1,kv1,bb1,rr1,w)
#undef UPD
  oo += __shfl_xor(oo, 1); oo += __shfl_xor(oo, 2); oo += __shfl_xor(oo, 4);
  zz += __shfl_xor(zz, 1); zz += __shfl_xor(zz, 2); zz += __shfl_xor(zz, 4);
  if (q == 0) { o0A[base + i] = oo; zA[base + i] = zz; }
}

__global__ __launch_bounds__(512) void k_scan_p1(
    const float* __restrict__ rA, const float* __restrict__ ewA,
    const float* __restrict__ kA, const float* __restrict__ vA,
    const float* __restrict__ kkA, const float* __restrict__ bbA,
    float* __restrict__ o0A, float* __restrict__ zA,
    float* __restrict__ UcA, float* __restrict__ PTcA)
{
  const int blk = blockIdx.x;
  const int bh = blk & 31, c = blk >> 5;
  const int b = bh >> 4, h = bh & 15;
  const int tid = threadIdx.x;
  const int i = tid >> 3, q = tid & 7, j0 = q * 8;
  const size_t base0 = (size_t)b*2048*1024 + (size_t)h*64 + (size_t)(c*64)*1024;

  __shared__ __align__(16) float smem[4160];   // staging 2*1536; tail transpose [64][65]

  const int active = (tid < 384);
  const int a0 = tid >> 6, rm0 = tid & 63, s0 = rm0 >> 4, f40 = rm0 & 15;
  const float* pa0 = (a0==0) ? ewA : (a0==1) ? kkA : (a0==2) ? bbA :
                     (a0==3) ? kA  : (a0==4) ? rA  : vA;
  const float* src0 = pa0 + base0 + (size_t)s0*1024 + f40*4;
  const int dst0 = a0*256 + s0*64 + f40*4;

  float u[8], p[8];
#pragma unroll
  for (int jj = 0; jj < 8; ++jj) { u[jj] = 0.f; p[jj] = (j0 + jj == i) ? 1.f : 0.f; }

  if (active) *(float4*)&smem[dst0] = *(const float4*)(src0);
  __syncthreads();

  int curb = 0;
  for (int g = 0; g < 16; ++g) {
    float4 n0;
    if (g < 15 && active) n0 = *(const float4*)(src0 + (size_t)(g+1)*4096);
    const float* sb = smem + curb*1536;
#pragma unroll
    for (int s = 0; s < 4; ++s)
      step_lds(sb, s, u, p, o0A, zA, base0 + (size_t)(g*4 + s)*1024, i, q, j0);
    if (g < 15 && active) *(float4*)&smem[(curb^1)*1536 + dst0] = n0;
    __syncthreads();
    curb ^= 1;
  }

  const size_t cbase = ((size_t)(bh*32 + c)) * 4096;
  *(float4*)(UcA + cbase + (size_t)i*64 + j0)     = make_float4(u[0],u[1],u[2],u[3]);
  *(float4*)(UcA + cbase + (size_t)i*64 + j0 + 4) = make_float4(u[4],u[5],u[6],u[7]);
  float (*lds)[65] = (float(*)[65])smem;
#pragma unroll
  for (int jj = 0; jj < 8; ++jj) lds[i][j0 + jj] = p[jj];
  __syncthreads();
  float4 w0 = make_float4(lds[j0+0][i], lds[j0+1][i], lds[j0+2][i], lds[j0+3][i]);
  float4 w1 = make_float4(lds[j0+4][i], lds[j0+5][i], lds[j0+6][i], lds[j0+7][i]);
  *(float4*)(PTcA + cbase + (size_t)i*64 + j0)     = w0;
  *(float4*)(PTcA + cbase + (size_t)i*64 + j0 + 4) = w1;
}

//==================== 6b. chain: S_{c+1} = U_c + S_c @ P_c (split-bf16, fp32-grade) ====================
__device__ __forceinline__ void chain_body(int c, int bh, int w, int lr, int lq,
    float (&Slds)[64][65], f32x4 (&acc)[4],
    float (&u_c)[4][4], float4 (&p_c)[2][2],
    float (&u_n)[4][4], float4 (&p_n)[2][2],
    const float* __restrict__ UcA, const float* __restrict__ PTcA,
    float* __restrict__ S0A)
{
  const size_t s0base = ((size_t)bh*32 + c) * 4096;
#pragma unroll
  for (int mt = 0; mt < 4; ++mt)
#pragma unroll
    for (int rg = 0; rg < 4; ++rg) {
      Slds[mt*16 + lq*4 + rg][w*16 + lr] = acc[mt][rg];
      if (c > 0) S0A[s0base + (size_t)(mt*16 + lq*4 + rg)*64 + w*16 + lr] = acc[mt][rg];
    }
  __syncthreads();
  if (c + 1 < 32) {
    const size_t nbase = ((size_t)bh*32 + c + 1) * 4096;
#pragma unroll
    for (int mt = 0; mt < 4; ++mt)
#pragma unroll
      for (int rg = 0; rg < 4; ++rg)
        u_n[mt][rg] = UcA[nbase + (size_t)(mt*16 + lq*4 + rg)*64 + w*16 + lr];
#pragma unroll
    for (int kt = 0; kt < 2; ++kt)
#pragma unroll
      for (int hh = 0; hh < 2; ++hh)
        p_n[kt][hh] = *(const float4*)(PTcA + nbase + (size_t)(w*16 + lr)*64 + kt*32 + lq*8 + hh*4);
  }
  short8 pbh[2], pbl[2];
#pragma unroll
  for (int kt = 0; kt < 2; ++kt) {
    float f[8] = {p_c[kt][0].x, p_c[kt][0].y, p_c[kt][0].z, p_c[kt][0].w,
                  p_c[kt][1].x, p_c[kt][1].y, p_c[kt][1].z, p_c[kt][1].w};
    split8(f, pbh[kt], pbl[kt]);
  }
  f32x4 nacc[4];
#pragma unroll
  for (int mt = 0; mt < 4; ++mt) {
    f32x4 z = {u_c[mt][0], u_c[mt][1], u_c[mt][2], u_c[mt][3]};
    nacc[mt] = z;
  }
#pragma unroll
  for (int kt = 0; kt < 2; ++kt)
#pragma unroll
    for (int mt = 0; mt < 4; ++mt) {
      float f[8];
#pragma unroll
      for (int e = 0; e < 8; ++e) f[e] = Slds[mt*16 + lr][kt*32 + lq*8 + e];
      short8 sah, sal;
      split8(f, sah, sal);
      nacc[mt] = __builtin_amdgcn_mfma_f32_16x16x32_bf16(sah, pbh[kt], nacc[mt], 0, 0, 0);
      nacc[mt] = __builtin_amdgcn_mfma_f32_16x16x32_bf16(sal, pbh[kt], nacc[mt], 0, 0, 0);
      nacc[mt] = __builtin_amdgcn_mfma_f32_16x16x32_bf16(sah, pbl[kt], nacc[mt], 0, 0, 0);
    }
#pragma unroll
  for (int mt = 0; mt < 4; ++mt) acc[mt] = nacc[mt];
  __syncthreads();
}

__global__ __launch_bounds__(256) void k_chain(
    const float* __restrict__ UcA, const float* __restrict__ PTcA,
    float* __restrict__ S0A)
{
  const int bh = blockIdx.x;
  const int l = threadIdx.x & 63, w = threadIdx.x >> 6;
  const int lr = l & 15, lq = l >> 4;
  __shared__ float Slds[64][65];

  f32x4 acc[4];
#pragma unroll
  for (int mt = 0; mt < 4; ++mt) { f32x4 z = {0.f,0.f,0.f,0.f}; acc[mt] = z; }

  float u0[4][4], u1[4][4];
  float4 p0[2][2], p1[2][2];
  {
    const size_t cbase = (size_t)bh * 32 * 4096;
#pragma unroll
    for (int mt = 0; mt < 4; ++mt)
#pragma unroll
      for (int rg = 0; rg < 4; ++rg)
        u0[mt][rg] = UcA[cbase + (size_t)(mt*16 + lq*4 + rg)*64 + w*16 + lr];
#pragma unroll
    for (int kt = 0; kt < 2; ++kt)
#pragma unroll
      for (int hh = 0; hh < 2; ++hh)
        p0[kt][hh] = *(const float4*)(PTcA + cbase + (size_t)(w*16 + lr)*64 + kt*32 + lq*8 + hh*4);
  }
  for (int c = 0; c < 32; c += 2) {
    chain_body(c,     bh, w, lr, lq, Slds, acc, u0, p0, u1, p1, UcA, PTcA, S0A);
    chain_body(c + 1, bh, w, lr, lq, Slds, acc, u1, p1, u0, p0, UcA, PTcA, S0A);
  }
}

//==================== 6c. fused correction + GroupNorm + bonus + gate -> fp16 y ====================
__global__ __launch_bounds__(256) void k_corrpost(
    const float* __restrict__ S0A, const float* __restrict__ zA,
    const float* __restrict__ o0A, const float* __restrict__ rA,
    const float* __restrict__ kA, const float* __restrict__ vA,
    const float* __restrict__ rk, const float* __restrict__ gnw,
    const float* __restrict__ gnb, const float* __restrict__ gA,
    f16* __restrict__ yH)
{
  const int blk = blockIdx.x;
  const int bh = blk & 31;
  const int c  = blk >> 5;               // 0..31
  const int b = bh >> 4, h = bh & 15;
  const int l = threadIdx.x & 63, w = threadIdx.x >> 6;
  const int lr = l & 15, lq = l >> 4;

  f32x4 a2[4];
#pragma unroll
  for (int nt = 0; nt < 4; ++nt) { f32x4 z = {0.f,0.f,0.f,0.f}; a2[nt] = z; }

  if (c > 0) {
    const size_t s0base = ((size_t)bh*32 + c) * 4096;
    short8 sbh[4][2], sbl[4][2];
#pragma unroll
    for (int nt = 0; nt < 4; ++nt)
#pragma unroll
      for (int kt = 0; kt < 2; ++kt) {
        float f[8];
#pragma unroll
        for (int e = 0; e < 8; ++e)
          f[e] = S0A[s0base + (size_t)(nt*16 + lr)*64 + kt*32 + lq*8 + e];
        split8(f, sbh[nt][kt], sbl[nt][kt]);
      }
    short8 zh[2], zl[2];
#pragma unroll
    for (int kt = 0; kt < 2; ++kt) {
      const float* zp = zA + ((size_t)(b*2048 + c*64 + w*16 + lr)*16 + h)*64 + kt*32 + lq*8;
      float f[8];
#pragma unroll
      for (int e = 0; e < 8; ++e) f[e] = zp[e];
      split8(f, zh[kt], zl[kt]);
    }
#pragma unroll
    for (int kt = 0; kt < 2; ++kt)
#pragma unroll
      for (int nt = 0; nt < 4; ++nt) {
        a2[nt] = __builtin_amdgcn_mfma_f32_16x16x32_bf16(zh[kt], sbh[nt][kt], a2[nt], 0, 0, 0);
        a2[nt] = __builtin_amdgcn_mfma_f32_16x16x32_bf16(zl[kt], sbh[nt][kt], a2[nt], 0, 0, 0);
        a2[nt] = __builtin_amdgcn_mfma_f32_16x16x32_bf16(zh[kt], sbl[nt][kt], a2[nt], 0, 0, 0);
      }
  }

#pragma unroll
  for (int rg = 0; rg < 4; ++rg) {
    const int tl = w*16 + lq*4 + rg;
    const size_t trow = (size_t)(b*2048 + c*64 + tl);
    const size_t rb = trow*1024 + h*64;
    float o4[4], v4[4];
    float sum = 0.f, pr = 0.f;
#pragma unroll
    for (int nt = 0; nt < 4; ++nt) {
      const int ii = nt*16 + lr;
      float o = o0A[rb + ii] + a2[nt][rg];
      o4[nt] = o; sum += o;
      v4[nt] = vA[rb + ii];
      pr += rA[rb + ii] * kA[rb + ii] * rk[h*64 + ii];
    }
    sum += __shfl_xor(sum,1); sum += __shfl_xor(sum,2);
    sum += __shfl_xor(sum,4); sum += __shfl_xor(sum,8);
    pr  += __shfl_xor(pr,1);  pr  += __shfl_xor(pr,2);
    pr  += __shfl_xor(pr,4);  pr  += __shfl_xor(pr,8);
    float mean = sum * (1.f/64.f);
    float vp = 0.f;
#pragma unroll
    for (int nt = 0; nt < 4; ++nt) { float d = o4[nt]-mean; vp += d*d; }
    vp += __shfl_xor(vp,1); vp += __shfl_xor(vp,2);
    vp += __shfl_xor(vp,4); vp += __shfl_xor(vp,8);
    float inv = rsqrtf(vp*(1.f/64.f) + 1e-5f);
#pragma unroll
    for (int nt = 0; nt < 4; ++nt) {
      const int ii = nt*16 + lr;
      const int ch = h*64 + ii;
      float y = (o4[nt]-mean)*inv*gnw[ch] + gnb[ch];
      y = fmaf(pr, v4[nt], y);
      y *= gA[rb + ii];
      yH[trow*1024 + ch] = (f16)y;
    }
  }
}

//==================== host ====================
extern "C" void kernel_launch(void* const* d_in, const int* in_sizes, int n_in,
                              void* d_out, int out_size, void* d_ws, size_t ws_size,
                              hipStream_t stream)
{
  (void)in_sizes; (void)n_in; (void)out_size; (void)ws_size;
  const float* hs     = (const float*)d_in[0];
  const float* x_r    = (const float*)d_in[1];
  const float* x_w    = (const float*)d_in[2];
  const float* x_k    = (const float*)d_in[3];
  const float* x_v    = (const float*)d_in[4];
  const float* x_a    = (const float*)d_in[5];
  const float* k_k    = (const float*)d_in[7];
  const float* k_a    = (const float*)d_in[8];
  const float* r_k    = (const float*)d_in[9];
  const float* W_r    = (const float*)d_in[10];
  const float* W_k    = (const float*)d_in[11];
  const float* W_v    = (const float*)d_in[12];
  const float* W_o    = (const float*)d_in[13];
  const float* wla    = (const float*)d_in[14];
  const float* wlb    = (const float*)d_in[15];
  const float* wlbias = (const float*)d_in[16];
  const float* ala    = (const float*)d_in[17];
  const float* alb    = (const float*)d_in[18];
  const float* albias = (const float*)d_in[19];
  const float* gla    = (const float*)d_in[20];
  const float* glb    = (const float*)d_in[21];
  const float* glbias = (const float*)d_in[22];
  const float* gnw    = (const float*)d_in[23];
  const float* gnb    = (const float*)d_in[24];

  char* ws = (char*)d_ws;
  size_t cur = 0;
  auto take = [&](size_t bytes) { size_t o = cur; cur += (bytes + 255) & ~(size_t)255; return o; };

  // fp16 A operands [4096][1024] (8MB each)
  f16* xr_h = (f16*)(ws + take((size_t)4096*1024*2));
  f16* xw_h = (f16*)(ws + take((size_t)4096*1024*2));
  f16* xk_h = (f16*)(ws + take((size_t)4096*1024*2));
  f16* xv_h = (f16*)(ws + take((size_t)4096*1024*2));
  f16* xa_h = (f16*)(ws + take((size_t)4096*1024*2));
  // fp16 B operands (transposed weights)
  f16* Wr_p  = (f16*)(ws + take((size_t)1024*1024*2));
  f16* Wk_p  = (f16*)(ws + take((size_t)1024*1024*2));
  f16* Wv_p  = (f16*)(ws + take((size_t)1024*1024*2));
  f16* Wo_p  = (f16*)(ws + take((size_t)1024*1024*2));
  f16* wla_p = (f16*)(ws + take((size_t)128*1024*2));
  f16* wlb_p = (f16*)(ws + take((size_t)1024*64*2));
  f16* ala_p = (f16*)(ws + take((size_t)128*1024*2));
  f16* alb_p = (f16*)(ws + take((size_t)1024*64*2));
  f16* gla_p = (f16*)(ws + take((size_t)128*1024*2));
  f16* glb_p = (f16*)(ws + take((size_t)1024*128*2));
  // chained fp16 A operands
  f16* r_h  = (f16*)(ws + take((size_t)4096*1024*2));
  f16* t2w  = (f16*)(ws + take((size_t)4096*64*2));
  f16* t2a  = (f16*)(ws + take((size_t)4096*64*2));
  f16* t2g  = (f16*)(ws + take((size_t)4096*128*2));
  // fp32 buffers (16MB each)
  float* r_f  = (float*)(ws + take((size_t)4096*1024*4));
  float* k_f  = (float*)(ws + take((size_t)4096*1024*4));
  float* v_f  = (float*)(ws + take((size_t)4096*1024*4));
  float* kk_f = (float*)(ws + take((size_t)4096*1024*4));
  float* z_f  = (float*)(ws + take((size_t)4096*1024*4));
  float* Uc_f = (float*)(ws + take((size_t)4096*1024*4));
  float* PT_f = (float*)(ws + take((size_t)4096*1024*4));
  // aliases (lifetime-checked against launch order):
  float* ew_f = (float*)xr_h;    // spans xr_h+xw_h (16MB); both dead after L2; ew written L3, read L6
  float* a_f  = (float*)xk_h;    // spans xk_h+xv_h (16MB); dead after L2; a written L3, read L5/L6
  float* g_f  = (float*)xa_h;    // spans xa_h+Wr_p..: xa_h 8MB + Wr_p 2MB + Wk_p 2MB + Wv_p 2MB + Wo_p... NO
  // g_f needs 16MB contiguous written L4 read L8; xa_h is only 8MB. Use r_h (8MB, dead after L3)
  // + t2w/t2a/t2g? Not contiguous guarantees. Safer: S0_f aliases kk_f (kk dead after L6, S0 written L7);
  // g_f gets its own allocation:
  g_f = (float*)(ws + take((size_t)4096*1024*4));
  float* S0_f = kk_f;            // kk read L6 only; S0 written L7, read L8
  f16*   y_h  = (f16*)xr_h;      // ew (aliased here) dead after L6; y written L8, read L9
  float* oF   = (float*)d_out;   // o0 lives in d_out until L9 overwrites

  // L1: prep -> 5 fp16 operands
  k_prep<<<4096, 256, 0, stream>>>(hs, x_r, x_w, x_k, x_v, x_a,
                                   xr_h, xw_h, xk_h, xv_h, xa_h);
  // L1b: weight transpose -> fp16
  SrcP sp; DstP dp;
  sp.p[0]=W_r; sp.p[1]=W_k; sp.p[2]=W_v; sp.p[3]=W_o;
  sp.p[4]=wla; sp.p[5]=wlb; sp.p[6]=ala; sp.p[7]=alb; sp.p[8]=gla; sp.p[9]=glb;
  dp.p[0]=Wr_p; dp.p[1]=Wk_p; dp.p[2]=Wv_p; dp.p[3]=Wo_p;
  dp.p[4]=wla_p; dp.p[5]=wlb_p; dp.p[6]=ala_p; dp.p[7]=alb_p; dp.p[8]=gla_p; dp.p[9]=glb_p;
  k_transpose<<<dim3(32,32,10), dim3(32,8), 0, stream>>>(sp, dp);

  GJobs J{};
  auto job = [](const f16* A, const f16* Bt, float* C, f16* Cpk, const float* bias,
                int K, int N, int Npk, int ldc, int act, int lda, int ldb) {
    GJob j; j.A=A; j.Bt=Bt; j.C=C; j.Cpk=Cpk; j.bias=bias;
    j.K=K; j.N=N; j.Npk=Npk; j.ldc=ldc; j.act=act; j.lda=lda; j.ldb=ldb;
    return j;
  };

  // L2: r(+fp16 copy), k, v, w-s1(tanh->t2w), a-s1(->t2a)
  J.j[0] = job(xr_h, Wr_p,  r_f, r_h,     nullptr, 1024, 1024, 1024, 1024, 0, 1024, 1024);
  J.j[1] = job(xk_h, Wk_p,  k_f, nullptr, nullptr, 1024, 1024, 0,    1024, 0, 1024, 1024);
  J.j[2] = job(xv_h, Wv_p,  v_f, nullptr, nullptr, 1024, 1024, 0,    1024, 0, 1024, 1024);
  J.j[3] = job(xw_h, wla_p, nullptr, t2w, nullptr, 1024, 128,  64,   0,    2, 1024, 1024);
  J.j[4] = job(xa_h, ala_p, nullptr, t2a, nullptr, 1024, 128,  64,   0,    0, 1024, 1024);
  k_gemm_fp16<<<dim3(32,8,5), 256, 0, stream>>>(J);

  // L3: w-s2 (ew), a-s2 (sigmoid), g-s1 (sigmoid -> t2g)
  J = GJobs{};
  J.j[0] = job(t2w, wlb_p, ew_f, nullptr, wlbias, 64,   1024, 0,   1024, 3, 64,   64);
  J.j[1] = job(t2a, alb_p, a_f,  nullptr, albias, 64,   1024, 0,   1024, 1, 64,   64);
  J.j[2] = job(r_h, gla_p, nullptr, t2g,  nullptr, 1024, 128, 128,  0,    1, 1024, 1024);
  k_gemm_fp16<<<dim3(32,8,3), 256, 0, stream>>>(J);

  // L4: g-s2 (+bias)
  J = GJobs{};
  J.j[0] = job(t2g, glb_p, g_f, nullptr, glbias, 128, 1024, 0, 1024, 0, 128, 128);
  k_gemm_fp16<<<dim3(32,8,1), 256, 0, stream>>>(J);

  // L5: kk normalize + k update + b precompute
  k_scanprep<<<16384, 256, 0, stream>>>(k_f, a_f, k_k, k_a, kk_f);

  // L6-L7: chunked scan (fp32 / split-bf16, unchanged)
  k_scan_p1<<<1024, 512, 0, stream>>>(r_f, ew_f, k_f, v_f, kk_f, a_f, oF, z_f, Uc_f, PT_f);
  k_chain<<<32, 256, 0, stream>>>(Uc_f, PT_f, S0_f);

  // L8: fused correction + groupnorm + bonus + gate -> fp16 y
  k_corrpost<<<1024, 256, 0, stream>>>(S0_f, z_f, oF, r_f, k_f, v_f,
                                       r_k, gnw, gnb, g_f, y_h);

  // L9: output projection (overwrites d_out)
  J = GJobs{};
  J.j[0] = job(y_h, Wo_p, (float*)d_out, nullptr, nullptr, 1024, 1024, 0, 1024, 0, 1024, 1024);
  k_gemm_fp16<<<dim3(32,8,1), 256, 0, stream>>>(J);
}

// Round 11
// 368.470 us; speedup vs baseline: 1.3777x; 1.0633x over previous
//
#include <hip/hip_runtime.h>
#include <hip/hip_bf16.h>
#include <hip/hip_fp16.h>
#include <stdint.h>
#include <stddef.h>

typedef __hip_bfloat16 bf16;
typedef _Float16 f16;
typedef __attribute__((ext_vector_type(8))) short short8;
typedef __attribute__((ext_vector_type(8))) _Float16 half8;
typedef __attribute__((ext_vector_type(4))) float f32x4;
typedef unsigned short us;

__device__ __forceinline__ float dsigm(float z){ return 1.f/(1.f+expf(-z)); }

// split fp32 -> hi (rounded bf16) + lo (rounded bf16 residual); scan-side MFMA only
__device__ __forceinline__ void split1(float v, us& h, us& l) {
  bf16 hb = __float2bfloat16(v);
  h = __builtin_bit_cast(us, hb);
  float hf = __bfloat162float(hb);
  bf16 lb = __float2bfloat16(v - hf);
  l = __builtin_bit_cast(us, lb);
}

__device__ __forceinline__ void split8(const float* f, short8& h, short8& l) {
#pragma unroll
  for (int e = 0; e < 8; ++e) {
    us hh, ll;
    split1(f[e], hh, ll);
    h[e] = (short)hh; l[e] = (short)ll;
  }
}

// async global->LDS, 16B per lane (dest = wave-uniform base + lane*16)
__device__ __forceinline__ void gl16(const f16* g, f16* l) {
  __builtin_amdgcn_global_load_lds((const __attribute__((address_space(1))) void*)g,
                                   (__attribute__((address_space(3))) void*)l, 16, 0, 0);
}

//==================== 1. time-shift lerp -> fp16 operands ====================
__device__ __forceinline__ void emit16(const float* __restrict__ marr, int c4,
    const float4& cur, const float4& dlt, f16* __restrict__ out, int row)
{
  float4 m = *(const float4*)(marr + c4);
  f16* o = out + (size_t)row*1024 + c4;
  o[0] = (f16)fmaf(dlt.x, m.x, cur.x);
  o[1] = (f16)fmaf(dlt.y, m.y, cur.y);
  o[2] = (f16)fmaf(dlt.z, m.z, cur.z);
  o[3] = (f16)fmaf(dlt.w, m.w, cur.w);
}

__global__ void k_prep(const float* __restrict__ hs,
    const float* __restrict__ mr, const float* __restrict__ mw, const float* __restrict__ mk,
    const float* __restrict__ mv, const float* __restrict__ ma,
    f16* __restrict__ oxr, f16* __restrict__ oxw, f16* __restrict__ oxk,
    f16* __restrict__ oxv, f16* __restrict__ oxa)
{
  int id = blockIdx.x * 256 + threadIdx.x;
  int row = id >> 8;
  int c4 = (id & 255) << 2;
  int t = row & 2047;
  const float* hp = hs + (size_t)row*1024 + c4;
  float4 cur = *(const float4*)hp;
  float4 prev = make_float4(0.f,0.f,0.f,0.f);
  if (t > 0) prev = *(const float4*)(hp - 1024);
  float4 dlt = make_float4(prev.x-cur.x, prev.y-cur.y, prev.z-cur.z, prev.w-cur.w);
  emit16(mr, c4, cur, dlt, oxr, row);
  emit16(mw, c4, cur, dlt, oxw, row);
  emit16(mk, c4, cur, dlt, oxk, row);
  emit16(mv, c4, cur, dlt, oxv, row);
  emit16(ma, c4, cur, dlt, oxa, row);
}

//==================== 2. weight transpose -> fp16 ====================
struct SrcP { const float* p[10]; };
struct DstP { f16* p[10]; };

__global__ void k_transpose(SrcP S, DstP Dd)
{
  static constexpr int TR[10]  = {1024,1024,1024,1024,1024,  64,1024,  64,1024, 128};
  static constexpr int TCC[10] = {1024,1024,1024,1024,  64,1024,  64,1024, 128,1024};
  static constexpr int TCP[10] = {1024,1024,1024,1024, 128,1024, 128,1024, 128,1024};
  int z = blockIdx.z;
  int R = TR[z], Cc = TCC[z], Cp = TCP[z];
  int n0 = blockIdx.x * 32, r0 = blockIdx.y * 32;
  if (n0 >= Cp || r0 >= R) return;
  const float* src = S.p[z];
  f16* dst = Dd.p[z];
  int tx = threadIdx.x, ty = threadIdx.y;
  __shared__ float tile[32][33];
  if (n0 < Cc) {
#pragma unroll
    for (int i = 0; i < 4; ++i)
      tile[ty + 8*i][tx] = src[(size_t)(r0 + ty + 8*i)*Cc + n0 + tx];
    __syncthreads();
#pragma unroll
    for (int i = 0; i < 4; ++i)
      dst[(size_t)(n0 + ty + 8*i)*R + r0 + tx] = (f16)tile[tx][ty + 8*i];
  } else {
#pragma unroll
    for (int i = 0; i < 4; ++i)
      dst[(size_t)(n0 + ty + 8*i)*R + r0 + tx] = (f16)0.f;
  }
}

//==================== 3. batched fp16 MFMA GEMM ====================
struct GJob {
  const f16* A;              // [4096][lda]
  const f16* Bt;             // [N][ldb]
  float* C;                  // optional fp32 out [4096][ldc]
  f16* Cpk;                  // optional fp16 out [4096][Npk]
  const float* bias;         // optional per-col (added before act)
  int K; int N; int Npk; int ldc; int act;   // act: 0 none, 1 sigmoid, 2 tanh, 3 e^-.5*sigmoid
  int lda; int ldb;
};
struct GJobs { GJob j[5]; };

__global__ __launch_bounds__(256) void k_gemm_fp16(GJobs jobs)
{
  GJob jb = jobs.j[blockIdx.z];
  const int colBase = blockIdx.y * 128;
  if (colBase >= jb.N) return;
  const int rowBase = blockIdx.x * 128;
  __shared__ __align__(16) f16 As[128*32];
  __shared__ __align__(16) f16 Bs[128*32];
  const int tid = threadIdx.x;
  const int l = tid & 63, w = tid >> 6;
  const int wm = w >> 1, wn = w & 1;
  const int lrow = l & 15, kid = (l >> 4) * 8;
  const int nk = jb.K >> 5;

  const int s0 = w*64 + l, s1 = (4 + w)*64 + l;
  const int ar0 = s0 >> 2, ac0 = (s0 & 3) * 8;
  const int ar1 = s1 >> 2, ac1 = (s1 & 3) * 8;
  const int ld0 = w*512, ld1 = (4 + w)*512;
  const f16* Arow0 = jb.A  + (size_t)(rowBase + ar0)*jb.lda + ac0;
  const f16* Arow1 = jb.A  + (size_t)(rowBase + ar1)*jb.lda + ac1;
  const f16* Brow0 = jb.Bt + (size_t)(colBase + ar0)*jb.ldb + ac0;
  const f16* Brow1 = jb.Bt + (size_t)(colBase + ar1)*jb.ldb + ac1;

  f32x4 acc[4][4];
#pragma unroll
  for (int i = 0; i < 4; ++i)
#pragma unroll
    for (int j = 0; j < 4; ++j) { f32x4 z = {0.f,0.f,0.f,0.f}; acc[i][j] = z; }

  for (int kt = 0; kt < nk; ++kt) {
    const int kh = kt*32;
    gl16(Arow0 + kh, &As[ld0]);  gl16(Arow1 + kh, &As[ld1]);
    gl16(Brow0 + kh, &Bs[ld0]);  gl16(Brow1 + kh, &Bs[ld1]);
    __syncthreads();
    half8 ah[4], bh[4];
#pragma unroll
    for (int mt = 0; mt < 4; ++mt) ah[mt] = *(const half8*)&As[(wm*64 + mt*16 + lrow)*32 + kid];
#pragma unroll
    for (int nt = 0; nt < 4; ++nt) bh[nt] = *(const half8*)&Bs[(wn*64 + nt*16 + lrow)*32 + kid];
#pragma unroll
    for (int mt = 0; mt < 4; ++mt)
#pragma unroll
      for (int nt = 0; nt < 4; ++nt)
        acc[mt][nt] = __builtin_amdgcn_mfma_f32_16x16x32_f16(ah[mt], bh[nt], acc[mt][nt], 0, 0, 0);
    __syncthreads();
  }
#pragma unroll
  for (int mt = 0; mt < 4; ++mt) {
    int row = rowBase + wm*64 + mt*16 + (l >> 4)*4;
#pragma unroll
    for (int nt = 0; nt < 4; ++nt) {
      int col = colBase + wn*64 + nt*16 + (l & 15);
      float bv = (jb.bias != nullptr) ? jb.bias[col] : 0.f;
#pragma unroll
      for (int rg = 0; rg < 4; ++rg) {
        float v = acc[mt][nt][rg] + bv;
        if (jb.act == 1)      v = dsigm(v);
        else if (jb.act == 2) v = tanhf(v);
        else if (jb.act == 3) v = 0.60653066f * dsigm(v);
        if (jb.C) jb.C[(size_t)(row + rg)*jb.ldc + col] = v;
        if (jb.Cpk && col < jb.Npk)
          jb.Cpk[(size_t)(row + rg)*jb.Npk + col] = (f16)v;
      }
    }
  }
}

//==================== 5. scan prep (fp16 I/O): kk normalize + k update + b=kk*a ====================
__global__ void k_scanprep(f16* __restrict__ kA, f16* __restrict__ aA,
                           const float* __restrict__ kkw, const float* __restrict__ kaw,
                           f16* __restrict__ kkA)
{
  int idx = blockIdx.x * 256 + threadIdx.x;      // 524288 threads, 8 elems each
  size_t gt8 = (size_t)idx * 8;
  int ch = (int)(gt8 & 1023);
  half8 k8 = *(const half8*)(kA + gt8);
  half8 a8 = *(const half8*)(aA + gt8);
  float kw[8], ka_[8];
  *(float4*)&kw[0]  = *(const float4*)(kkw + ch);
  *(float4*)&kw[4]  = *(const float4*)(kkw + ch + 4);
  *(float4*)&ka_[0] = *(const float4*)(kaw + ch);
  *(float4*)&ka_[4] = *(const float4*)(kaw + ch + 4);
  float kkv[8]; float ss = 0.f;
#pragma unroll
  for (int e = 0; e < 8; ++e) { kkv[e] = (float)k8[e] * kw[e]; ss += kkv[e]*kkv[e]; }
  ss += __shfl_xor(ss, 1); ss += __shfl_xor(ss, 2); ss += __shfl_xor(ss, 4);
  float inv = 1.f / fmaxf(sqrtf(ss), 1e-12f);
  half8 kkn8, bb8, kup8;
#pragma unroll
  for (int e = 0; e < 8; ++e) {
    float kkn = kkv[e] * inv;
    float av = (float)a8[e];
    kkn8[e] = (f16)kkn;
    bb8[e]  = (f16)(kkn * av);
    kup8[e] = (f16)((float)k8[e] * fmaf(av - 1.f, ka_[e], 1.f));
  }
  *(half8*)(kkA + gt8) = kkn8;
  *(half8*)(aA + gt8)  = bb8;
  *(half8*)(kA + gt8)  = kup8;
}

//==================== 6a. chunked scan pass 1 (f16 LDS staging, 8-step groups) ====================
// LDS f16 layout per buffer (f16 units): [array:6][step:8][ch:64]; arrays 0=ew 1=kk 2=bb 3=k 4=r 5=v
// buffer = 3072 f16 (6KB), double-buffered (12KB), aliased under the 16.6KB fp32 transpose tail.
__device__ __forceinline__ void step_lds(const f16* __restrict__ sb, int s,
    float* u, float* p, float* __restrict__ o0A, float* __restrict__ zA,
    size_t base, int i, int q, int j0)
{
  half8 ew = *(const half8*)(sb + 0    + s*64 + j0);
  half8 kk = *(const half8*)(sb + 512  + s*64 + j0);
  half8 bb = *(const half8*)(sb + 1024 + s*64 + j0);
  half8 kv = *(const half8*)(sb + 1536 + s*64 + j0);
  half8 rr = *(const half8*)(sb + 2048 + s*64 + j0);
  float vi = (float)sb[2560 + s*64 + i];

  float uk = 0.f, pk = 0.f;
#pragma unroll
  for (int e = 0; e < 8; ++e) { uk += u[e]*(float)kk[e]; pk += p[e]*(float)kk[e]; }
  uk += __shfl_xor(uk, 1); uk += __shfl_xor(uk, 2); uk += __shfl_xor(uk, 4);
  pk += __shfl_xor(pk, 1); pk += __shfl_xor(pk, 2); pk += __shfl_xor(pk, 4);
  const float su = -uk, sp = -pk;
  float oo = 0.f, zz = 0.f;
#pragma unroll
  for (int e = 0; e < 8; ++e) {
    float uu = u[e]*(float)ew[e] + su*(float)bb[e] + vi*(float)kv[e];
    u[e] = uu; oo += uu*(float)rr[e];
    float pp = p[e]*(float)ew[e] + sp*(float)bb[e];
    p[e] = pp; zz += pp*(float)rr[e];
  }
  oo += __shfl_xor(oo, 1); oo += __shfl_xor(oo, 2); oo += __shfl_xor(oo, 4);
  zz += __shfl_xor(zz, 1); zz += __shfl_xor(zz, 2); zz += __shfl_xor(zz, 4);
  if (q == 0) { o0A[base + i] = oo; zA[base + i] = zz; }
}

__global__ __launch_bounds__(512) void k_scan_p1(
    const f16* __restrict__ rA, const f16* __restrict__ ewA,
    const f16* __restrict__ kA, const f16* __restrict__ vA,
    const f16* __restrict__ kkA, const f16* __restrict__ bbA,
    float* __restrict__ o0A, float* __restrict__ zA,
    float* __restrict__ UcA, float* __restrict__ PTcA)
{
  const int blk = blockIdx.x;
  const int bh = blk & 31, c = blk >> 5;
  const int b = bh >> 4, h = bh & 15;
  const int tid = threadIdx.x;
  const int i = tid >> 3, q = tid & 7, j0 = q * 8;
  const size_t base0 = (size_t)b*2048*1024 + (size_t)h*64 + (size_t)(c*64)*1024;

  __shared__ __align__(16) float smem[4160];   // 16.64KB; f16 staging (12KB) aliased below
  f16* hsm = (f16*)smem;

  // staging: 384 active lanes; per group 6 arrays x 8 steps x 64ch f16 = 384 x 16B
  const int active = (tid < 384);
  const int a0 = tid >> 6, rm0 = tid & 63, s0 = rm0 >> 3, f0 = rm0 & 7;
  const f16* pa0 = (a0==0) ? ewA : (a0==1) ? kkA : (a0==2) ? bbA :
                   (a0==3) ? kA  : (a0==4) ? rA  : vA;
  const f16* src0 = pa0 + base0 + (size_t)s0*1024 + f0*8;
  const int dst0 = a0*512 + s0*64 + f0*8;

  float u[8], p[8];
#pragma unroll
  for (int jj = 0; jj < 8; ++jj) { u[jj] = 0.f; p[jj] = (j0 + jj == i) ? 1.f : 0.f; }

  if (active) *(half8*)&hsm[dst0] = *(const half8*)(src0);
  __syncthreads();

  int curb = 0;
  for (int g = 0; g < 8; ++g) {
    half8 n0;
    if (g < 7 && active) n0 = *(const half8*)(src0 + (size_t)(g+1)*8192);
    const f16* sb = hsm + curb*3072;
#pragma unroll
    for (int s = 0; s < 8; ++s)
      step_lds(sb, s, u, p, o0A, zA, base0 + (size_t)(g*8 + s)*1024, i, q, j0);
    if (g < 7 && active) *(half8*)&hsm[(curb^1)*3072 + dst0] = n0;
    __syncthreads();
    curb ^= 1;
  }

  // store U_c (row-major [i][j]) and P_c^T (row-major [j][m]) for pass 2
  const size_t cbase = ((size_t)(bh*32 + c)) * 4096;
  *(float4*)(UcA + cbase + (size_t)i*64 + j0)     = make_float4(u[0],u[1],u[2],u[3]);
  *(float4*)(UcA + cbase + (size_t)i*64 + j0 + 4) = make_float4(u[4],u[5],u[6],u[7]);
  float (*lds)[65] = (float(*)[65])smem;
#pragma unroll
  for (int jj = 0; jj < 8; ++jj) lds[i][j0 + jj] = p[jj];
  __syncthreads();
  float4 w0 = make_float4(lds[j0+0][i], lds[j0+1][i], lds[j0+2][i], lds[j0+3][i]);
  float4 w1 = make_float4(lds[j0+4][i], lds[j0+5][i], lds[j0+6][i], lds[j0+7][i]);
  *(float4*)(PTcA + cbase + (size_t)i*64 + j0)     = w0;
  *(float4*)(PTcA + cbase + (size_t)i*64 + j0 + 4) = w1;
}

//==================== 6b. chain: S_{c+1} = U_c + S_c @ P_c (split-bf16, fp32-grade) ====================
__device__ __forceinline__ void chain_body(int c, int bh, int w, int lr, int lq,
    float (&Slds)[64][65], f32x4 (&acc)[4],
    float (&u_c)[4][4], float4 (&p_c)[2][2],
    float (&u_n)[4][4], float4 (&p_n)[2][2],
    const float* __restrict__ UcA, const float* __restrict__ PTcA,
    float* __restrict__ S0A)
{
  const size_t s0base = ((size_t)bh*32 + c) * 4096;
#pragma unroll
  for (int mt = 0; mt < 4; ++mt)
#pragma unroll
    for (int rg = 0; rg < 4; ++rg) {
      Slds[mt*16 + lq*4 + rg][w*16 + lr] = acc[mt][rg];
      if (c > 0) S0A[s0base + (size_t)(mt*16 + lq*4 + rg)*64 + w*16 + lr] = acc[mt][rg];
    }
  __syncthreads();
  if (c + 1 < 32) {
    const size_t nbase = ((size_t)bh*32 + c + 1) * 4096;
#pragma unroll
    for (int mt = 0; mt < 4; ++mt)
#pragma unroll
      for (int rg = 0; rg < 4; ++rg)
        u_n[mt][rg] = UcA[nbase + (size_t)(mt*16 + lq*4 + rg)*64 + w*16 + lr];
#pragma unroll
    for (int kt = 0; kt < 2; ++kt)
#pragma unroll
      for (int hh = 0; hh < 2; ++hh)
        p_n[kt][hh] = *(const float4*)(PTcA + nbase + (size_t)(w*16 + lr)*64 + kt*32 + lq*8 + hh*4);
  }
  short8 pbh[2], pbl[2];
#pragma unroll
  for (int kt = 0; kt < 2; ++kt) {
    float f[8] = {p_c[kt][0].x, p_c[kt][0].y, p_c[kt][0].z, p_c[kt][0].w,
                  p_c[kt][1].x, p_c[kt][1].y, p_c[kt][1].z, p_c[kt][1].w};
    split8(f, pbh[kt], pbl[kt]);
  }
  f32x4 nacc[4];
#pragma unroll
  for (int mt = 0; mt < 4; ++mt) {
    f32x4 z = {u_c[mt][0], u_c[mt][1], u_c[mt][2], u_c[mt][3]};
    nacc[mt] = z;
  }
#pragma unroll
  for (int kt = 0; kt < 2; ++kt)
#pragma unroll
    for (int mt = 0; mt < 4; ++mt) {
      float f[8];
#pragma unroll
      for (int e = 0; e < 8; ++e) f[e] = Slds[mt*16 + lr][kt*32 + lq*8 + e];
      short8 sah, sal;
      split8(f, sah, sal);
      nacc[mt] = __builtin_amdgcn_mfma_f32_16x16x32_bf16(sah, pbh[kt], nacc[mt], 0, 0, 0);
      nacc[mt] = __builtin_amdgcn_mfma_f32_16x16x32_bf16(sal, pbh[kt], nacc[mt], 0, 0, 0);
      nacc[mt] = __builtin_amdgcn_mfma_f32_16x16x32_bf16(sah, pbl[kt], nacc[mt], 0, 0, 0);
    }
#pragma unroll
  for (int mt = 0; mt < 4; ++mt) acc[mt] = nacc[mt];
  __syncthreads();
}

__global__ __launch_bounds__(256) void k_chain(
    const float* __restrict__ UcA, const float* __restrict__ PTcA,
    float* __restrict__ S0A)
{
  const int bh = blockIdx.x;
  const int l = threadIdx.x & 63, w = threadIdx.x >> 6;
  const int lr = l & 15, lq = l >> 4;
  __shared__ float Slds[64][65];

  f32x4 acc[4];
#pragma unroll
  for (int mt = 0; mt < 4; ++mt) { f32x4 z = {0.f,0.f,0.f,0.f}; acc[mt] = z; }

  float u0[4][4], u1[4][4];
  float4 p0[2][2], p1[2][2];
  {
    const size_t cbase = (size_t)bh * 32 * 4096;
#pragma unroll
    for (int mt = 0; mt < 4; ++mt)
#pragma unroll
      for (int rg = 0; rg < 4; ++rg)
        u0[mt][rg] = UcA[cbase + (size_t)(mt*16 + lq*4 + rg)*64 + w*16 + lr];
#pragma unroll
    for (int kt = 0; kt < 2; ++kt)
#pragma unroll
      for (int hh = 0; hh < 2; ++hh)
        p0[kt][hh] = *(const float4*)(PTcA + cbase + (size_t)(w*16 + lr)*64 + kt*32 + lq*8 + hh*4);
  }
  for (int c = 0; c < 32; c += 2) {
    chain_body(c,     bh, w, lr, lq, Slds, acc, u0, p0, u1, p1, UcA, PTcA, S0A);
    chain_body(c + 1, bh, w, lr, lq, Slds, acc, u1, p1, u0, p0, UcA, PTcA, S0A);
  }
}

//==================== 6c. fused correction + GroupNorm + bonus + gate -> fp16 y ====================
__global__ __launch_bounds__(256) void k_corrpost(
    const float* __restrict__ S0A, const float* __restrict__ zA,
    const float* __restrict__ o0A, const f16* __restrict__ rA,
    const f16* __restrict__ kA, const f16* __restrict__ vA,
    const float* __restrict__ rk, const float* __restrict__ gnw,
    const float* __restrict__ gnb, const f16* __restrict__ gA,
    f16* __restrict__ yH)
{
  const int blk = blockIdx.x;
  const int bh = blk & 31;
  const int c  = blk >> 5;               // 0..31
  const int b = bh >> 4, h = bh & 15;
  const int l = threadIdx.x & 63, w = threadIdx.x >> 6;
  const int lr = l & 15, lq = l >> 4;

  f32x4 a2[4];
#pragma unroll
  for (int nt = 0; nt < 4; ++nt) { f32x4 z = {0.f,0.f,0.f,0.f}; a2[nt] = z; }

  if (c > 0) {
    const size_t s0base = ((size_t)bh*32 + c) * 4096;
    short8 sbh[4][2], sbl[4][2];
#pragma unroll
    for (int nt = 0; nt < 4; ++nt)
#pragma unroll
      for (int kt = 0; kt < 2; ++kt) {
        float f[8];
#pragma unroll
        for (int e = 0; e < 8; ++e)
          f[e] = S0A[s0base + (size_t)(nt*16 + lr)*64 + kt*32 + lq*8 + e];
        split8(f, sbh[nt][kt], sbl[nt][kt]);
      }
    short8 zh[2], zl[2];
#pragma unroll
    for (int kt = 0; kt < 2; ++kt) {
      const float* zp = zA + ((size_t)(b*2048 + c*64 + w*16 + lr)*16 + h)*64 + kt*32 + lq*8;
      float f[8];
#pragma unroll
      for (int e = 0; e < 8; ++e) f[e] = zp[e];
      split8(f, zh[kt], zl[kt]);
    }
#pragma unroll
    for (int kt = 0; kt < 2; ++kt)
#pragma unroll
      for (int nt = 0; nt < 4; ++nt) {
        a2[nt] = __builtin_amdgcn_mfma_f32_16x16x32_bf16(zh[kt], sbh[nt][kt], a2[nt], 0, 0, 0);
        a2[nt] = __builtin_amdgcn_mfma_f32_16x16x32_bf16(zl[kt], sbh[nt][kt], a2[nt], 0, 0, 0);
        a2[nt] = __builtin_amdgcn_mfma_f32_16x16x32_bf16(zh[kt], sbl[nt][kt], a2[nt], 0, 0, 0);
      }
  }

#pragma unroll
  for (int rg = 0; rg < 4; ++rg) {
    const int tl = w*16 + lq*4 + rg;
    const size_t trow = (size_t)(b*2048 + c*64 + tl);
    const size_t rb = trow*1024 + h*64;
    float o4[4], v4[4];
    float sum = 0.f, pr = 0.f;
#pragma unroll
    for (int nt = 0; nt < 4; ++nt) {
      const int ii = nt*16 + lr;
      float o = o0A[rb + ii] + a2[nt][rg];
      o4[nt] = o; sum += o;
      v4[nt] = (float)vA[rb + ii];
      pr += (float)rA[rb + ii] * (float)kA[rb + ii] * rk[h*64 + ii];
    }
    sum += __shfl_xor(sum,1); sum += __shfl_xor(sum,2);
    sum += __shfl_xor(sum,4); sum += __shfl_xor(sum,8);
    pr  += __shfl_xor(pr,1);  pr  += __shfl_xor(pr,2);
    pr  += __shfl_xor(pr,4);  pr  += __shfl_xor(pr,8);
    float mean = sum * (1.f/64.f);
    float vp = 0.f;
#pragma unroll
    for (int nt = 0; nt < 4; ++nt) { float d = o4[nt]-mean; vp += d*d; }
    vp += __shfl_xor(vp,1); vp += __shfl_xor(vp,2);
    vp += __shfl_xor(vp,4); vp += __shfl_xor(vp,8);
    float inv = rsqrtf(vp*(1.f/64.f) + 1e-5f);
#pragma unroll
    for (int nt = 0; nt < 4; ++nt) {
      const int ii = nt*16 + lr;
      const int ch = h*64 + ii;
      float y = (o4[nt]-mean)*inv*gnw[ch] + gnb[ch];
      y = fmaf(pr, v4[nt], y);
      y *= (float)gA[rb + ii];
      yH[trow*1024 + ch] = (f16)y;
    }
  }
}

//==================== host ====================
extern "C" void kernel_launch(void* const* d_in, const int* in_sizes, int n_in,
                              void* d_out, int out_size, void* d_ws, size_t ws_size,
                              hipStream_t stream)
{
  (void)in_sizes; (void)n_in; (void)out_size; (void)ws_size;
  const float* hs     = (const float*)d_in[0];
  const float* x_r    = (const float*)d_in[1];
  const float* x_w    = (const float*)d_in[2];
  const float* x_k    = (const float*)d_in[3];
  const float* x_v    = (const float*)d_in[4];
  const float* x_a    = (const float*)d_in[5];
  const float* k_k    = (const float*)d_in[7];
  const float* k_a    = (const float*)d_in[8];
  const float* r_k    = (const float*)d_in[9];
  const float* W_r    = (const float*)d_in[10];
  const float* W_k    = (const float*)d_in[11];
  const float* W_v    = (const float*)d_in[12];
  const float* W_o    = (const float*)d_in[13];
  const float* wla    = (const float*)d_in[14];
  const float* wlb    = (const float*)d_in[15];
  const float* wlbias = (const float*)d_in[16];
  const float* ala    = (const float*)d_in[17];
  const float* alb    = (const float*)d_in[18];
  const float* albias = (const float*)d_in[19];
  const float* gla    = (const float*)d_in[20];
  const float* glb    = (const float*)d_in[21];
  const float* glbias = (const float*)d_in[22];
  const float* gnw    = (const float*)d_in[23];
  const float* gnb    = (const float*)d_in[24];

  char* ws = (char*)d_ws;
  size_t cur = 0;
  auto take = [&](size_t bytes) { size_t o = cur; cur += (bytes + 255) & ~(size_t)255; return o; };

  // fp16 x operands [4096][1024] (8MB each); xk,xv consecutive (S0_f spans them)
  f16* xr_h = (f16*)(ws + take((size_t)4096*1024*2));
  f16* xw_h = (f16*)(ws + take((size_t)4096*1024*2));
  f16* xk_h = (f16*)(ws + take((size_t)4096*1024*2));
  f16* xv_h = (f16*)(ws + take((size_t)4096*1024*2));
  f16* xa_h = (f16*)(ws + take((size_t)4096*1024*2));
  // fp16 weights
  f16* Wr_p  = (f16*)(ws + take((size_t)1024*1024*2));
  f16* Wk_p  = (f16*)(ws + take((size_t)1024*1024*2));
  f16* Wv_p  = (f16*)(ws + take((size_t)1024*1024*2));
  f16* Wo_p  = (f16*)(ws + take((size_t)1024*1024*2));
  f16* wla_p = (f16*)(ws + take((size_t)128*1024*2));
  f16* wlb_p = (f16*)(ws + take((size_t)1024*64*2));
  f16* ala_p = (f16*)(ws + take((size_t)128*1024*2));
  f16* alb_p = (f16*)(ws + take((size_t)1024*64*2));
  f16* gla_p = (f16*)(ws + take((size_t)128*1024*2));
  f16* glb_p = (f16*)(ws + take((size_t)1024*128*2));
  // fp16 scan operands
  f16* r_h  = (f16*)(ws + take((size_t)4096*1024*2));
  f16* k_h  = (f16*)(ws + take((size_t)4096*1024*2));
  f16* v_h  = (f16*)(ws + take((size_t)4096*1024*2));
  f16* kk_h = (f16*)(ws + take((size_t)4096*1024*2));
  f16* g_h  = (f16*)(ws + take((size_t)4096*1024*2));
  f16* t2w  = (f16*)(ws + take((size_t)4096*64*2));
  f16* t2a  = (f16*)(ws + take((size_t)4096*64*2));
  f16* t2g  = (f16*)(ws + take((size_t)4096*128*2));
  // fp32 buffers
  float* z_f  = (float*)(ws + take((size_t)4096*1024*4));
  float* Uc_f = (float*)(ws + take((size_t)4096*1024*4));
  float* PT_f = (float*)(ws + take((size_t)4096*1024*4));
  // aliases (lifetime-checked against launch order):
  f16*   ew_h = xw_h;            // xw read L2 (w-s1); ew written L3, read p1 L6
  f16*   a_h  = xa_h;            // xa read L2 (a-s1); a written L3, scanprep L5 -> bb, read p1 L6
  f16*   y_h  = xr_h;            // xr read L2 (r); y written L8, read L9
  float* S0_f = (float*)xk_h;    // spans xk_h+xv_h (16MB, consecutive); both dead after L2;
                                 // S0 written L7, read L8
  float* oF   = (float*)d_out;   // o0 lives in d_out until L9 overwrites

  // L1: prep -> 5 fp16 operands
  k_prep<<<4096, 256, 0, stream>>>(hs, x_r, x_w, x_k, x_v, x_a,
                                   xr_h, xw_h, xk_h, xv_h, xa_h);
  // L1b: weight transpose -> fp16
  SrcP sp; DstP dp;
  sp.p[0]=W_r; sp.p[1]=W_k; sp.p[2]=W_v; sp.p[3]=W_o;
  sp.p[4]=wla; sp.p[5]=wlb; sp.p[6]=ala; sp.p[7]=alb; sp.p[8]=gla; sp.p[9]=glb;
  dp.p[0]=Wr_p; dp.p[1]=Wk_p; dp.p[2]=Wv_p; dp.p[3]=Wo_p;
  dp.p[4]=wla_p; dp.p[5]=wlb_p; dp.p[6]=ala_p; dp.p[7]=alb_p; dp.p[8]=gla_p; dp.p[9]=glb_p;
  k_transpose<<<dim3(32,32,10), dim3(32,8), 0, stream>>>(sp, dp);

  GJobs J{};
  auto job = [](const f16* A, const f16* Bt, float* C, f16* Cpk, const float* bias,
                int K, int N, int Npk, int ldc, int act, int lda, int ldb) {
    GJob j; j.A=A; j.Bt=Bt; j.C=C; j.Cpk=Cpk; j.bias=bias;
    j.K=K; j.N=N; j.Npk=Npk; j.ldc=ldc; j.act=act; j.lda=lda; j.ldb=ldb;
    return j;
  };

  // L2: r, k, v (fp16 outs), w-s1(tanh->t2w), a-s1(->t2a)
  J.j[0] = job(xr_h, Wr_p,  nullptr, r_h, nullptr, 1024, 1024, 1024, 0, 0, 1024, 1024);
  J.j[1] = job(xk_h, Wk_p,  nullptr, k_h, nullptr, 1024, 1024, 1024, 0, 0, 1024, 1024);
  J.j[2] = job(xv_h, Wv_p,  nullptr, v_h, nullptr, 1024, 1024, 1024, 0, 0, 1024, 1024);
  J.j[3] = job(xw_h, wla_p, nullptr, t2w, nullptr, 1024, 128,  64,   0, 2, 1024, 1024);
  J.j[4] = job(xa_h, ala_p, nullptr, t2a, nullptr, 1024, 128,  64,   0, 0, 1024, 1024);
  k_gemm_fp16<<<dim3(32,8,5), 256, 0, stream>>>(J);

  // L3: w-s2 (ew), a-s2 (sigmoid), g-s1 (sigmoid -> t2g)
  J = GJobs{};
  J.j[0] = job(t2w, wlb_p, nullptr, ew_h, wlbias, 64,   1024, 1024, 0, 3, 64,   64);
  J.j[1] = job(t2a, alb_p, nullptr, a_h,  albias, 64,   1024, 1024, 0, 1, 64,   64);
  J.j[2] = job(r_h, gla_p, nullptr, t2g,  nullptr, 1024, 128,  128,  0, 1, 1024, 1024);
  k_gemm_fp16<<<dim3(32,8,3), 256, 0, stream>>>(J);

  // L4: g-s2 (+bias)
  J = GJobs{};
  J.j[0] = job(t2g, glb_p, nullptr, g_h, glbias, 128, 1024, 1024, 0, 0, 128, 128);
  k_gemm_fp16<<<dim3(32,8,1), 256, 0, stream>>>(J);

  // L5: kk normalize + k update + b precompute (fp16 I/O)
  k_scanprep<<<2048, 256, 0, stream>>>(k_h, a_h, k_k, k_a, kk_h);

  // L6-L7: chunked scan
  k_scan_p1<<<1024, 512, 0, stream>>>(r_h, ew_h, k_h, v_h, kk_h, a_h, oF, z_f, Uc_f, PT_f);
  k_chain<<<32, 256, 0, stream>>>(Uc_f, PT_f, S0_f);

  // L8: fused correction + groupnorm + bonus + gate -> fp16 y
  k_corrpost<<<1024, 256, 0, stream>>>(S0_f, z_f, oF, r_h, k_h, v_h,
                                       r_k, gnw, gnb, g_h, y_h);

  // L9: output projection (overwrites d_out)
  J = GJobs{};
  J.j[0] = job(y_h, Wo_p, (float*)d_out, nullptr, nullptr, 1024, 1024, 0, 1024, 0, 1024, 1024);
  k_gemm_fp16<<<dim3(32,8,1), 256, 0, stream>>>(J);
}

// Round 13
// 331.844 us; speedup vs baseline: 1.5298x; 1.1104x over previous
//
#include <hip/hip_runtime.h>
#include <hip/hip_bf16.h>
#include <hip/hip_fp16.h>
#include <stdint.h>
#include <stddef.h>

typedef __hip_bfloat16 bf16;
typedef _Float16 f16;
typedef __attribute__((ext_vector_type(8))) short short8;
typedef __attribute__((ext_vector_type(8))) _Float16 half8;
typedef __attribute__((ext_vector_type(4))) float f32x4;
typedef __attribute__((ext_vector_type(2))) float f32x2;
typedef unsigned short us;

__device__ __forceinline__ float dsigm(float z){ return 1.f/(1.f+expf(-z)); }

// DPP lane-group(8) sum: xor1 (quad_perm 0xB1), xor2 (quad_perm 0x4E), xor4 (row_half_mirror 0x141)
template<int CTRL>
__device__ __forceinline__ float dpp_term(float x) {
  int xi = __builtin_bit_cast(int, x);
  int yi = __builtin_amdgcn_update_dpp(0, xi, CTRL, 0xF, 0xF, false);
  return __builtin_bit_cast(float, yi);
}
__device__ __forceinline__ float red8(float x) {
  x += dpp_term<0xB1>(x);
  x += dpp_term<0x4E>(x);
  x += dpp_term<0x141>(x);
  return x;
}

// split fp32 -> hi (rounded bf16) + lo (rounded bf16 residual); scan-side MFMA only
__device__ __forceinline__ void split1(float v, us& h, us& l) {
  bf16 hb = __float2bfloat16(v);
  h = __builtin_bit_cast(us, hb);
  float hf = __bfloat162float(hb);
  bf16 lb = __float2bfloat16(v - hf);
  l = __builtin_bit_cast(us, lb);
}

__device__ __forceinline__ void split8(const float* f, short8& h, short8& l) {
#pragma unroll
  for (int e = 0; e < 8; ++e) {
    us hh, ll;
    split1(f[e], hh, ll);
    h[e] = (short)hh; l[e] = (short)ll;
  }
}

// async global->LDS, 16B per lane (dest = wave-uniform base + lane*16)
__device__ __forceinline__ void gl16(const f16* g, f16* l) {
  __builtin_amdgcn_global_load_lds((const __attribute__((address_space(1))) void*)g,
                                   (__attribute__((address_space(3))) void*)l, 16, 0, 0);
}

//==================== 1. time-shift lerp -> fp16 operands ====================
__device__ __forceinline__ void emit16(const float* __restrict__ marr, int c4,
    const float4& cur, const float4& dlt, f16* __restrict__ out, int row)
{
  float4 m = *(const float4*)(marr + c4);
  f16* o = out + (size_t)row*1024 + c4;
  o[0] = (f16)fmaf(dlt.x, m.x, cur.x);
  o[1] = (f16)fmaf(dlt.y, m.y, cur.y);
  o[2] = (f16)fmaf(dlt.z, m.z, cur.z);
  o[3] = (f16)fmaf(dlt.w, m.w, cur.w);
}

__global__ void k_prep(const float* __restrict__ hs,
    const float* __restrict__ mr, const float* __restrict__ mw, const float* __restrict__ mk,
    const float* __restrict__ mv, const float* __restrict__ ma,
    f16* __restrict__ oxr, f16* __restrict__ oxw, f16* __restrict__ oxk,
    f16* __restrict__ oxv, f16* __restrict__ oxa)
{
  int id = blockIdx.x * 256 + threadIdx.x;
  int row = id >> 8;
  int c4 = (id & 255) << 2;
  int t = row & 2047;
  const float* hp = hs + (size_t)row*1024 + c4;
  float4 cur = *(const float4*)hp;
  float4 prev = make_float4(0.f,0.f,0.f,0.f);
  if (t > 0) prev = *(const float4*)(hp - 1024);
  float4 dlt = make_float4(prev.x-cur.x, prev.y-cur.y, prev.z-cur.z, prev.w-cur.w);
  emit16(mr, c4, cur, dlt, oxr, row);
  emit16(mw, c4, cur, dlt, oxw, row);
  emit16(mk, c4, cur, dlt, oxk, row);
  emit16(mv, c4, cur, dlt, oxv, row);
  emit16(ma, c4, cur, dlt, oxa, row);
}

//==================== 2. weight transpose -> fp16 ====================
struct SrcP { const float* p[10]; };
struct DstP { f16* p[10]; };

__global__ void k_transpose(SrcP S, DstP Dd)
{
  static constexpr int TR[10]  = {1024,1024,1024,1024,1024,  64,1024,  64,1024, 128};
  static constexpr int TCC[10] = {1024,1024,1024,1024,  64,1024,  64,1024, 128,1024};
  static constexpr int TCP[10] = {1024,1024,1024,1024, 128,1024, 128,1024, 128,1024};
  int z = blockIdx.z;
  int R = TR[z], Cc = TCC[z], Cp = TCP[z];
  int n0 = blockIdx.x * 32, r0 = blockIdx.y * 32;
  if (n0 >= Cp || r0 >= R) return;
  const float* src = S.p[z];
  f16* dst = Dd.p[z];
  int tx = threadIdx.x, ty = threadIdx.y;
  __shared__ float tile[32][33];
  if (n0 < Cc) {
#pragma unroll
    for (int i = 0; i < 4; ++i)
      tile[ty + 8*i][tx] = src[(size_t)(r0 + ty + 8*i)*Cc + n0 + tx];
    __syncthreads();
#pragma unroll
    for (int i = 0; i < 4; ++i)
      dst[(size_t)(n0 + ty + 8*i)*R + r0 + tx] = (f16)tile[tx][ty + 8*i];
  } else {
#pragma unroll
    for (int i = 0; i < 4; ++i)
      dst[(size_t)(n0 + ty + 8*i)*R + r0 + tx] = (f16)0.f;
  }
}

//==================== 3. batched fp16 MFMA GEMM ====================
struct GJob {
  const f16* A;              // [4096][lda]
  const f16* Bt;             // [N][ldb]
  float* C;                  // optional fp32 out [4096][ldc]
  f16* Cpk;                  // optional fp16 out [4096][Npk]
  const float* bias;         // optional per-col (added before act)
  int K; int N; int Npk; int ldc; int act;   // act: 0 none, 1 sigmoid, 2 tanh, 3 e^-.5*sigmoid
  int lda; int ldb;
};
struct GJobs { GJob j[5]; };

__global__ __launch_bounds__(256) void k_gemm_fp16(GJobs jobs)
{
  GJob jb = jobs.j[blockIdx.z];
  const int colBase = blockIdx.y * 128;
  if (colBase >= jb.N) return;
  const int rowBase = blockIdx.x * 128;
  __shared__ __align__(16) f16 As[128*32];
  __shared__ __align__(16) f16 Bs[128*32];
  const int tid = threadIdx.x;
  const int l = tid & 63, w = tid >> 6;
  const int wm = w >> 1, wn = w & 1;
  const int lrow = l & 15, kid = (l >> 4) * 8;
  const int nk = jb.K >> 5;

  const int s0 = w*64 + l, s1 = (4 + w)*64 + l;
  const int ar0 = s0 >> 2, ac0 = (s0 & 3) * 8;
  const int ar1 = s1 >> 2, ac1 = (s1 & 3) * 8;
  const int ld0 = w*512, ld1 = (4 + w)*512;
  const f16* Arow0 = jb.A  + (size_t)(rowBase + ar0)*jb.lda + ac0;
  const f16* Arow1 = jb.A  + (size_t)(rowBase + ar1)*jb.lda + ac1;
  const f16* Brow0 = jb.Bt + (size_t)(colBase + ar0)*jb.ldb + ac0;
  const f16* Brow1 = jb.Bt + (size_t)(colBase + ar1)*jb.ldb + ac1;

  f32x4 acc[4][4];
#pragma unroll
  for (int i = 0; i < 4; ++i)
#pragma unroll
    for (int j = 0; j < 4; ++j) { f32x4 z = {0.f,0.f,0.f,0.f}; acc[i][j] = z; }

  for (int kt = 0; kt < nk; ++kt) {
    const int kh = kt*32;
    gl16(Arow0 + kh, &As[ld0]);  gl16(Arow1 + kh, &As[ld1]);
    gl16(Brow0 + kh, &Bs[ld0]);  gl16(Brow1 + kh, &Bs[ld1]);
    __syncthreads();
    half8 ah[4], bh[4];
#pragma unroll
    for (int mt = 0; mt < 4; ++mt) ah[mt] = *(const half8*)&As[(wm*64 + mt*16 + lrow)*32 + kid];
#pragma unroll
    for (int nt = 0; nt < 4; ++nt) bh[nt] = *(const half8*)&Bs[(wn*64 + nt*16 + lrow)*32 + kid];
#pragma unroll
    for (int mt = 0; mt < 4; ++mt)
#pragma unroll
      for (int nt = 0; nt < 4; ++nt)
        acc[mt][nt] = __builtin_amdgcn_mfma_f32_16x16x32_f16(ah[mt], bh[nt], acc[mt][nt], 0, 0, 0);
    __syncthreads();
  }
#pragma unroll
  for (int mt = 0; mt < 4; ++mt) {
    int row = rowBase + wm*64 + mt*16 + (l >> 4)*4;
#pragma unroll
    for (int nt = 0; nt < 4; ++nt) {
      int col = colBase + wn*64 + nt*16 + (l & 15);
      float bv = (jb.bias != nullptr) ? jb.bias[col] : 0.f;
#pragma unroll
      for (int rg = 0; rg < 4; ++rg) {
        float v = acc[mt][nt][rg] + bv;
        if (jb.act == 1)      v = dsigm(v);
        else if (jb.act == 2) v = tanhf(v);
        else if (jb.act == 3) v = 0.60653066f * dsigm(v);
        if (jb.C) jb.C[(size_t)(row + rg)*jb.ldc + col] = v;
        if (jb.Cpk && col < jb.Npk)
          jb.Cpk[(size_t)(row + rg)*jb.Npk + col] = (f16)v;
      }
    }
  }
}

//==================== 5. scan prep (fp16 I/O): kk normalize + k update + b=kk*a ====================
__global__ void k_scanprep(f16* __restrict__ kA, f16* __restrict__ aA,
                           const float* __restrict__ kkw, const float* __restrict__ kaw,
                           f16* __restrict__ kkA)
{
  int idx = blockIdx.x * 256 + threadIdx.x;      // 524288 threads, 8 elems each
  size_t gt8 = (size_t)idx * 8;
  int ch = (int)(gt8 & 1023);
  half8 k8 = *(const half8*)(kA + gt8);
  half8 a8 = *(const half8*)(aA + gt8);
  float kw[8], ka_[8];
  *(float4*)&kw[0]  = *(const float4*)(kkw + ch);
  *(float4*)&kw[4]  = *(const float4*)(kkw + ch + 4);
  *(float4*)&ka_[0] = *(const float4*)(kaw + ch);
  *(float4*)&ka_[4] = *(const float4*)(kaw + ch + 4);
  float kkv[8]; float ss = 0.f;
#pragma unroll
  for (int e = 0; e < 8; ++e) { kkv[e] = (float)k8[e] * kw[e]; ss += kkv[e]*kkv[e]; }
  ss += __shfl_xor(ss, 1); ss += __shfl_xor(ss, 2); ss += __shfl_xor(ss, 4);
  float inv = 1.f / fmaxf(sqrtf(ss), 1e-12f);
  half8 kkn8, bb8, kup8;
#pragma unroll
  for (int e = 0; e < 8; ++e) {
    float kkn = kkv[e] * inv;
    float av = (float)a8[e];
    kkn8[e] = (f16)kkn;
    bb8[e]  = (f16)(kkn * av);
    kup8[e] = (f16)((float)k8[e] * fmaf(av - 1.f, ka_[e], 1.f));
  }
  *(half8*)(kkA + gt8) = kkn8;
  *(half8*)(aA + gt8)  = bb8;
  *(half8*)(kA + gt8)  = kup8;
}

//==================== 6a. chunked scan pass 1 ====================
// f16 global operands; staging lanes convert once -> f32 LDS [6][8][64] per buffer
// (12KB, double-buffered 24KB). Step math in packed f32x2 (v_pk_fma_f32), reductions
// via DPP adds. Arrays: 0=ew 1=kk 2=bb 3=k 4=r 5=v.
__device__ __forceinline__ void step_pk(const float* __restrict__ sb, int s,
    f32x2* u2, f32x2* p2, float* __restrict__ o0A, float* __restrict__ zA,
    size_t base, int i, int q, int j0)
{
  f32x2 ew2[4], kk2[4], bb2[4], kv2[4], rr2[4];
#pragma unroll
  for (int hh = 0; hh < 2; ++hh) {
    float4 a0 = *(const float4*)(sb + 0    + s*64 + j0 + hh*4);
    float4 a1 = *(const float4*)(sb + 512  + s*64 + j0 + hh*4);
    float4 a2 = *(const float4*)(sb + 1024 + s*64 + j0 + hh*4);
    float4 a3 = *(const float4*)(sb + 1536 + s*64 + j0 + hh*4);
    float4 a4 = *(const float4*)(sb + 2048 + s*64 + j0 + hh*4);
    ew2[hh*2+0] = f32x2{a0.x, a0.y}; ew2[hh*2+1] = f32x2{a0.z, a0.w};
    kk2[hh*2+0] = f32x2{a1.x, a1.y}; kk2[hh*2+1] = f32x2{a1.z, a1.w};
    bb2[hh*2+0] = f32x2{a2.x, a2.y}; bb2[hh*2+1] = f32x2{a2.z, a2.w};
    kv2[hh*2+0] = f32x2{a3.x, a3.y}; kv2[hh*2+1] = f32x2{a3.z, a3.w};
    rr2[hh*2+0] = f32x2{a4.x, a4.y}; rr2[hh*2+1] = f32x2{a4.z, a4.w};
  }
  float vi = sb[2560 + s*64 + i];

  f32x2 uk2 = u2[0]*kk2[0], pk2 = p2[0]*kk2[0];
#pragma unroll
  for (int e = 1; e < 4; ++e) { uk2 += u2[e]*kk2[e]; pk2 += p2[e]*kk2[e]; }
  float uk = red8(uk2.x + uk2.y);
  float pk = red8(pk2.x + pk2.y);
  const f32x2 su2 = {-uk, -uk}, sp2 = {-pk, -pk}, vi2 = {vi, vi};
  f32x2 oo2 = {0.f, 0.f}, zz2 = {0.f, 0.f};
#pragma unroll
  for (int e = 0; e < 4; ++e) {
    f32x2 uu = u2[e]*ew2[e] + su2*bb2[e] + vi2*kv2[e];
    u2[e] = uu; oo2 += uu*rr2[e];
    f32x2 pp = p2[e]*ew2[e] + sp2*bb2[e];
    p2[e] = pp; zz2 += pp*rr2[e];
  }
  float oo = red8(oo2.x + oo2.y);
  float zz = red8(zz2.x + zz2.y);
  if (q == 0) { o0A[base + i] = oo; zA[base + i] = zz; }
}

__global__ __launch_bounds__(512) void k_scan_p1(
    const f16* __restrict__ rA, const f16* __restrict__ ewA,
    const f16* __restrict__ kA, const f16* __restrict__ vA,
    const f16* __restrict__ kkA, const f16* __restrict__ bbA,
    float* __restrict__ o0A, float* __restrict__ zA,
    float* __restrict__ UcA, float* __restrict__ PTcA)
{
  const int blk = blockIdx.x;
  const int bh = blk & 31, c = blk >> 5;
  const int b = bh >> 4, h = bh & 15;
  const int tid = threadIdx.x;
  const int i = tid >> 3, q = tid & 7, j0 = q * 8;
  const size_t base0 = (size_t)b*2048*1024 + (size_t)h*64 + (size_t)(c*64)*1024;

  __shared__ __align__(16) float smem[6144];   // 2x3072 f32 staging; [64][65] tail fits

  // staging: 384 active lanes; lane -> (array a0, step s0, ch-oct f0)
  const int active = (tid < 384);
  const int a0 = tid >> 6, rm0 = tid & 63, s0 = rm0 >> 3, f0 = rm0 & 7;
  const f16* pa0 = (a0==0) ? ewA : (a0==1) ? kkA : (a0==2) ? bbA :
                   (a0==3) ? kA  : (a0==4) ? rA  : vA;
  const f16* src0 = pa0 + base0 + (size_t)s0*1024 + f0*8;
  const int dst0 = a0*512 + s0*64 + f0*8;

  f32x2 u2[4], p2[4];
#pragma unroll
  for (int e = 0; e < 4; ++e) {
    u2[e] = f32x2{0.f, 0.f};
    float p0 = (j0 + 2*e     == i) ? 1.f : 0.f;
    float p1 = (j0 + 2*e + 1 == i) ? 1.f : 0.f;
    p2[e] = f32x2{p0, p1};
  }

  if (active) {
    half8 hh = *(const half8*)(src0);
    float4 lo = {(float)hh[0], (float)hh[1], (float)hh[2], (float)hh[3]};
    float4 hi = {(float)hh[4], (float)hh[5], (float)hh[6], (float)hh[7]};
    *(float4*)&smem[dst0]     = lo;
    *(float4*)&smem[dst0 + 4] = hi;
  }
  __syncthreads();

  int curb = 0;
  for (int g = 0; g < 8; ++g) {
    half8 n0;
    if (g < 7 && active) n0 = *(const half8*)(src0 + (size_t)(g+1)*8192);
    const float* sb = smem + curb*3072;
#pragma unroll
    for (int s = 0; s < 8; ++s)
      step_pk(sb, s, u2, p2, o0A, zA, base0 + (size_t)(g*8 + s)*1024, i, q, j0);
    if (g < 7 && active) {
      float4 lo = {(float)n0[0], (float)n0[1], (float)n0[2], (float)n0[3]};
      float4 hi = {(float)n0[4], (float)n0[5], (float)n0[6], (float)n0[7]};
      *(float4*)&smem[(curb^1)*3072 + dst0]     = lo;
      *(float4*)&smem[(curb^1)*3072 + dst0 + 4] = hi;
    }
    __syncthreads();
    curb ^= 1;
  }

  // store U_c (row-major [i][j]) and P_c^T (row-major [j][m]) for pass 2
  const size_t cbase = ((size_t)(bh*32 + c)) * 4096;
  *(float4*)(UcA + cbase + (size_t)i*64 + j0)     = make_float4(u2[0].x,u2[0].y,u2[1].x,u2[1].y);
  *(float4*)(UcA + cbase + (size_t)i*64 + j0 + 4) = make_float4(u2[2].x,u2[2].y,u2[3].x,u2[3].y);
  float (*lds)[65] = (float(*)[65])smem;
#pragma unroll
  for (int e = 0; e < 4; ++e) {
    lds[i][j0 + 2*e]     = p2[e].x;
    lds[i][j0 + 2*e + 1] = p2[e].y;
  }
  __syncthreads();
  float4 w0 = make_float4(lds[j0+0][i], lds[j0+1][i], lds[j0+2][i], lds[j0+3][i]);
  float4 w1 = make_float4(lds[j0+4][i], lds[j0+5][i], lds[j0+6][i], lds[j0+7][i]);
  *(float4*)(PTcA + cbase + (size_t)i*64 + j0)     = w0;
  *(float4*)(PTcA + cbase + (size_t)i*64 + j0 + 4) = w1;
}

//==================== 6b. chain: S_{c+1} = U_c + S_c @ P_c (split-bf16, fp32-grade) ====================
__device__ __forceinline__ void chain_body(int c, int bh, int w, int lr, int lq,
    float (&Slds)[64][65], f32x4 (&acc)[4],
    float (&u_c)[4][4], float4 (&p_c)[2][2],
    float (&u_n)[4][4], float4 (&p_n)[2][2],
    const float* __restrict__ UcA, const float* __restrict__ PTcA,
    float* __restrict__ S0A)
{
  const size_t s0base = ((size_t)bh*32 + c) * 4096;
#pragma unroll
  for (int mt = 0; mt < 4; ++mt)
#pragma unroll
    for (int rg = 0; rg < 4; ++rg) {
      Slds[mt*16 + lq*4 + rg][w*16 + lr] = acc[mt][rg];
      if (c > 0) S0A[s0base + (size_t)(mt*16 + lq*4 + rg)*64 + w*16 + lr] = acc[mt][rg];
    }
  __syncthreads();
  if (c + 1 < 32) {
    const size_t nbase = ((size_t)bh*32 + c + 1) * 4096;
#pragma unroll
    for (int mt = 0; mt < 4; ++mt)
#pragma unroll
      for (int rg = 0; rg < 4; ++rg)
        u_n[mt][rg] = UcA[nbase + (size_t)(mt*16 + lq*4 + rg)*64 + w*16 + lr];
#pragma unroll
    for (int kt = 0; kt < 2; ++kt)
#pragma unroll
      for (int hh = 0; hh < 2; ++hh)
        p_n[kt][hh] = *(const float4*)(PTcA + nbase + (size_t)(w*16 + lr)*64 + kt*32 + lq*8 + hh*4);
  }
  short8 pbh[2], pbl[2];
#pragma unroll
  for (int kt = 0; kt < 2; ++kt) {
    float f[8] = {p_c[kt][0].x, p_c[kt][0].y, p_c[kt][0].z, p_c[kt][0].w,
                  p_c[kt][1].x, p_c[kt][1].y, p_c[kt][1].z, p_c[kt][1].w};
    split8(f, pbh[kt], pbl[kt]);
  }
  f32x4 nacc[4];
#pragma unroll
  for (int mt = 0; mt < 4; ++mt) {
    f32x4 z = {u_c[mt][0], u_c[mt][1], u_c[mt][2], u_c[mt][3]};
    nacc[mt] = z;
  }
#pragma unroll
  for (int kt = 0; kt < 2; ++kt)
#pragma unroll
    for (int mt = 0; mt < 4; ++mt) {
      float f[8];
#pragma unroll
      for (int e = 0; e < 8; ++e) f[e] = Slds[mt*16 + lr][kt*32 + lq*8 + e];
      short8 sah, sal;
      split8(f, sah, sal);
      nacc[mt] = __builtin_amdgcn_mfma_f32_16x16x32_bf16(sah, pbh[kt], nacc[mt], 0, 0, 0);
      nacc[mt] = __builtin_amdgcn_mfma_f32_16x16x32_bf16(sal, pbh[kt], nacc[mt], 0, 0, 0);
      nacc[mt] = __builtin_amdgcn_mfma_f32_16x16x32_bf16(sah, pbl[kt], nacc[mt], 0, 0, 0);
    }
#pragma unroll
  for (int mt = 0; mt < 4; ++mt) acc[mt] = nacc[mt];
  __syncthreads();
}

__global__ __launch_bounds__(256) void k_chain(
    const float* __restrict__ UcA, const float* __restrict__ PTcA,
    float* __restrict__ S0A)
{
  const int bh = blockIdx.x;
  const int l = threadIdx.x & 63, w = threadIdx.x >> 6;
  const int lr = l & 15, lq = l >> 4;
  __shared__ float Slds[64][65];

  f32x4 acc[4];
#pragma unroll
  for (int mt = 0; mt < 4; ++mt) { f32x4 z = {0.f,0.f,0.f,0.f}; acc[mt] = z; }

  float u0[4][4], u1[4][4];
  float4 p0[2][2], p1[2][2];
  {
    const size_t cbase = (size_t)bh * 32 * 4096;
#pragma unroll
    for (int mt = 0; mt < 4; ++mt)
#pragma unroll
      for (int rg = 0; rg < 4; ++rg)
        u0[mt][rg] = UcA[cbase + (size_t)(mt*16 + lq*4 + rg)*64 + w*16 + lr];
#pragma unroll
    for (int kt = 0; kt < 2; ++kt)
#pragma unroll
      for (int hh = 0; hh < 2; ++hh)
        p0[kt][hh] = *(const float4*)(PTcA + cbase + (size_t)(w*16 + lr)*64 + kt*32 + lq*8 + hh*4);
  }
  for (int c = 0; c < 32; c += 2) {
    chain_body(c,     bh, w, lr, lq, Slds, acc, u0, p0, u1, p1, UcA, PTcA, S0A);
    chain_body(c + 1, bh, w, lr, lq, Slds, acc, u1, p1, u0, p0, UcA, PTcA, S0A);
  }
}

//==================== 6c. fused correction + GroupNorm + bonus + gate -> fp16 y ====================
__global__ __launch_bounds__(256) void k_corrpost(
    const float* __restrict__ S0A, const float* __restrict__ zA,
    const float* __restrict__ o0A, const f16* __restrict__ rA,
    const f16* __restrict__ kA, const f16* __restrict__ vA,
    const float* __restrict__ rk, const float* __restrict__ gnw,
    const float* __restrict__ gnb, const f16* __restrict__ gA,
    f16* __restrict__ yH)
{
  const int blk = blockIdx.x;
  const int bh = blk & 31;
  const int c  = blk >> 5;               // 0..31
  const int b = bh >> 4, h = bh & 15;
  const int l = threadIdx.x & 63, w = threadIdx.x >> 6;
  const int lr = l & 15, lq = l >> 4;

  f32x4 a2[4];
#pragma unroll
  for (int nt = 0; nt < 4; ++nt) { f32x4 z = {0.f,0.f,0.f,0.f}; a2[nt] = z; }

  if (c > 0) {
    const size_t s0base = ((size_t)bh*32 + c) * 4096;
    short8 sbh[4][2], sbl[4][2];
#pragma unroll
    for (int nt = 0; nt < 4; ++nt)
#pragma unroll
      for (int kt = 0; kt < 2; ++kt) {
        float f[8];
#pragma unroll
        for (int e = 0; e < 8; ++e)
          f[e] = S0A[s0base + (size_t)(nt*16 + lr)*64 + kt*32 + lq*8 + e];
        split8(f, sbh[nt][kt], sbl[nt][kt]);
      }
    short8 zh[2], zl[2];
#pragma unroll
    for (int kt = 0; kt < 2; ++kt) {
      const float* zp = zA + ((size_t)(b*2048 + c*64 + w*16 + lr)*16 + h)*64 + kt*32 + lq*8;
      float f[8];
#pragma unroll
      for (int e = 0; e < 8; ++e) f[e] = zp[e];
      split8(f, zh[kt], zl[kt]);
    }
#pragma unroll
    for (int kt = 0; kt < 2; ++kt)
#pragma unroll
      for (int nt = 0; nt < 4; ++nt) {
        a2[nt] = __builtin_amdgcn_mfma_f32_16x16x32_bf16(zh[kt], sbh[nt][kt], a2[nt], 0, 0, 0);
        a2[nt] = __builtin_amdgcn_mfma_f32_16x16x32_bf16(zl[kt], sbh[nt][kt], a2[nt], 0, 0, 0);
        a2[nt] = __builtin_amdgcn_mfma_f32_16x16x32_bf16(zh[kt], sbl[nt][kt], a2[nt], 0, 0, 0);
      }
  }

#pragma unroll
  for (int rg = 0; rg < 4; ++rg) {
    const int tl = w*16 + lq*4 + rg;
    const size_t trow = (size_t)(b*2048 + c*64 + tl);
    const size_t rb = trow*1024 + h*64;
    float o4[4], v4[4];
    float sum = 0.f, pr = 0.f;
#pragma unroll
    for (int nt = 0; nt < 4; ++nt) {
      const int ii = nt*16 + lr;
      float o = o0A[rb + ii] + a2[nt][rg];
      o4[nt] = o; sum += o;
      v4[nt] = (float)vA[rb + ii];
      pr += (float)rA[rb + ii] * (float)kA[rb + ii] * rk[h*64 + ii];
    }
    sum += __shfl_xor(sum,1); sum += __shfl_xor(sum,2);
    sum += __shfl_xor(sum,4); sum += __shfl_xor(sum,8);
    pr  += __shfl_xor(pr,1);  pr  += __shfl_xor(pr,2);
    pr  += __shfl_xor(pr,4);  pr  += __shfl_xor(pr,8);
    float mean = sum * (1.f/64.f);
    float vp = 0.f;
#pragma unroll
    for (int nt = 0; nt < 4; ++nt) { float d = o4[nt]-mean; vp += d*d; }
    vp += __shfl_xor(vp,1); vp += __shfl_xor(vp,2);
    vp += __shfl_xor(vp,4); vp += __shfl_xor(vp,8);
    float inv = rsqrtf(vp*(1.f/64.f) + 1e-5f);
#pragma unroll
    for (int nt = 0; nt < 4; ++nt) {
      const int ii = nt*16 + lr;
      const int ch = h*64 + ii;
      float y = (o4[nt]-mean)*inv*gnw[ch] + gnb[ch];
      y = fmaf(pr, v4[nt], y);
      y *= (float)gA[rb + ii];
      yH[trow*1024 + ch] = (f16)y;
    }
  }
}

//==================== host ====================
extern "C" void kernel_launch(void* const* d_in, const int* in_sizes, int n_in,
                              void* d_out, int out_size, void* d_ws, size_t ws_size,
                              hipStream_t stream)
{
  (void)in_sizes; (void)n_in; (void)out_size; (void)ws_size;
  const float* hs     = (const float*)d_in[0];
  const float* x_r    = (const float*)d_in[1];
  const float* x_w    = (const float*)d_in[2];
  const float* x_k    = (const float*)d_in[3];
  const float* x_v    = (const float*)d_in[4];
  const float* x_a    = (const float*)d_in[5];
  const float* k_k    = (const float*)d_in[7];
  const float* k_a    = (const float*)d_in[8];
  const float* r_k    = (const float*)d_in[9];
  const float* W_r    = (const float*)d_in[10];
  const float* W_k    = (const float*)d_in[11];
  const float* W_v    = (const float*)d_in[12];
  const float* W_o    = (const float*)d_in[13];
  const float* wla    = (const float*)d_in[14];
  const float* wlb    = (const float*)d_in[15];
  const float* wlbias = (const float*)d_in[16];
  const float* ala    = (const float*)d_in[17];
  const float* alb    = (const float*)d_in[18];
  const float* albias = (const float*)d_in[19];
  const float* gla    = (const float*)d_in[20];
  const float* glb    = (const float*)d_in[21];
  const float* glbias = (const float*)d_in[22];
  const float* gnw    = (const float*)d_in[23];
  const float* gnb    = (const float*)d_in[24];

  char* ws = (char*)d_ws;
  size_t cur = 0;
  auto take = [&](size_t bytes) { size_t o = cur; cur += (bytes + 255) & ~(size_t)255; return o; };

  // fp16 x operands [4096][1024] (8MB each); xk,xv consecutive (S0_f spans them)
  f16* xr_h = (f16*)(ws + take((size_t)4096*1024*2));
  f16* xw_h = (f16*)(ws + take((size_t)4096*1024*2));
  f16* xk_h = (f16*)(ws + take((size_t)4096*1024*2));
  f16* xv_h = (f16*)(ws + take((size_t)4096*1024*2));
  f16* xa_h = (f16*)(ws + take((size_t)4096*1024*2));
  // fp16 weights
  f16* Wr_p  = (f16*)(ws + take((size_t)1024*1024*2));
  f16* Wk_p  = (f16*)(ws + take((size_t)1024*1024*2));
  f16* Wv_p  = (f16*)(ws + take((size_t)1024*1024*2));
  f16* Wo_p  = (f16*)(ws + take((size_t)1024*1024*2));
  f16* wla_p = (f16*)(ws + take((size_t)128*1024*2));
  f16* wlb_p = (f16*)(ws + take((size_t)1024*64*2));
  f16* ala_p = (f16*)(ws + take((size_t)128*1024*2));
  f16* alb_p = (f16*)(ws + take((size_t)1024*64*2));
  f16* gla_p = (f16*)(ws + take((size_t)128*1024*2));
  f16* glb_p = (f16*)(ws + take((size_t)1024*128*2));
  // fp16 scan operands
  f16* r_h  = (f16*)(ws + take((size_t)4096*1024*2));
  f16* k_h  = (f16*)(ws + take((size_t)4096*1024*2));
  f16* v_h  = (f16*)(ws + take((size_t)4096*1024*2));
  f16* kk_h = (f16*)(ws + take((size_t)4096*1024*2));
  f16* g_h  = (f16*)(ws + take((size_t)4096*1024*2));
  f16* t2w  = (f16*)(ws + take((size_t)4096*64*2));
  f16* t2a  = (f16*)(ws + take((size_t)4096*64*2));
  f16* t2g  = (f16*)(ws + take((size_t)4096*128*2));
  // fp32 buffers
  float* z_f  = (float*)(ws + take((size_t)4096*1024*4));
  float* Uc_f = (float*)(ws + take((size_t)4096*1024*4));
  float* PT_f = (float*)(ws + take((size_t)4096*1024*4));
  // aliases (lifetime-checked against launch order):
  f16*   ew_h = xw_h;            // xw read L2 (w-s1); ew written L3, read p1 L6
  f16*   a_h  = xa_h;            // xa read L2 (a-s1); a written L3, scanprep L5 -> bb, read p1 L6
  f16*   y_h  = xr_h;            // xr read L2 (r); y written L8, read L9
  float* S0_f = (float*)xk_h;    // spans xk_h+xv_h (16MB, consecutive); both dead after L2;
                                 // S0 written L7, read L8
  float* oF   = (float*)d_out;   // o0 lives in d_out until L9 overwrites

  // L1: prep -> 5 fp16 operands
  k_prep<<<4096, 256, 0, stream>>>(hs, x_r, x_w, x_k, x_v, x_a,
                                   xr_h, xw_h, xk_h, xv_h, xa_h);
  // L1b: weight transpose -> fp16
  SrcP sp; DstP dp;
  sp.p[0]=W_r; sp.p[1]=W_k; sp.p[2]=W_v; sp.p[3]=W_o;
  sp.p[4]=wla; sp.p[5]=wlb; sp.p[6]=ala; sp.p[7]=alb; sp.p[8]=gla; sp.p[9]=glb;
  dp.p[0]=Wr_p; dp.p[1]=Wk_p; dp.p[2]=Wv_p; dp.p[3]=Wo_p;
  dp.p[4]=wla_p; dp.p[5]=wlb_p; dp.p[6]=ala_p; dp.p[7]=alb_p; dp.p[8]=gla_p; dp.p[9]=glb_p;
  k_transpose<<<dim3(32,32,10), dim3(32,8), 0, stream>>>(sp, dp);

  GJobs J{};
  auto job = [](const f16* A, const f16* Bt, float* C, f16* Cpk, const float* bias,
                int K, int N, int Npk, int ldc, int act, int lda, int ldb) {
    GJob j; j.A=A; j.Bt=Bt; j.C=C; j.Cpk=Cpk; j.bias=bias;
    j.K=K; j.N=N; j.Npk=Npk; j.ldc=ldc; j.act=act; j.lda=lda; j.ldb=ldb;
    return j;
  };

  // L2: r, k, v (fp16 outs), w-s1(tanh->t2w), a-s1(->t2a)
  J.j[0] = job(xr_h, Wr_p,  nullptr, r_h, nullptr, 1024, 1024, 1024, 0, 0, 1024, 1024);
  J.j[1] = job(xk_h, Wk_p,  nullptr, k_h, nullptr, 1024, 1024, 1024, 0, 0, 1024, 1024);
  J.j[2] = job(xv_h, Wv_p,  nullptr, v_h, nullptr, 1024, 1024, 1024, 0, 0, 1024, 1024);
  J.j[3] = job(xw_h, wla_p, nullptr, t2w, nullptr, 1024, 128,  64,   0, 2, 1024, 1024);
  J.j[4] = job(xa_h, ala_p, nullptr, t2a, nullptr, 1024, 128,  64,   0, 0, 1024, 1024);
  k_gemm_fp16<<<dim3(32,8,5), 256, 0, stream>>>(J);

  // L3: w-s2 (ew), a-s2 (sigmoid), g-s1 (sigmoid -> t2g)
  J = GJobs{};
  J.j[0] = job(t2w, wlb_p, nullptr, ew_h, wlbias, 64,   1024, 1024, 0, 3, 64,   64);
  J.j[1] = job(t2a, alb_p, nullptr, a_h,  albias, 64,   1024, 1024, 0, 1, 64,   64);
  J.j[2] = job(r_h, gla_p, nullptr, t2g,  nullptr, 1024, 128,  128,  0, 1, 1024, 1024);
  k_gemm_fp16<<<dim3(32,8,3), 256, 0, stream>>>(J);

  // L4: g-s2 (+bias)
  J = GJobs{};
  J.j[0] = job(t2g, glb_p, nullptr, g_h, glbias, 128, 1024, 1024, 0, 0, 128, 128);
  k_gemm_fp16<<<dim3(32,8,1), 256, 0, stream>>>(J);

  // L5: kk normalize + k update + b precompute (fp16 I/O)
  k_scanprep<<<2048, 256, 0, stream>>>(k_h, a_h, k_k, k_a, kk_h);

  // L6-L7: chunked scan
  k_scan_p1<<<1024, 512, 0, stream>>>(r_h, ew_h, k_h, v_h, kk_h, a_h, oF, z_f, Uc_f, PT_f);
  k_chain<<<32, 256, 0, stream>>>(Uc_f, PT_f, S0_f);

  // L8: fused correction + groupnorm + bonus + gate -> fp16 y
  k_corrpost<<<1024, 256, 0, stream>>>(S0_f, z_f, oF, r_h, k_h, v_h,
                                       r_k, gnw, gnb, g_h, y_h);

  // L9: output projection (overwrites d_out)
  J = GJobs{};
  J.j[0] = job(y_h, Wo_p, (float*)d_out, nullptr, nullptr, 1024, 1024, 0, 1024, 0, 1024, 1024);
  k_gemm_fp16<<<dim3(32,8,1), 256, 0, stream>>>(J);
}

// Round 14
// 322.752 us; speedup vs baseline: 1.5729x; 1.0282x over previous
//
#include <hip/hip_runtime.h>
#include <hip/hip_bf16.h>
#include <hip/hip_fp16.h>
#include <stdint.h>
#include <stddef.h>

typedef __hip_bfloat16 bf16;
typedef _Float16 f16;
typedef __attribute__((ext_vector_type(8))) short short8;
typedef __attribute__((ext_vector_type(8))) _Float16 half8;
typedef __attribute__((ext_vector_type(4))) float f32x4;
typedef __attribute__((ext_vector_type(2))) float f32x2;
typedef unsigned short us;

__device__ __forceinline__ float dsigm(float z){ return 1.f/(1.f+expf(-z)); }

// DPP lane-group(8) sum: xor1 (quad_perm 0xB1), xor2 (quad_perm 0x4E), xor4 (row_half_mirror 0x141)
template<int CTRL>
__device__ __forceinline__ float dpp_term(float x) {
  int xi = __builtin_bit_cast(int, x);
  int yi = __builtin_amdgcn_update_dpp(0, xi, CTRL, 0xF, 0xF, false);
  return __builtin_bit_cast(float, yi);
}
__device__ __forceinline__ float red8(float x) {
  x += dpp_term<0xB1>(x);
  x += dpp_term<0x4E>(x);
  x += dpp_term<0x141>(x);
  return x;
}

// split fp32 -> hi (rounded bf16) + lo (rounded bf16 residual); scan-side MFMA only
__device__ __forceinline__ void split1(float v, us& h, us& l) {
  bf16 hb = __float2bfloat16(v);
  h = __builtin_bit_cast(us, hb);
  float hf = __bfloat162float(hb);
  bf16 lb = __float2bfloat16(v - hf);
  l = __builtin_bit_cast(us, lb);
}

__device__ __forceinline__ void split8(const float* f, short8& h, short8& l) {
#pragma unroll
  for (int e = 0; e < 8; ++e) {
    us hh, ll;
    split1(f[e], hh, ll);
    h[e] = (short)hh; l[e] = (short)ll;
  }
}

// async global->LDS, 16B per lane (dest = wave-uniform base + lane*16)
__device__ __forceinline__ void gl16(const f16* g, f16* l) {
  __builtin_amdgcn_global_load_lds((const __attribute__((address_space(1))) void*)g,
                                   (__attribute__((address_space(3))) void*)l, 16, 0, 0);
}

//==================== 1. time-shift lerp -> fp16 operands ====================
__device__ __forceinline__ void emit16(const float* __restrict__ marr, int c4,
    const float4& cur, const float4& dlt, f16* __restrict__ out, int row)
{
  float4 m = *(const float4*)(marr + c4);
  f16* o = out + (size_t)row*1024 + c4;
  o[0] = (f16)fmaf(dlt.x, m.x, cur.x);
  o[1] = (f16)fmaf(dlt.y, m.y, cur.y);
  o[2] = (f16)fmaf(dlt.z, m.z, cur.z);
  o[3] = (f16)fmaf(dlt.w, m.w, cur.w);
}

__global__ void k_prep(const float* __restrict__ hs,
    const float* __restrict__ mr, const float* __restrict__ mw, const float* __restrict__ mk,
    const float* __restrict__ mv, const float* __restrict__ ma,
    f16* __restrict__ oxr, f16* __restrict__ oxw, f16* __restrict__ oxk,
    f16* __restrict__ oxv, f16* __restrict__ oxa)
{
  int id = blockIdx.x * 256 + threadIdx.x;
  int row = id >> 8;
  int c4 = (id & 255) << 2;
  int t = row & 2047;
  const float* hp = hs + (size_t)row*1024 + c4;
  float4 cur = *(const float4*)hp;
  float4 prev = make_float4(0.f,0.f,0.f,0.f);
  if (t > 0) prev = *(const float4*)(hp - 1024);
  float4 dlt = make_float4(prev.x-cur.x, prev.y-cur.y, prev.z-cur.z, prev.w-cur.w);
  emit16(mr, c4, cur, dlt, oxr, row);
  emit16(mw, c4, cur, dlt, oxw, row);
  emit16(mk, c4, cur, dlt, oxk, row);
  emit16(mv, c4, cur, dlt, oxv, row);
  emit16(ma, c4, cur, dlt, oxa, row);
}

//==================== 2. weight transpose -> fp16 ====================
struct SrcP { const float* p[10]; };
struct DstP { f16* p[10]; };

__global__ void k_transpose(SrcP S, DstP Dd)
{
  static constexpr int TR[10]  = {1024,1024,1024,1024,1024,  64,1024,  64,1024, 128};
  static constexpr int TCC[10] = {1024,1024,1024,1024,  64,1024,  64,1024, 128,1024};
  static constexpr int TCP[10] = {1024,1024,1024,1024, 128,1024, 128,1024, 128,1024};
  int z = blockIdx.z;
  int R = TR[z], Cc = TCC[z], Cp = TCP[z];
  int n0 = blockIdx.x * 32, r0 = blockIdx.y * 32;
  if (n0 >= Cp || r0 >= R) return;
  const float* src = S.p[z];
  f16* dst = Dd.p[z];
  int tx = threadIdx.x, ty = threadIdx.y;
  __shared__ float tile[32][33];
  if (n0 < Cc) {
#pragma unroll
    for (int i = 0; i < 4; ++i)
      tile[ty + 8*i][tx] = src[(size_t)(r0 + ty + 8*i)*Cc + n0 + tx];
    __syncthreads();
#pragma unroll
    for (int i = 0; i < 4; ++i)
      dst[(size_t)(n0 + ty + 8*i)*R + r0 + tx] = (f16)tile[tx][ty + 8*i];
  } else {
#pragma unroll
    for (int i = 0; i < 4; ++i)
      dst[(size_t)(n0 + ty + 8*i)*R + r0 + tx] = (f16)0.f;
  }
}

//==================== 3. batched fp16 MFMA GEMM (BK=64, XOR-swizzled LDS) ====================
// LDS tiles [128][64] f16 (stride 128B). 16B-unit swizzle cu^=(row&7) applied to BOTH
// the per-lane global staging source and the ds_read address (linear gl_lds dest) —
// conflict-free fragment reads (rule #21 correct form).
struct GJob {
  const f16* A;              // [4096][lda]
  const f16* Bt;             // [N][ldb]
  float* C;                  // optional fp32 out [4096][ldc]
  f16* Cpk;                  // optional fp16 out [4096][Npk]
  const float* bias;         // optional per-col (added before act)
  int K; int N; int Npk; int ldc; int act;   // act: 0 none, 1 sigmoid, 2 tanh, 3 e^-.5*sigmoid
  int lda; int ldb;
};
struct GJobs { GJob j[5]; };

__global__ __launch_bounds__(256) void k_gemm_fp16(GJobs jobs)
{
  GJob jb = jobs.j[blockIdx.z];
  const int colBase = blockIdx.y * 128;
  if (colBase >= jb.N) return;
  const int rowBase = blockIdx.x * 128;
  __shared__ __align__(16) f16 As[128*64];
  __shared__ __align__(16) f16 Bs[128*64];
  const int tid = threadIdx.x;
  const int l = tid & 63, w = tid >> 6;
  const int wm = w >> 1, wn = w & 1;
  const int lrow = l & 15;
  const int nk = jb.K >> 6;

  // staging geometry: call i (0..3): slot s=(i*4+w)*64+l covers 8 f16;
  // row=s>>3, unit=s&7; SOURCE col pre-swizzled: (unit^(row&7))*8
  const f16* Arow[4]; const f16* Brow[4]; int ld[4];
#pragma unroll
  for (int i2 = 0; i2 < 4; ++i2) {
    int s = (i2*4 + w)*64 + l;
    int ar = s >> 3;
    int unit = s & 7;
    int acs = (unit ^ (ar & 7)) * 8;
    Arow[i2] = jb.A  + (size_t)(rowBase + ar)*jb.lda + acs;
    Brow[i2] = jb.Bt + (size_t)(colBase + ar)*jb.ldb + acs;
    ld[i2] = (i2*4 + w) * 512;
  }

  f32x4 acc[4][4];
#pragma unroll
  for (int i = 0; i < 4; ++i)
#pragma unroll
    for (int j = 0; j < 4; ++j) { f32x4 z = {0.f,0.f,0.f,0.f}; acc[i][j] = z; }

  for (int kt = 0; kt < nk; ++kt) {
    const int kh = kt*64;
#pragma unroll
    for (int i2 = 0; i2 < 4; ++i2) {
      gl16(Arow[i2] + kh, &As[ld[i2]]);
      gl16(Brow[i2] + kh, &Bs[ld[i2]]);
    }
    __syncthreads();
#pragma unroll
    for (int ks = 0; ks < 2; ++ks) {
      half8 ah[4], bh[4];
#pragma unroll
      for (int mt = 0; mt < 4; ++mt) {
        int row = wm*64 + mt*16 + lrow;
        int cu = ks*4 + (l >> 4);
        ah[mt] = *(const half8*)&As[row*64 + ((cu ^ (row & 7)) * 8)];
      }
#pragma unroll
      for (int nt = 0; nt < 4; ++nt) {
        int row = wn*64 + nt*16 + lrow;
        int cu = ks*4 + (l >> 4);
        bh[nt] = *(const half8*)&Bs[row*64 + ((cu ^ (row & 7)) * 8)];
      }
#pragma unroll
      for (int mt = 0; mt < 4; ++mt)
#pragma unroll
        for (int nt = 0; nt < 4; ++nt)
          acc[mt][nt] = __builtin_amdgcn_mfma_f32_16x16x32_f16(ah[mt], bh[nt], acc[mt][nt], 0, 0, 0);
    }
    __syncthreads();
  }
#pragma unroll
  for (int mt = 0; mt < 4; ++mt) {
    int row = rowBase + wm*64 + mt*16 + (l >> 4)*4;
#pragma unroll
    for (int nt = 0; nt < 4; ++nt) {
      int col = colBase + wn*64 + nt*16 + (l & 15);
      float bv = (jb.bias != nullptr) ? jb.bias[col] : 0.f;
#pragma unroll
      for (int rg = 0; rg < 4; ++rg) {
        float v = acc[mt][nt][rg] + bv;
        if (jb.act == 1)      v = dsigm(v);
        else if (jb.act == 2) v = tanhf(v);
        else if (jb.act == 3) v = 0.60653066f * dsigm(v);
        if (jb.C) jb.C[(size_t)(row + rg)*jb.ldc + col] = v;
        if (jb.Cpk && col < jb.Npk)
          jb.Cpk[(size_t)(row + rg)*jb.Npk + col] = (f16)v;
      }
    }
  }
}

//==================== 5. scan prep (fp16 I/O): kk normalize + k update + b=kk*a ====================
__global__ void k_scanprep(f16* __restrict__ kA, f16* __restrict__ aA,
                           const float* __restrict__ kkw, const float* __restrict__ kaw,
                           f16* __restrict__ kkA)
{
  int idx = blockIdx.x * 256 + threadIdx.x;      // 524288 threads, 8 elems each
  size_t gt8 = (size_t)idx * 8;
  int ch = (int)(gt8 & 1023);
  half8 k8 = *(const half8*)(kA + gt8);
  half8 a8 = *(const half8*)(aA + gt8);
  float kw[8], ka_[8];
  *(float4*)&kw[0]  = *(const float4*)(kkw + ch);
  *(float4*)&kw[4]  = *(const float4*)(kkw + ch + 4);
  *(float4*)&ka_[0] = *(const float4*)(kaw + ch);
  *(float4*)&ka_[4] = *(const float4*)(kaw + ch + 4);
  float kkv[8]; float ss = 0.f;
#pragma unroll
  for (int e = 0; e < 8; ++e) { kkv[e] = (float)k8[e] * kw[e]; ss += kkv[e]*kkv[e]; }
  ss += __shfl_xor(ss, 1); ss += __shfl_xor(ss, 2); ss += __shfl_xor(ss, 4);
  float inv = 1.f / fmaxf(sqrtf(ss), 1e-12f);
  half8 kkn8, bb8, kup8;
#pragma unroll
  for (int e = 0; e < 8; ++e) {
    float kkn = kkv[e] * inv;
    float av = (float)a8[e];
    kkn8[e] = (f16)kkn;
    bb8[e]  = (f16)(kkn * av);
    kup8[e] = (f16)((float)k8[e] * fmaf(av - 1.f, ka_[e], 1.f));
  }
  *(half8*)(kkA + gt8) = kkn8;
  *(half8*)(aA + gt8)  = bb8;
  *(half8*)(kA + gt8)  = kup8;
}

//==================== 6a. chunked scan pass 1 ====================
// f16 global operands; staging lanes convert once -> f32 LDS [6][8][64] per buffer
// (12KB, double-buffered 24KB). Step math in packed f32x2 (v_pk_fma_f32), reductions
// via DPP adds. Arrays: 0=ew 1=kk 2=bb 3=k 4=r 5=v.
__device__ __forceinline__ void step_pk(const float* __restrict__ sb, int s,
    f32x2* u2, f32x2* p2, float* __restrict__ o0A, float* __restrict__ zA,
    size_t base, int i, int q, int j0)
{
  f32x2 ew2[4], kk2[4], bb2[4], kv2[4], rr2[4];
#pragma unroll
  for (int hh = 0; hh < 2; ++hh) {
    float4 a0 = *(const float4*)(sb + 0    + s*64 + j0 + hh*4);
    float4 a1 = *(const float4*)(sb + 512  + s*64 + j0 + hh*4);
    float4 a2 = *(const float4*)(sb + 1024 + s*64 + j0 + hh*4);
    float4 a3 = *(const float4*)(sb + 1536 + s*64 + j0 + hh*4);
    float4 a4 = *(const float4*)(sb + 2048 + s*64 + j0 + hh*4);
    ew2[hh*2+0] = f32x2{a0.x, a0.y}; ew2[hh*2+1] = f32x2{a0.z, a0.w};
    kk2[hh*2+0] = f32x2{a1.x, a1.y}; kk2[hh*2+1] = f32x2{a1.z, a1.w};
    bb2[hh*2+0] = f32x2{a2.x, a2.y}; bb2[hh*2+1] = f32x2{a2.z, a2.w};
    kv2[hh*2+0] = f32x2{a3.x, a3.y}; kv2[hh*2+1] = f32x2{a3.z, a3.w};
    rr2[hh*2+0] = f32x2{a4.x, a4.y}; rr2[hh*2+1] = f32x2{a4.z, a4.w};
  }
  float vi = sb[2560 + s*64 + i];

  f32x2 uk2 = u2[0]*kk2[0], pk2 = p2[0]*kk2[0];
#pragma unroll
  for (int e = 1; e < 4; ++e) { uk2 += u2[e]*kk2[e]; pk2 += p2[e]*kk2[e]; }
  float uk = red8(uk2.x + uk2.y);
  float pk = red8(pk2.x + pk2.y);
  const f32x2 su2 = {-uk, -uk}, sp2 = {-pk, -pk}, vi2 = {vi, vi};
  f32x2 oo2 = {0.f, 0.f}, zz2 = {0.f, 0.f};
#pragma unroll
  for (int e = 0; e < 4; ++e) {
    f32x2 uu = u2[e]*ew2[e] + su2*bb2[e] + vi2*kv2[e];
    u2[e] = uu; oo2 += uu*rr2[e];
    f32x2 pp = p2[e]*ew2[e] + sp2*bb2[e];
    p2[e] = pp; zz2 += pp*rr2[e];
  }
  float oo = red8(oo2.x + oo2.y);
  float zz = red8(zz2.x + zz2.y);
  if (q == 0) { o0A[base + i] = oo; zA[base + i] = zz; }
}

__global__ __launch_bounds__(512) void k_scan_p1(
    const f16* __restrict__ rA, const f16* __restrict__ ewA,
    const f16* __restrict__ kA, const f16* __restrict__ vA,
    const f16* __restrict__ kkA, const f16* __restrict__ bbA,
    float* __restrict__ o0A, float* __restrict__ zA,
    float* __restrict__ UcA, float* __restrict__ PTcA)
{
  const int blk = blockIdx.x;
  const int bh = blk & 31, c = blk >> 5;
  const int b = bh >> 4, h = bh & 15;
  const int tid = threadIdx.x;
  const int i = tid >> 3, q = tid & 7, j0 = q * 8;
  const size_t base0 = (size_t)b*2048*1024 + (size_t)h*64 + (size_t)(c*64)*1024;

  __shared__ __align__(16) float smem[6144];   // 2x3072 f32 staging; [64][65] tail fits

  // staging: 384 active lanes; lane -> (array a0, step s0, ch-oct f0)
  const int active = (tid < 384);
  const int a0 = tid >> 6, rm0 = tid & 63, s0 = rm0 >> 3, f0 = rm0 & 7;
  const f16* pa0 = (a0==0) ? ewA : (a0==1) ? kkA : (a0==2) ? bbA :
                   (a0==3) ? kA  : (a0==4) ? rA  : vA;
  const f16* src0 = pa0 + base0 + (size_t)s0*1024 + f0*8;
  const int dst0 = a0*512 + s0*64 + f0*8;

  f32x2 u2[4], p2[4];
#pragma unroll
  for (int e = 0; e < 4; ++e) {
    u2[e] = f32x2{0.f, 0.f};
    float p0 = (j0 + 2*e     == i) ? 1.f : 0.f;
    float p1 = (j0 + 2*e + 1 == i) ? 1.f : 0.f;
    p2[e] = f32x2{p0, p1};
  }

  if (active) {
    half8 hh = *(const half8*)(src0);
    float4 lo = {(float)hh[0], (float)hh[1], (float)hh[2], (float)hh[3]};
    float4 hi = {(float)hh[4], (float)hh[5], (float)hh[6], (float)hh[7]};
    *(float4*)&smem[dst0]     = lo;
    *(float4*)&smem[dst0 + 4] = hi;
  }
  __syncthreads();

  int curb = 0;
  for (int g = 0; g < 8; ++g) {
    half8 n0;
    if (g < 7 && active) n0 = *(const half8*)(src0 + (size_t)(g+1)*8192);
    const float* sb = smem + curb*3072;
#pragma unroll
    for (int s = 0; s < 8; ++s)
      step_pk(sb, s, u2, p2, o0A, zA, base0 + (size_t)(g*8 + s)*1024, i, q, j0);
    if (g < 7 && active) {
      float4 lo = {(float)n0[0], (float)n0[1], (float)n0[2], (float)n0[3]};
      float4 hi = {(float)n0[4], (float)n0[5], (float)n0[6], (float)n0[7]};
      *(float4*)&smem[(curb^1)*3072 + dst0]     = lo;
      *(float4*)&smem[(curb^1)*3072 + dst0 + 4] = hi;
    }
    __syncthreads();
    curb ^= 1;
  }

  // store U_c (row-major [i][j]) and P_c^T (row-major [j][m]) for pass 2
  const size_t cbase = ((size_t)(bh*32 + c)) * 4096;
  *(float4*)(UcA + cbase + (size_t)i*64 + j0)     = make_float4(u2[0].x,u2[0].y,u2[1].x,u2[1].y);
  *(float4*)(UcA + cbase + (size_t)i*64 + j0 + 4) = make_float4(u2[2].x,u2[2].y,u2[3].x,u2[3].y);
  float (*lds)[65] = (float(*)[65])smem;
#pragma unroll
  for (int e = 0; e < 4; ++e) {
    lds[i][j0 + 2*e]     = p2[e].x;
    lds[i][j0 + 2*e + 1] = p2[e].y;
  }
  __syncthreads();
  float4 w0 = make_float4(lds[j0+0][i], lds[j0+1][i], lds[j0+2][i], lds[j0+3][i]);
  float4 w1 = make_float4(lds[j0+4][i], lds[j0+5][i], lds[j0+6][i], lds[j0+7][i]);
  *(float4*)(PTcA + cbase + (size_t)i*64 + j0)     = w0;
  *(float4*)(PTcA + cbase + (size_t)i*64 + j0 + 4) = w1;
}

//==================== 6b. chain: S_{c+1} = U_c + S_c @ P_c (split-bf16, fp32-grade) ====================
__device__ __forceinline__ void chain_body(int c, int bh, int w, int lr, int lq,
    float (&Slds)[64][65], f32x4 (&acc)[4],
    float (&u_c)[4][4], float4 (&p_c)[2][2],
    float (&u_n)[4][4], float4 (&p_n)[2][2],
    const float* __restrict__ UcA, const float* __restrict__ PTcA,
    float* __restrict__ S0A)
{
  const size_t s0base = ((size_t)bh*32 + c) * 4096;
#pragma unroll
  for (int mt = 0; mt < 4; ++mt)
#pragma unroll
    for (int rg = 0; rg < 4; ++rg) {
      Slds[mt*16 + lq*4 + rg][w*16 + lr] = acc[mt][rg];
      if (c > 0) S0A[s0base + (size_t)(mt*16 + lq*4 + rg)*64 + w*16 + lr] = acc[mt][rg];
    }
  __syncthreads();
  if (c + 1 < 32) {
    const size_t nbase = ((size_t)bh*32 + c + 1) * 4096;
#pragma unroll
    for (int mt = 0; mt < 4; ++mt)
#pragma unroll
      for (int rg = 0; rg < 4; ++rg)
        u_n[mt][rg] = UcA[nbase + (size_t)(mt*16 + lq*4 + rg)*64 + w*16 + lr];
#pragma unroll
    for (int kt = 0; kt < 2; ++kt)
#pragma unroll
      for (int hh = 0; hh < 2; ++hh)
        p_n[kt][hh] = *(const float4*)(PTcA + nbase + (size_t)(w*16 + lr)*64 + kt*32 + lq*8 + hh*4);
  }
  short8 pbh[2], pbl[2];
#pragma unroll
  for (int kt = 0; kt < 2; ++kt) {
    float f[8] = {p_c[kt][0].x, p_c[kt][0].y, p_c[kt][0].z, p_c[kt][0].w,
                  p_c[kt][1].x, p_c[kt][1].y, p_c[kt][1].z, p_c[kt][1].w};
    split8(f, pbh[kt], pbl[kt]);
  }
  f32x4 nacc[4];
#pragma unroll
  for (int mt = 0; mt < 4; ++mt) {
    f32x4 z = {u_c[mt][0], u_c[mt][1], u_c[mt][2], u_c[mt][3]};
    nacc[mt] = z;
  }
#pragma unroll
  for (int kt = 0; kt < 2; ++kt)
#pragma unroll
    for (int mt = 0; mt < 4; ++mt) {
      float f[8];
#pragma unroll
      for (int e = 0; e < 8; ++e) f[e] = Slds[mt*16 + lr][kt*32 + lq*8 + e];
      short8 sah, sal;
      split8(f, sah, sal);
      nacc[mt] = __builtin_amdgcn_mfma_f32_16x16x32_bf16(sah, pbh[kt], nacc[mt], 0, 0, 0);
      nacc[mt] = __builtin_amdgcn_mfma_f32_16x16x32_bf16(sal, pbh[kt], nacc[mt], 0, 0, 0);
      nacc[mt] = __builtin_amdgcn_mfma_f32_16x16x32_bf16(sah, pbl[kt], nacc[mt], 0, 0, 0);
    }
#pragma unroll
  for (int mt = 0; mt < 4; ++mt) acc[mt] = nacc[mt];
  __syncthreads();
}

__global__ __launch_bounds__(256) void k_chain(
    const float* __restrict__ UcA, const float* __restrict__ PTcA,
    float* __restrict__ S0A)
{
  const int bh = blockIdx.x;
  const int l = threadIdx.x & 63, w = threadIdx.x >> 6;
  const int lr = l & 15, lq = l >> 4;
  __shared__ float Slds[64][65];

  f32x4 acc[4];
#pragma unroll
  for (int mt = 0; mt < 4; ++mt) { f32x4 z = {0.f,0.f,0.f,0.f}; acc[mt] = z; }

  float u0[4][4], u1[4][4];
  float4 p0[2][2], p1[2][2];
  {
    const size_t cbase = (size_t)bh * 32 * 4096;
#pragma unroll
    for (int mt = 0; mt < 4; ++mt)
#pragma unroll
      for (int rg = 0; rg < 4; ++rg)
        u0[mt][rg] = UcA[cbase + (size_t)(mt*16 + lq*4 + rg)*64 + w*16 + lr];
#pragma unroll
    for (int kt = 0; kt < 2; ++kt)
#pragma unroll
      for (int hh = 0; hh < 2; ++hh)
        p0[kt][hh] = *(const float4*)(PTcA + cbase + (size_t)(w*16 + lr)*64 + kt*32 + lq*8 + hh*4);
  }
  for (int c = 0; c < 32; c += 2) {
    chain_body(c,     bh, w, lr, lq, Slds, acc, u0, p0, u1, p1, UcA, PTcA, S0A);
    chain_body(c + 1, bh, w, lr, lq, Slds, acc, u1, p1, u0, p0, UcA, PTcA, S0A);
  }
}

//==================== 6c. fused correction + GroupNorm + bonus + gate -> fp16 y ====================
__global__ __launch_bounds__(256) void k_corrpost(
    const float* __restrict__ S0A, const float* __restrict__ zA,
    const float* __restrict__ o0A, const f16* __restrict__ rA,
    const f16* __restrict__ kA, const f16* __restrict__ vA,
    const float* __restrict__ rk, const float* __restrict__ gnw,
    const float* __restrict__ gnb, const f16* __restrict__ gA,
    f16* __restrict__ yH)
{
  const int blk = blockIdx.x;
  const int bh = blk & 31;
  const int c  = blk >> 5;               // 0..31
  const int b = bh >> 4, h = bh & 15;
  const int l = threadIdx.x & 63, w = threadIdx.x >> 6;
  const int lr = l & 15, lq = l >> 4;

  f32x4 a2[4];
#pragma unroll
  for (int nt = 0; nt < 4; ++nt) { f32x4 z = {0.f,0.f,0.f,0.f}; a2[nt] = z; }

  if (c > 0) {
    const size_t s0base = ((size_t)bh*32 + c) * 4096;
    short8 sbh[4][2], sbl[4][2];
#pragma unroll
    for (int nt = 0; nt < 4; ++nt)
#pragma unroll
      for (int kt = 0; kt < 2; ++kt) {
        float f[8];
#pragma unroll
        for (int e = 0; e < 8; ++e)
          f[e] = S0A[s0base + (size_t)(nt*16 + lr)*64 + kt*32 + lq*8 + e];
        split8(f, sbh[nt][kt], sbl[nt][kt]);
      }
    short8 zh[2], zl[2];
#pragma unroll
    for (int kt = 0; kt < 2; ++kt) {
      const float* zp = zA + ((size_t)(b*2048 + c*64 + w*16 + lr)*16 + h)*64 + kt*32 + lq*8;
      float f[8];
#pragma unroll
      for (int e = 0; e < 8; ++e) f[e] = zp[e];
      split8(f, zh[kt], zl[kt]);
    }
#pragma unroll
    for (int kt = 0; kt < 2; ++kt)
#pragma unroll
      for (int nt = 0; nt < 4; ++nt) {
        a2[nt] = __builtin_amdgcn_mfma_f32_16x16x32_bf16(zh[kt], sbh[nt][kt], a2[nt], 0, 0, 0);
        a2[nt] = __builtin_amdgcn_mfma_f32_16x16x32_bf16(zl[kt], sbh[nt][kt], a2[nt], 0, 0, 0);
        a2[nt] = __builtin_amdgcn_mfma_f32_16x16x32_bf16(zh[kt], sbl[nt][kt], a2[nt], 0, 0, 0);
      }
  }

#pragma unroll
  for (int rg = 0; rg < 4; ++rg) {
    const int tl = w*16 + lq*4 + rg;
    const size_t trow = (size_t)(b*2048 + c*64 + tl);
    const size_t rb = trow*1024 + h*64;
    float o4[4], v4[4];
    float sum = 0.f, pr = 0.f;
#pragma unroll
    for (int nt = 0; nt < 4; ++nt) {
      const int ii = nt*16 + lr;
      float o = o0A[rb + ii] + a2[nt][rg];
      o4[nt] = o; sum += o;
      v4[nt] = (float)vA[rb + ii];
      pr += (float)rA[rb + ii] * (float)kA[rb + ii] * rk[h*64 + ii];
    }
    sum += __shfl_xor(sum,1); sum += __shfl_xor(sum,2);
    sum += __shfl_xor(sum,4); sum += __shfl_xor(sum,8);
    pr  += __shfl_xor(pr,1);  pr  += __shfl_xor(pr,2);
    pr  += __shfl_xor(pr,4);  pr  += __shfl_xor(pr,8);
    float mean = sum * (1.f/64.f);
    float vp = 0.f;
#pragma unroll
    for (int nt = 0; nt < 4; ++nt) { float d = o4[nt]-mean; vp += d*d; }
    vp += __shfl_xor(vp,1); vp += __shfl_xor(vp,2);
    vp += __shfl_xor(vp,4); vp += __shfl_xor(vp,8);
    float inv = rsqrtf(vp*(1.f/64.f) + 1e-5f);
#pragma unroll
    for (int nt = 0; nt < 4; ++nt) {
      const int ii = nt*16 + lr;
      const int ch = h*64 + ii;
      float y = (o4[nt]-mean)*inv*gnw[ch] + gnb[ch];
      y = fmaf(pr, v4[nt], y);
      y *= (float)gA[rb + ii];
      yH[trow*1024 + ch] = (f16)y;
    }
  }
}

//==================== host ====================
extern "C" void kernel_launch(void* const* d_in, const int* in_sizes, int n_in,
                              void* d_out, int out_size, void* d_ws, size_t ws_size,
                              hipStream_t stream)
{
  (void)in_sizes; (void)n_in; (void)out_size; (void)ws_size;
  const float* hs     = (const float*)d_in[0];
  const float* x_r    = (const float*)d_in[1];
  const float* x_w    = (const float*)d_in[2];
  const float* x_k    = (const float*)d_in[3];
  const float* x_v    = (const float*)d_in[4];
  const float* x_a    = (const float*)d_in[5];
  const float* k_k    = (const float*)d_in[7];
  const float* k_a    = (const float*)d_in[8];
  const float* r_k    = (const float*)d_in[9];
  const float* W_r    = (const float*)d_in[10];
  const float* W_k    = (const float*)d_in[11];
  const float* W_v    = (const float*)d_in[12];
  const float* W_o    = (const float*)d_in[13];
  const float* wla    = (const float*)d_in[14];
  const float* wlb    = (const float*)d_in[15];
  const float* wlbias = (const float*)d_in[16];
  const float* ala    = (const float*)d_in[17];
  const float* alb    = (const float*)d_in[18];
  const float* albias = (const float*)d_in[19];
  const float* gla    = (const float*)d_in[20];
  const float* glb    = (const float*)d_in[21];
  const float* glbias = (const float*)d_in[22];
  const float* gnw    = (const float*)d_in[23];
  const float* gnb    = (const float*)d_in[24];

  char* ws = (char*)d_ws;
  size_t cur = 0;
  auto take = [&](size_t bytes) { size_t o = cur; cur += (bytes + 255) & ~(size_t)255; return o; };

  // fp16 x operands [4096][1024] (8MB each); xk,xv consecutive (S0_f spans them)
  f16* xr_h = (f16*)(ws + take((size_t)4096*1024*2));
  f16* xw_h = (f16*)(ws + take((size_t)4096*1024*2));
  f16* xk_h = (f16*)(ws + take((size_t)4096*1024*2));
  f16* xv_h = (f16*)(ws + take((size_t)4096*1024*2));
  f16* xa_h = (f16*)(ws + take((size_t)4096*1024*2));
  // fp16 weights
  f16* Wr_p  = (f16*)(ws + take((size_t)1024*1024*2));
  f16* Wk_p  = (f16*)(ws + take((size_t)1024*1024*2));
  f16* Wv_p  = (f16*)(ws + take((size_t)1024*1024*2));
  f16* Wo_p  = (f16*)(ws + take((size_t)1024*1024*2));
  f16* wla_p = (f16*)(ws + take((size_t)128*1024*2));
  f16* wlb_p = (f16*)(ws + take((size_t)1024*64*2));
  f16* ala_p = (f16*)(ws + take((size_t)128*1024*2));
  f16* alb_p = (f16*)(ws + take((size_t)1024*64*2));
  f16* gla_p = (f16*)(ws + take((size_t)128*1024*2));
  f16* glb_p = (f16*)(ws + take((size_t)1024*128*2));
  // fp16 scan operands
  f16* r_h  = (f16*)(ws + take((size_t)4096*1024*2));
  f16* k_h  = (f16*)(ws + take((size_t)4096*1024*2));
  f16* v_h  = (f16*)(ws + take((size_t)4096*1024*2));
  f16* kk_h = (f16*)(ws + take((size_t)4096*1024*2));
  f16* g_h  = (f16*)(ws + take((size_t)4096*1024*2));
  f16* t2w  = (f16*)(ws + take((size_t)4096*64*2));
  f16* t2a  = (f16*)(ws + take((size_t)4096*64*2));
  f16* t2g  = (f16*)(ws + take((size_t)4096*128*2));
  // fp32 buffers
  float* z_f  = (float*)(ws + take((size_t)4096*1024*4));
  float* Uc_f = (float*)(ws + take((size_t)4096*1024*4));
  float* PT_f = (float*)(ws + take((size_t)4096*1024*4));
  // aliases (lifetime-checked against launch order):
  f16*   ew_h = xw_h;            // xw read L2 (w-s1); ew written L3, read p1 L6
  f16*   a_h  = xa_h;            // xa read L2 (a-s1); a written L3, scanprep L5 -> bb, read p1 L6
  f16*   y_h  = xr_h;            // xr read L2 (r); y written L8, read L9
  float* S0_f = (float*)xk_h;    // spans xk_h+xv_h (16MB, consecutive); both dead after L2;
                                 // S0 written L7, read L8
  float* oF   = (float*)d_out;   // o0 lives in d_out until L9 overwrites

  // L1: prep -> 5 fp16 operands
  k_prep<<<4096, 256, 0, stream>>>(hs, x_r, x_w, x_k, x_v, x_a,
                                   xr_h, xw_h, xk_h, xv_h, xa_h);
  // L1b: weight transpose -> fp16
  SrcP sp; DstP dp;
  sp.p[0]=W_r; sp.p[1]=W_k; sp.p[2]=W_v; sp.p[3]=W_o;
  sp.p[4]=wla; sp.p[5]=wlb; sp.p[6]=ala; sp.p[7]=alb; sp.p[8]=gla; sp.p[9]=glb;
  dp.p[0]=Wr_p; dp.p[1]=Wk_p; dp.p[2]=Wv_p; dp.p[3]=Wo_p;
  dp.p[4]=wla_p; dp.p[5]=wlb_p; dp.p[6]=ala_p; dp.p[7]=alb_p; dp.p[8]=gla_p; dp.p[9]=glb_p;
  k_transpose<<<dim3(32,32,10), dim3(32,8), 0, stream>>>(sp, dp);

  GJobs J{};
  auto job = [](const f16* A, const f16* Bt, float* C, f16* Cpk, const float* bias,
                int K, int N, int Npk, int ldc, int act, int lda, int ldb) {
    GJob j; j.A=A; j.Bt=Bt; j.C=C; j.Cpk=Cpk; j.bias=bias;
    j.K=K; j.N=N; j.Npk=Npk; j.ldc=ldc; j.act=act; j.lda=lda; j.ldb=ldb;
    return j;
  };

  // L2: r, k, v (fp16 outs), w-s1(tanh->t2w), a-s1(->t2a)
  J.j[0] = job(xr_h, Wr_p,  nullptr, r_h, nullptr, 1024, 1024, 1024, 0, 0, 1024, 1024);
  J.j[1] = job(xk_h, Wk_p,  nullptr, k_h, nullptr, 1024, 1024, 1024, 0, 0, 1024, 1024);
  J.j[2] = job(xv_h, Wv_p,  nullptr, v_h, nullptr, 1024, 1024, 1024, 0, 0, 1024, 1024);
  J.j[3] = job(xw_h, wla_p, nullptr, t2w, nullptr, 1024, 128,  64,   0, 2, 1024, 1024);
  J.j[4] = job(xa_h, ala_p, nullptr, t2a, nullptr, 1024, 128,  64,   0, 0, 1024, 1024);
  k_gemm_fp16<<<dim3(32,8,5), 256, 0, stream>>>(J);

  // L3: w-s2 (ew), a-s2 (sigmoid), g-s1 (sigmoid -> t2g)
  J = GJobs{};
  J.j[0] = job(t2w, wlb_p, nullptr, ew_h, wlbias, 64,   1024, 1024, 0, 3, 64,   64);
  J.j[1] = job(t2a, alb_p, nullptr, a_h,  albias, 64,   1024, 1024, 0, 1, 64,   64);
  J.j[2] = job(r_h, gla_p, nullptr, t2g,  nullptr, 1024, 128,  128,  0, 1, 1024, 1024);
  k_gemm_fp16<<<dim3(32,8,3), 256, 0, stream>>>(J);

  // L4: g-s2 (+bias)
  J = GJobs{};
  J.j[0] = job(t2g, glb_p, nullptr, g_h, glbias, 128, 1024, 1024, 0, 0, 128, 128);
  k_gemm_fp16<<<dim3(32,8,1), 256, 0, stream>>>(J);

  // L5: kk normalize + k update + b precompute (fp16 I/O)
  k_scanprep<<<2048, 256, 0, stream>>>(k_h, a_h, k_k, k_a, kk_h);

  // L6-L7: chunked scan
  k_scan_p1<<<1024, 512, 0, stream>>>(r_h, ew_h, k_h, v_h, kk_h, a_h, oF, z_f, Uc_f, PT_f);
  k_chain<<<32, 256, 0, stream>>>(Uc_f, PT_f, S0_f);

  // L8: fused correction + groupnorm + bonus + gate -> fp16 y
  k_corrpost<<<1024, 256, 0, stream>>>(S0_f, z_f, oF, r_h, k_h, v_h,
                                       r_k, gnw, gnb, g_h, y_h);

  // L9: output projection (overwrites d_out)
  J = GJobs{};
  J.j[0] = job(y_h, Wo_p, (float*)d_out, nullptr, nullptr, 1024, 1024, 0, 1024, 0, 1024, 1024);
  k_gemm_fp16<<<dim3(32,8,1), 256, 0, stream>>>(J);
}

// Round 15
// 315.145 us; speedup vs baseline: 1.6109x; 1.0241x over previous
//
#include <hip/hip_runtime.h>
#include <hip/hip_bf16.h>
#include <hip/hip_fp16.h>
#include <stdint.h>
#include <stddef.h>

typedef __hip_bfloat16 bf16;
typedef _Float16 f16;
typedef __attribute__((ext_vector_type(8))) short short8;
typedef __attribute__((ext_vector_type(8))) _Float16 half8;
typedef __attribute__((ext_vector_type(4))) float f32x4;
typedef __attribute__((ext_vector_type(2))) float f32x2;
typedef unsigned short us;

__device__ __forceinline__ float dsigm(float z){ return 1.f/(1.f+expf(-z)); }

// DPP sums: quad_perm 0xB1 = xor1, 0x4E = xor2 (within quad); 0x141 = row_half_mirror (xor4)
template<int CTRL>
__device__ __forceinline__ float dpp_term(float x) {
  int xi = __builtin_bit_cast(int, x);
  int yi = __builtin_amdgcn_update_dpp(0, xi, CTRL, 0xF, 0xF, false);
  return __builtin_bit_cast(float, yi);
}
__device__ __forceinline__ float red4(float x) {   // sum over quad (q = lane&3)
  x += dpp_term<0xB1>(x);
  x += dpp_term<0x4E>(x);
  return x;
}

// split fp32 -> hi (rounded bf16) + lo (rounded bf16 residual); scan-side MFMA only
__device__ __forceinline__ void split1(float v, us& h, us& l) {
  bf16 hb = __float2bfloat16(v);
  h = __builtin_bit_cast(us, hb);
  float hf = __bfloat162float(hb);
  bf16 lb = __float2bfloat16(v - hf);
  l = __builtin_bit_cast(us, lb);
}

__device__ __forceinline__ void split8(const float* f, short8& h, short8& l) {
#pragma unroll
  for (int e = 0; e < 8; ++e) {
    us hh, ll;
    split1(f[e], hh, ll);
    h[e] = (short)hh; l[e] = (short)ll;
  }
}

// async global->LDS, 16B per lane (dest = wave-uniform base + lane*16)
__device__ __forceinline__ void gl16(const f16* g, f16* l) {
  __builtin_amdgcn_global_load_lds((const __attribute__((address_space(1))) void*)g,
                                   (__attribute__((address_space(3))) void*)l, 16, 0, 0);
}

//==================== 1. time-shift lerp -> fp16 operands ====================
__device__ __forceinline__ void emit16(const float* __restrict__ marr, int c4,
    const float4& cur, const float4& dlt, f16* __restrict__ out, int row)
{
  float4 m = *(const float4*)(marr + c4);
  f16* o = out + (size_t)row*1024 + c4;
  o[0] = (f16)fmaf(dlt.x, m.x, cur.x);
  o[1] = (f16)fmaf(dlt.y, m.y, cur.y);
  o[2] = (f16)fmaf(dlt.z, m.z, cur.z);
  o[3] = (f16)fmaf(dlt.w, m.w, cur.w);
}

__global__ void k_prep(const float* __restrict__ hs,
    const float* __restrict__ mr, const float* __restrict__ mw, const float* __restrict__ mk,
    const float* __restrict__ mv, const float* __restrict__ ma,
    f16* __restrict__ oxr, f16* __restrict__ oxw, f16* __restrict__ oxk,
    f16* __restrict__ oxv, f16* __restrict__ oxa)
{
  int id = blockIdx.x * 256 + threadIdx.x;
  int row = id >> 8;
  int c4 = (id & 255) << 2;
  int t = row & 2047;
  const float* hp = hs + (size_t)row*1024 + c4;
  float4 cur = *(const float4*)hp;
  float4 prev = make_float4(0.f,0.f,0.f,0.f);
  if (t > 0) prev = *(const float4*)(hp - 1024);
  float4 dlt = make_float4(prev.x-cur.x, prev.y-cur.y, prev.z-cur.z, prev.w-cur.w);
  emit16(mr, c4, cur, dlt, oxr, row);
  emit16(mw, c4, cur, dlt, oxw, row);
  emit16(mk, c4, cur, dlt, oxk, row);
  emit16(mv, c4, cur, dlt, oxv, row);
  emit16(ma, c4, cur, dlt, oxa, row);
}

//==================== 2. weight transpose -> fp16 ====================
struct SrcP { const float* p[10]; };
struct DstP { f16* p[10]; };

__global__ void k_transpose(SrcP S, DstP Dd)
{
  static constexpr int TR[10]  = {1024,1024,1024,1024,1024,  64,1024,  64,1024, 128};
  static constexpr int TCC[10] = {1024,1024,1024,1024,  64,1024,  64,1024, 128,1024};
  static constexpr int TCP[10] = {1024,1024,1024,1024, 128,1024, 128,1024, 128,1024};
  int z = blockIdx.z;
  int R = TR[z], Cc = TCC[z], Cp = TCP[z];
  int n0 = blockIdx.x * 32, r0 = blockIdx.y * 32;
  if (n0 >= Cp || r0 >= R) return;
  const float* src = S.p[z];
  f16* dst = Dd.p[z];
  int tx = threadIdx.x, ty = threadIdx.y;
  __shared__ float tile[32][33];
  if (n0 < Cc) {
#pragma unroll
    for (int i = 0; i < 4; ++i)
      tile[ty + 8*i][tx] = src[(size_t)(r0 + ty + 8*i)*Cc + n0 + tx];
    __syncthreads();
#pragma unroll
    for (int i = 0; i < 4; ++i)
      dst[(size_t)(n0 + ty + 8*i)*R + r0 + tx] = (f16)tile[tx][ty + 8*i];
  } else {
#pragma unroll
    for (int i = 0; i < 4; ++i)
      dst[(size_t)(n0 + ty + 8*i)*R + r0 + tx] = (f16)0.f;
  }
}

//==================== 3. batched fp16 MFMA GEMM (BK=64, XOR-swizzled LDS) ====================
struct GJob {
  const f16* A;              // [4096][lda]
  const f16* Bt;             // [N][ldb]
  float* C;                  // optional fp32 out [4096][ldc]
  f16* Cpk;                  // optional fp16 out [4096][Npk]
  const float* bias;         // optional per-col (added before act)
  int K; int N; int Npk; int ldc; int act;   // act: 0 none, 1 sigmoid, 2 tanh, 3 e^-.5*sigmoid
  int lda; int ldb;
};
struct GJobs { GJob j[5]; };

__global__ __launch_bounds__(256) void k_gemm_fp16(GJobs jobs)
{
  GJob jb = jobs.j[blockIdx.z];
  const int colBase = blockIdx.y * 128;
  if (colBase >= jb.N) return;
  const int rowBase = blockIdx.x * 128;
  __shared__ __align__(16) f16 As[128*64];
  __shared__ __align__(16) f16 Bs[128*64];
  const int tid = threadIdx.x;
  const int l = tid & 63, w = tid >> 6;
  const int wm = w >> 1, wn = w & 1;
  const int lrow = l & 15;
  const int nk = jb.K >> 6;

  const f16* Arow[4]; const f16* Brow[4]; int ld[4];
#pragma unroll
  for (int i2 = 0; i2 < 4; ++i2) {
    int s = (i2*4 + w)*64 + l;
    int ar = s >> 3;
    int unit = s & 7;
    int acs = (unit ^ (ar & 7)) * 8;
    Arow[i2] = jb.A  + (size_t)(rowBase + ar)*jb.lda + acs;
    Brow[i2] = jb.Bt + (size_t)(colBase + ar)*jb.ldb + acs;
    ld[i2] = (i2*4 + w) * 512;
  }

  f32x4 acc[4][4];
#pragma unroll
  for (int i = 0; i < 4; ++i)
#pragma unroll
    for (int j = 0; j < 4; ++j) { f32x4 z = {0.f,0.f,0.f,0.f}; acc[i][j] = z; }

  for (int kt = 0; kt < nk; ++kt) {
    const int kh = kt*64;
#pragma unroll
    for (int i2 = 0; i2 < 4; ++i2) {
      gl16(Arow[i2] + kh, &As[ld[i2]]);
      gl16(Brow[i2] + kh, &Bs[ld[i2]]);
    }
    __syncthreads();
#pragma unroll
    for (int ks = 0; ks < 2; ++ks) {
      half8 ah[4], bh[4];
#pragma unroll
      for (int mt = 0; mt < 4; ++mt) {
        int row = wm*64 + mt*16 + lrow;
        int cu = ks*4 + (l >> 4);
        ah[mt] = *(const half8*)&As[row*64 + ((cu ^ (row & 7)) * 8)];
      }
#pragma unroll
      for (int nt = 0; nt < 4; ++nt) {
        int row = wn*64 + nt*16 + lrow;
        int cu = ks*4 + (l >> 4);
        bh[nt] = *(const half8*)&Bs[row*64 + ((cu ^ (row & 7)) * 8)];
      }
#pragma unroll
      for (int mt = 0; mt < 4; ++mt)
#pragma unroll
        for (int nt = 0; nt < 4; ++nt)
          acc[mt][nt] = __builtin_amdgcn_mfma_f32_16x16x32_f16(ah[mt], bh[nt], acc[mt][nt], 0, 0, 0);
    }
    __syncthreads();
  }
#pragma unroll
  for (int mt = 0; mt < 4; ++mt) {
    int row = rowBase + wm*64 + mt*16 + (l >> 4)*4;
#pragma unroll
    for (int nt = 0; nt < 4; ++nt) {
      int col = colBase + wn*64 + nt*16 + (l & 15);
      float bv = (jb.bias != nullptr) ? jb.bias[col] : 0.f;
#pragma unroll
      for (int rg = 0; rg < 4; ++rg) {
        float v = acc[mt][nt][rg] + bv;
        if (jb.act == 1)      v = dsigm(v);
        else if (jb.act == 2) v = tanhf(v);
        else if (jb.act == 3) v = 0.60653066f * dsigm(v);
        if (jb.C) jb.C[(size_t)(row + rg)*jb.ldc + col] = v;
        if (jb.Cpk && col < jb.Npk)
          jb.Cpk[(size_t)(row + rg)*jb.Npk + col] = (f16)v;
      }
    }
  }
}

//==================== 5. scan prep (fp16 I/O): kk normalize + k update + b=kk*a ====================
__global__ void k_scanprep(f16* __restrict__ kA, f16* __restrict__ aA,
                           const float* __restrict__ kkw, const float* __restrict__ kaw,
                           f16* __restrict__ kkA)
{
  int idx = blockIdx.x * 256 + threadIdx.x;      // 524288 threads, 8 elems each
  size_t gt8 = (size_t)idx * 8;
  int ch = (int)(gt8 & 1023);
  half8 k8 = *(const half8*)(kA + gt8);
  half8 a8 = *(const half8*)(aA + gt8);
  float kw[8], ka_[8];
  *(float4*)&kw[0]  = *(const float4*)(kkw + ch);
  *(float4*)&kw[4]  = *(const float4*)(kkw + ch + 4);
  *(float4*)&ka_[0] = *(const float4*)(kaw + ch);
  *(float4*)&ka_[4] = *(const float4*)(kaw + ch + 4);
  float kkv[8]; float ss = 0.f;
#pragma unroll
  for (int e = 0; e < 8; ++e) { kkv[e] = (float)k8[e] * kw[e]; ss += kkv[e]*kkv[e]; }
  ss += __shfl_xor(ss, 1); ss += __shfl_xor(ss, 2); ss += __shfl_xor(ss, 4);
  float inv = 1.f / fmaxf(sqrtf(ss), 1e-12f);
  half8 kkn8, bb8, kup8;
#pragma unroll
  for (int e = 0; e < 8; ++e) {
    float kkn = kkv[e] * inv;
    float av = (float)a8[e];
    kkn8[e] = (f16)kkn;
    bb8[e]  = (f16)(kkn * av);
    kup8[e] = (f16)((float)k8[e] * fmaf(av - 1.f, ka_[e], 1.f));
  }
  *(half8*)(kkA + gt8) = kkn8;
  *(half8*)(aA + gt8)  = bb8;
  *(half8*)(kA + gt8)  = kup8;
}

//==================== 6a. chunked scan pass 1 (256 thr, 16 cols/thread, quad reductions) ====================
// f16 global operands; staging lanes convert once -> f32 LDS [6][8][64] per buffer
// (12KB, double-buffered 24KB). Thread (i = tid>>2, q = tid&3) owns cols [q*16, q*16+16).
// Packed f32x2 math; reductions via 2-stage quad DPP (red4). Arrays: 0=ew 1=kk 2=bb 3=k 4=r 5=v.
__device__ __forceinline__ void step_pk16(const float* __restrict__ sb, int s,
    f32x2* u2, f32x2* p2, float* __restrict__ o0A, float* __restrict__ zA,
    size_t base, int i, int q, int j0)
{
  // dots against kk
  f32x2 kk2[8];
#pragma unroll
  for (int hh = 0; hh < 4; ++hh) {
    float4 a1 = *(const float4*)(sb + 512 + s*64 + j0 + hh*4);
    kk2[hh*2+0] = f32x2{a1.x, a1.y}; kk2[hh*2+1] = f32x2{a1.z, a1.w};
  }
  f32x2 uk2 = u2[0]*kk2[0], pk2 = p2[0]*kk2[0];
#pragma unroll
  for (int e = 1; e < 8; ++e) { uk2 += u2[e]*kk2[e]; pk2 += p2[e]*kk2[e]; }
  float uk = red4(uk2.x + uk2.y);
  float pk = red4(pk2.x + pk2.y);
  float vi = sb[2560 + s*64 + i];
  const f32x2 su2 = {-uk, -uk}, sp2 = {-pk, -pk}, vi2 = {vi, vi};
  f32x2 oo2 = {0.f, 0.f}, zz2 = {0.f, 0.f};
#pragma unroll
  for (int hh = 0; hh < 4; ++hh) {
    float4 e4 = *(const float4*)(sb + 0    + s*64 + j0 + hh*4);
    float4 b4 = *(const float4*)(sb + 1024 + s*64 + j0 + hh*4);
    float4 k4 = *(const float4*)(sb + 1536 + s*64 + j0 + hh*4);
    float4 r4 = *(const float4*)(sb + 2048 + s*64 + j0 + hh*4);
    f32x2 ew0 = {e4.x, e4.y}, ew1 = {e4.z, e4.w};
    f32x2 bb0 = {b4.x, b4.y}, bb1 = {b4.z, b4.w};
    f32x2 kv0 = {k4.x, k4.y}, kv1 = {k4.z, k4.w};
    f32x2 rr0 = {r4.x, r4.y}, rr1 = {r4.z, r4.w};
    int e0 = hh*2, e1 = hh*2 + 1;
    f32x2 uu0 = u2[e0]*ew0 + su2*bb0 + vi2*kv0;
    u2[e0] = uu0; oo2 += uu0*rr0;
    f32x2 pp0 = p2[e0]*ew0 + sp2*bb0;
    p2[e0] = pp0; zz2 += pp0*rr0;
    f32x2 uu1 = u2[e1]*ew1 + su2*bb1 + vi2*kv1;
    u2[e1] = uu1; oo2 += uu1*rr1;
    f32x2 pp1 = p2[e1]*ew1 + sp2*bb1;
    p2[e1] = pp1; zz2 += pp1*rr1;
  }
  float oo = red4(oo2.x + oo2.y);
  float zz = red4(zz2.x + zz2.y);
  if (q == 0) { o0A[base + i] = oo; zA[base + i] = zz; }
}

__global__ __launch_bounds__(256) void k_scan_p1(
    const f16* __restrict__ rA, const f16* __restrict__ ewA,
    const f16* __restrict__ kA, const f16* __restrict__ vA,
    const f16* __restrict__ kkA, const f16* __restrict__ bbA,
    float* __restrict__ o0A, float* __restrict__ zA,
    float* __restrict__ UcA, float* __restrict__ PTcA)
{
  const int blk = blockIdx.x;
  const int bh = blk & 31, c = blk >> 5;
  const int b = bh >> 4, h = bh & 15;
  const int tid = threadIdx.x;
  const int i = tid >> 2, q = tid & 3, j0 = q * 16;
  const size_t base0 = (size_t)b*2048*1024 + (size_t)h*64 + (size_t)(c*64)*1024;

  __shared__ __align__(16) float smem[6144];   // 2x3072 f32 staging; [64][65] tail fits

  // staging: 384 slots of 8 f16; thread covers slot tid (all) and 256+tid (tid<128)
  const int aA_ = tid >> 6, rmA = tid & 63, ssA = rmA >> 3, fA = rmA & 7;
  const f16* paA = (aA_==0) ? ewA : (aA_==1) ? kkA : (aA_==2) ? bbA : kA;
  const f16* srcA = paA + base0 + (size_t)ssA*1024 + fA*8;
  const int dstA = aA_*512 + ssA*64 + fA*8;
  const int hasB = (tid < 128);
  const int sB = 256 + tid;
  const int aB_ = sB >> 6, rmB = sB & 63, ssB = rmB >> 3, fB = rmB & 7;
  const f16* paB = (aB_ == 4) ? rA : vA;
  const f16* srcB = paB + base0 + (size_t)ssB*1024 + fB*8;
  const int dstB = aB_*512 + ssB*64 + fB*8;

  f32x2 u2[8], p2[8];
#pragma unroll
  for (int e = 0; e < 8; ++e) {
    u2[e] = f32x2{0.f, 0.f};
    float p0 = (j0 + 2*e     == i) ? 1.f : 0.f;
    float p1 = (j0 + 2*e + 1 == i) ? 1.f : 0.f;
    p2[e] = f32x2{p0, p1};
  }

  {
    half8 hA = *(const half8*)(srcA);
    *(float4*)&smem[dstA]     = make_float4((float)hA[0], (float)hA[1], (float)hA[2], (float)hA[3]);
    *(float4*)&smem[dstA + 4] = make_float4((float)hA[4], (float)hA[5], (float)hA[6], (float)hA[7]);
    if (hasB) {
      half8 hB = *(const half8*)(srcB);
      *(float4*)&smem[dstB]     = make_float4((float)hB[0], (float)hB[1], (float)hB[2], (float)hB[3]);
      *(float4*)&smem[dstB + 4] = make_float4((float)hB[4], (float)hB[5], (float)hB[6], (float)hB[7]);
    }
  }
  __syncthreads();

  int curb = 0;
  for (int g = 0; g < 8; ++g) {
    half8 nA, nB;
    if (g < 7) {
      nA = *(const half8*)(srcA + (size_t)(g+1)*8192);
      if (hasB) nB = *(const half8*)(srcB + (size_t)(g+1)*8192);
    }
    const float* sb = smem + curb*3072;
#pragma unroll
    for (int s = 0; s < 8; ++s)
      step_pk16(sb, s, u2, p2, o0A, zA, base0 + (size_t)(g*8 + s)*1024, i, q, j0);
    if (g < 7) {
      int nb = curb ^ 1;
      *(float4*)&smem[nb*3072 + dstA]     = make_float4((float)nA[0], (float)nA[1], (float)nA[2], (float)nA[3]);
      *(float4*)&smem[nb*3072 + dstA + 4] = make_float4((float)nA[4], (float)nA[5], (float)nA[6], (float)nA[7]);
      if (hasB) {
        *(float4*)&smem[nb*3072 + dstB]     = make_float4((float)nB[0], (float)nB[1], (float)nB[2], (float)nB[3]);
        *(float4*)&smem[nb*3072 + dstB + 4] = make_float4((float)nB[4], (float)nB[5], (float)nB[6], (float)nB[7]);
      }
    }
    __syncthreads();
    curb ^= 1;
  }

  // store U_c (row-major [i][j]) and P_c^T (row-major [j][m]) for pass 2
  const size_t cbase = ((size_t)(bh*32 + c)) * 4096;
#pragma unroll
  for (int e4 = 0; e4 < 4; ++e4)
    *(float4*)(UcA + cbase + (size_t)i*64 + j0 + e4*4) =
      make_float4(u2[e4*2].x, u2[e4*2].y, u2[e4*2+1].x, u2[e4*2+1].y);
  float (*lds)[65] = (float(*)[65])smem;
#pragma unroll
  for (int e = 0; e < 8; ++e) {
    lds[i][j0 + 2*e]     = p2[e].x;
    lds[i][j0 + 2*e + 1] = p2[e].y;
  }
  __syncthreads();
#pragma unroll
  for (int e4 = 0; e4 < 4; ++e4) {
    float4 wv = make_float4(lds[j0 + e4*4 + 0][i], lds[j0 + e4*4 + 1][i],
                            lds[j0 + e4*4 + 2][i], lds[j0 + e4*4 + 3][i]);
    *(float4*)(PTcA + cbase + (size_t)i*64 + j0 + e4*4) = wv;
  }
}

//==================== 6b. chain: S_{c+1} = U_c + S_c @ P_c (split-bf16, fp32-grade) ====================
__device__ __forceinline__ void chain_body(int c, int bh, int w, int lr, int lq,
    float (&Slds)[64][65], f32x4 (&acc)[4],
    float (&u_c)[4][4], float4 (&p_c)[2][2],
    float (&u_n)[4][4], float4 (&p_n)[2][2],
    const float* __restrict__ UcA, const float* __restrict__ PTcA,
    float* __restrict__ S0A)
{
  const size_t s0base = ((size_t)bh*32 + c) * 4096;
#pragma unroll
  for (int mt = 0; mt < 4; ++mt)
#pragma unroll
    for (int rg = 0; rg < 4; ++rg) {
      Slds[mt*16 + lq*4 + rg][w*16 + lr] = acc[mt][rg];
      if (c > 0) S0A[s0base + (size_t)(mt*16 + lq*4 + rg)*64 + w*16 + lr] = acc[mt][rg];
    }
  __syncthreads();
  if (c + 1 < 32) {
    const size_t nbase = ((size_t)bh*32 + c + 1) * 4096;
#pragma unroll
    for (int mt = 0; mt < 4; ++mt)
#pragma unroll
      for (int rg = 0; rg < 4; ++rg)
        u_n[mt][rg] = UcA[nbase + (size_t)(mt*16 + lq*4 + rg)*64 + w*16 + lr];
#pragma unroll
    for (int kt = 0; kt < 2; ++kt)
#pragma unroll
      for (int hh = 0; hh < 2; ++hh)
        p_n[kt][hh] = *(const float4*)(PTcA + nbase + (size_t)(w*16 + lr)*64 + kt*32 + lq*8 + hh*4);
  }
  short8 pbh[2], pbl[2];
#pragma unroll
  for (int kt = 0; kt < 2; ++kt) {
    float f[8] = {p_c[kt][0].x, p_c[kt][0].y, p_c[kt][0].z, p_c[kt][0].w,
                  p_c[kt][1].x, p_c[kt][1].y, p_c[kt][1].z, p_c[kt][1].w};
    split8(f, pbh[kt], pbl[kt]);
  }
  f32x4 nacc[4];
#pragma unroll
  for (int mt = 0; mt < 4; ++mt) {
    f32x4 z = {u_c[mt][0], u_c[mt][1], u_c[mt][2], u_c[mt][3]};
    nacc[mt] = z;
  }
#pragma unroll
  for (int kt = 0; kt < 2; ++kt)
#pragma unroll
    for (int mt = 0; mt < 4; ++mt) {
      float f[8];
#pragma unroll
      for (int e = 0; e < 8; ++e) f[e] = Slds[mt*16 + lr][kt*32 + lq*8 + e];
      short8 sah, sal;
      split8(f, sah, sal);
      nacc[mt] = __builtin_amdgcn_mfma_f32_16x16x32_bf16(sah, pbh[kt], nacc[mt], 0, 0, 0);
      nacc[mt] = __builtin_amdgcn_mfma_f32_16x16x32_bf16(sal, pbh[kt], nacc[mt], 0, 0, 0);
      nacc[mt] = __builtin_amdgcn_mfma_f32_16x16x32_bf16(sah, pbl[kt], nacc[mt], 0, 0, 0);
    }
#pragma unroll
  for (int mt = 0; mt < 4; ++mt) acc[mt] = nacc[mt];
  __syncthreads();
}

__global__ __launch_bounds__(256) void k_chain(
    const float* __restrict__ UcA, const float* __restrict__ PTcA,
    float* __restrict__ S0A)
{
  const int bh = blockIdx.x;
  const int l = threadIdx.x & 63, w = threadIdx.x >> 6;
  const int lr = l & 15, lq = l >> 4;
  __shared__ float Slds[64][65];

  f32x4 acc[4];
#pragma unroll
  for (int mt = 0; mt < 4; ++mt) { f32x4 z = {0.f,0.f,0.f,0.f}; acc[mt] = z; }

  float u0[4][4], u1[4][4];
  float4 p0[2][2], p1[2][2];
  {
    const size_t cbase = (size_t)bh * 32 * 4096;
#pragma unroll
    for (int mt = 0; mt < 4; ++mt)
#pragma unroll
      for (int rg = 0; rg < 4; ++rg)
        u0[mt][rg] = UcA[cbase + (size_t)(mt*16 + lq*4 + rg)*64 + w*16 + lr];
#pragma unroll
    for (int kt = 0; kt < 2; ++kt)
#pragma unroll
      for (int hh = 0; hh < 2; ++hh)
        p0[kt][hh] = *(const float4*)(PTcA + cbase + (size_t)(w*16 + lr)*64 + kt*32 + lq*8 + hh*4);
  }
  for (int c = 0; c < 32; c += 2) {
    chain_body(c,     bh, w, lr, lq, Slds, acc, u0, p0, u1, p1, UcA, PTcA, S0A);
    chain_body(c + 1, bh, w, lr, lq, Slds, acc, u1, p1, u0, p0, UcA, PTcA, S0A);
  }
}

//==================== 6c. fused correction + GroupNorm + bonus + gate -> fp16 y ====================
__global__ __launch_bounds__(256) void k_corrpost(
    const float* __restrict__ S0A, const float* __restrict__ zA,
    const float* __restrict__ o0A, const f16* __restrict__ rA,
    const f16* __restrict__ kA, const f16* __restrict__ vA,
    const float* __restrict__ rk, const float* __restrict__ gnw,
    const float* __restrict__ gnb, const f16* __restrict__ gA,
    f16* __restrict__ yH)
{
  const int blk = blockIdx.x;
  const int bh = blk & 31;
  const int c  = blk >> 5;               // 0..31
  const int b = bh >> 4, h = bh & 15;
  const int l = threadIdx.x & 63, w = threadIdx.x >> 6;
  const int lr = l & 15, lq = l >> 4;

  f32x4 a2[4];
#pragma unroll
  for (int nt = 0; nt < 4; ++nt) { f32x4 z = {0.f,0.f,0.f,0.f}; a2[nt] = z; }

  if (c > 0) {
    const size_t s0base = ((size_t)bh*32 + c) * 4096;
    short8 sbh[4][2], sbl[4][2];
#pragma unroll
    for (int nt = 0; nt < 4; ++nt)
#pragma unroll
      for (int kt = 0; kt < 2; ++kt) {
        float f[8];
#pragma unroll
        for (int e = 0; e < 8; ++e)
          f[e] = S0A[s0base + (size_t)(nt*16 + lr)*64 + kt*32 + lq*8 + e];
        split8(f, sbh[nt][kt], sbl[nt][kt]);
      }
    short8 zh[2], zl[2];
#pragma unroll
    for (int kt = 0; kt < 2; ++kt) {
      const float* zp = zA + ((size_t)(b*2048 + c*64 + w*16 + lr)*16 + h)*64 + kt*32 + lq*8;
      float f[8];
#pragma unroll
      for (int e = 0; e < 8; ++e) f[e] = zp[e];
      split8(f, zh[kt], zl[kt]);
    }
#pragma unroll
    for (int kt = 0; kt < 2; ++kt)
#pragma unroll
      for (int nt = 0; nt < 4; ++nt) {
        a2[nt] = __builtin_amdgcn_mfma_f32_16x16x32_bf16(zh[kt], sbh[nt][kt], a2[nt], 0, 0, 0);
        a2[nt] = __builtin_amdgcn_mfma_f32_16x16x32_bf16(zl[kt], sbh[nt][kt], a2[nt], 0, 0, 0);
        a2[nt] = __builtin_amdgcn_mfma_f32_16x16x32_bf16(zh[kt], sbl[nt][kt], a2[nt], 0, 0, 0);
      }
  }

#pragma unroll
  for (int rg = 0; rg < 4; ++rg) {
    const int tl = w*16 + lq*4 + rg;
    const size_t trow = (size_t)(b*2048 + c*64 + tl);
    const size_t rb = trow*1024 + h*64;
    float o4[4], v4[4];
    float sum = 0.f, pr = 0.f;
#pragma unroll
    for (int nt = 0; nt < 4; ++nt) {
      const int ii = nt*16 + lr;
      float o = o0A[rb + ii] + a2[nt][rg];
      o4[nt] = o; sum += o;
      v4[nt] = (float)vA[rb + ii];
      pr += (float)rA[rb + ii] * (float)kA[rb + ii] * rk[h*64 + ii];
    }
    sum += __shfl_xor(sum,1); sum += __shfl_xor(sum,2);
    sum += __shfl_xor(sum,4); sum += __shfl_xor(sum,8);
    pr  += __shfl_xor(pr,1);  pr  += __shfl_xor(pr,2);
    pr  += __shfl_xor(pr,4);  pr  += __shfl_xor(pr,8);
    float mean = sum * (1.f/64.f);
    float vp = 0.f;
#pragma unroll
    for (int nt = 0; nt < 4; ++nt) { float d = o4[nt]-mean; vp += d*d; }
    vp += __shfl_xor(vp,1); vp += __shfl_xor(vp,2);
    vp += __shfl_xor(vp,4); vp += __shfl_xor(vp,8);
    float inv = rsqrtf(vp*(1.f/64.f) + 1e-5f);
#pragma unroll
    for (int nt = 0; nt < 4; ++nt) {
      const int ii = nt*16 + lr;
      const int ch = h*64 + ii;
      float y = (o4[nt]-mean)*inv*gnw[ch] + gnb[ch];
      y = fmaf(pr, v4[nt], y);
      y *= (float)gA[rb + ii];
      yH[trow*1024 + ch] = (f16)y;
    }
  }
}

//==================== host ====================
extern "C" void kernel_launch(void* const* d_in, const int* in_sizes, int n_in,
                              void* d_out, int out_size, void* d_ws, size_t ws_size,
                              hipStream_t stream)
{
  (void)in_sizes; (void)n_in; (void)out_size; (void)ws_size;
  const float* hs     = (const float*)d_in[0];
  const float* x_r    = (const float*)d_in[1];
  const float* x_w    = (const float*)d_in[2];
  const float* x_k    = (const float*)d_in[3];
  const float* x_v    = (const float*)d_in[4];
  const float* x_a    = (const float*)d_in[5];
  const float* k_k    = (const float*)d_in[7];
  const float* k_a    = (const float*)d_in[8];
  const float* r_k    = (const float*)d_in[9];
  const float* W_r    = (const float*)d_in[10];
  const float* W_k    = (const float*)d_in[11];
  const float* W_v    = (const float*)d_in[12];
  const float* W_o    = (const float*)d_in[13];
  const float* wla    = (const float*)d_in[14];
  const float* wlb    = (const float*)d_in[15];
  const float* wlbias = (const float*)d_in[16];
  const float* ala    = (const float*)d_in[17];
  const float* alb    = (const float*)d_in[18];
  const float* albias = (const float*)d_in[19];
  const float* gla    = (const float*)d_in[20];
  const float* glb    = (const float*)d_in[21];
  const float* glbias = (const float*)d_in[22];
  const float* gnw    = (const float*)d_in[23];
  const float* gnb    = (const float*)d_in[24];

  char* ws = (char*)d_ws;
  size_t cur = 0;
  auto take = [&](size_t bytes) { size_t o = cur; cur += (bytes + 255) & ~(size_t)255; return o; };

  // fp16 x operands [4096][1024] (8MB each); xk,xv consecutive (S0_f spans them)
  f16* xr_h = (f16*)(ws + take((size_t)4096*1024*2));
  f16* xw_h = (f16*)(ws + take((size_t)4096*1024*2));
  f16* xk_h = (f16*)(ws + take((size_t)4096*1024*2));
  f16* xv_h = (f16*)(ws + take((size_t)4096*1024*2));
  f16* xa_h = (f16*)(ws + take((size_t)4096*1024*2));
  // fp16 weights
  f16* Wr_p  = (f16*)(ws + take((size_t)1024*1024*2));
  f16* Wk_p  = (f16*)(ws + take((size_t)1024*1024*2));
  f16* Wv_p  = (f16*)(ws + take((size_t)1024*1024*2));
  f16* Wo_p  = (f16*)(ws + take((size_t)1024*1024*2));
  f16* wla_p = (f16*)(ws + take((size_t)128*1024*2));
  f16* wlb_p = (f16*)(ws + take((size_t)1024*64*2));
  f16* ala_p = (f16*)(ws + take((size_t)128*1024*2));
  f16* alb_p = (f16*)(ws + take((size_t)1024*64*2));
  f16* gla_p = (f16*)(ws + take((size_t)128*1024*2));
  f16* glb_p = (f16*)(ws + take((size_t)1024*128*2));
  // fp16 scan operands
  f16* r_h  = (f16*)(ws + take((size_t)4096*1024*2));
  f16* k_h  = (f16*)(ws + take((size_t)4096*1024*2));
  f16* v_h  = (f16*)(ws + take((size_t)4096*1024*2));
  f16* kk_h = (f16*)(ws + take((size_t)4096*1024*2));
  f16* g_h  = (f16*)(ws + take((size_t)4096*1024*2));
  f16* t2w  = (f16*)(ws + take((size_t)4096*64*2));
  f16* t2a  = (f16*)(ws + take((size_t)4096*64*2));
  f16* t2g  = (f16*)(ws + take((size_t)4096*128*2));
  // fp32 buffers
  float* z_f  = (float*)(ws + take((size_t)4096*1024*4));
  float* Uc_f = (float*)(ws + take((size_t)4096*1024*4));
  float* PT_f = (float*)(ws + take((size_t)4096*1024*4));
  // aliases (lifetime-checked against launch order):
  f16*   ew_h = xw_h;            // xw read L2 (w-s1); ew written L3, read p1 L6
  f16*   a_h  = xa_h;            // xa read L2 (a-s1); a written L3, scanprep L5 -> bb, read p1 L6
  f16*   y_h  = xr_h;            // xr read L2 (r); y written L8, read L9
  float* S0_f = (float*)xk_h;    // spans xk_h+xv_h (16MB, consecutive); both dead after L2;
                                 // S0 written L7, read L8
  float* oF   = (float*)d_out;   // o0 lives in d_out until L9 overwrites

  // L1: prep -> 5 fp16 operands
  k_prep<<<4096, 256, 0, stream>>>(hs, x_r, x_w, x_k, x_v, x_a,
                                   xr_h, xw_h, xk_h, xv_h, xa_h);
  // L1b: weight transpose -> fp16
  SrcP sp; DstP dp;
  sp.p[0]=W_r; sp.p[1]=W_k; sp.p[2]=W_v; sp.p[3]=W_o;
  sp.p[4]=wla; sp.p[5]=wlb; sp.p[6]=ala; sp.p[7]=alb; sp.p[8]=gla; sp.p[9]=glb;
  dp.p[0]=Wr_p; dp.p[1]=Wk_p; dp.p[2]=Wv_p; dp.p[3]=Wo_p;
  dp.p[4]=wla_p; dp.p[5]=wlb_p; dp.p[6]=ala_p; dp.p[7]=alb_p; dp.p[8]=gla_p; dp.p[9]=glb_p;
  k_transpose<<<dim3(32,32,10), dim3(32,8), 0, stream>>>(sp, dp);

  GJobs J{};
  auto job = [](const f16* A, const f16* Bt, float* C, f16* Cpk, const float* bias,
                int K, int N, int Npk, int ldc, int act, int lda, int ldb) {
    GJob j; j.A=A; j.Bt=Bt; j.C=C; j.Cpk=Cpk; j.bias=bias;
    j.K=K; j.N=N; j.Npk=Npk; j.ldc=ldc; j.act=act; j.lda=lda; j.ldb=ldb;
    return j;
  };

  // L2: r, k, v (fp16 outs), w-s1(tanh->t2w), a-s1(->t2a)
  J.j[0] = job(xr_h, Wr_p,  nullptr, r_h, nullptr, 1024, 1024, 1024, 0, 0, 1024, 1024);
  J.j[1] = job(xk_h, Wk_p,  nullptr, k_h, nullptr, 1024, 1024, 1024, 0, 0, 1024, 1024);
  J.j[2] = job(xv_h, Wv_p,  nullptr, v_h, nullptr, 1024, 1024, 1024, 0, 0, 1024, 1024);
  J.j[3] = job(xw_h, wla_p, nullptr, t2w, nullptr, 1024, 128,  64,   0, 2, 1024, 1024);
  J.j[4] = job(xa_h, ala_p, nullptr, t2a, nullptr, 1024, 128,  64,   0, 0, 1024, 1024);
  k_gemm_fp16<<<dim3(32,8,5), 256, 0, stream>>>(J);

  // L3: w-s2 (ew), a-s2 (sigmoid), g-s1 (sigmoid -> t2g)
  J = GJobs{};
  J.j[0] = job(t2w, wlb_p, nullptr, ew_h, wlbias, 64,   1024, 1024, 0, 3, 64,   64);
  J.j[1] = job(t2a, alb_p, nullptr, a_h,  albias, 64,   1024, 1024, 0, 1, 64,   64);
  J.j[2] = job(r_h, gla_p, nullptr, t2g,  nullptr, 1024, 128,  128,  0, 1, 1024, 1024);
  k_gemm_fp16<<<dim3(32,8,3), 256, 0, stream>>>(J);

  // L4: g-s2 (+bias)
  J = GJobs{};
  J.j[0] = job(t2g, glb_p, nullptr, g_h, glbias, 128, 1024, 1024, 0, 0, 128, 128);
  k_gemm_fp16<<<dim3(32,8,1), 256, 0, stream>>>(J);

  // L5: kk normalize + k update + b precompute (fp16 I/O)
  k_scanprep<<<2048, 256, 0, stream>>>(k_h, a_h, k_k, k_a, kk_h);

  // L6-L7: chunked scan
  k_scan_p1<<<1024, 256, 0, stream>>>(r_h, ew_h, k_h, v_h, kk_h, a_h, oF, z_f, Uc_f, PT_f);
  k_chain<<<32, 256, 0, stream>>>(Uc_f, PT_f, S0_f);

  // L8: fused correction + groupnorm + bonus + gate -> fp16 y
  k_corrpost<<<1024, 256, 0, stream>>>(S0_f, z_f, oF, r_h, k_h, v_h,
                                       r_k, gnw, gnb, g_h, y_h);

  // L9: output projection (overwrites d_out)
  J = GJobs{};
  J.j[0] = job(y_h, Wo_p, (float*)d_out, nullptr, nullptr, 1024, 1024, 0, 1024, 0, 1024, 1024);
  k_gemm_fp16<<<dim3(32,8,1), 256, 0, stream>>>(J);
}